// Round 9
// baseline (581.715 us; speedup 1.0000x reference)
//
#include <hip/hip_runtime.h>
#include <math.h>

#define CCH    512
#define HWN    4096
#define NPIX   65536
#define OC3    1536
#define QSCALE 0.125f
#define LN_EPS 1e-5f

typedef _Float16 h16;
typedef h16  f16x8 __attribute__((ext_vector_type(8)));
typedef float f32x4 __attribute__((ext_vector_type(4)));

__device__ __forceinline__ float waveReduceSum(float v) {
#pragma unroll
    for (int off = 32; off; off >>= 1) v += __shfl_xor(v, off);
    return v;
}
__device__ __forceinline__ float waveReduceMax(float v) {
#pragma unroll
    for (int off = 32; off; off >>= 1) v = fmaxf(v, __shfl_xor(v, off));
    return v;
}

__device__ __forceinline__ void gl_lds16(const void* g, void* l) {
    __builtin_amdgcn_global_load_lds((const __attribute__((address_space(1))) void*)g,
                                     (__attribute__((address_space(3))) void*)l, 16, 0, 0);
}

// ---------------------------------------------------------------------------
// merged weight prep: o<1536 -> wg (w_qkv*g_ln, x64, hi/lo) + row-sum s;
//                     o>=1536 -> wo (w_out, x64, hi/lo)
__global__ __launch_bounds__(64) void prep_w(const float* __restrict__ w_qkv,
                                             const float* __restrict__ g_ln,
                                             const float* __restrict__ w_out,
                                             h16* __restrict__ wg_h, h16* __restrict__ wg_l,
                                             float* __restrict__ s,
                                             h16* __restrict__ wo_h, h16* __restrict__ wo_l) {
    const int o = blockIdx.x, lane = threadIdx.x;
    if (o < OC3) {
        float sum = 0.f;
#pragma unroll
        for (int j = 0; j < 8; ++j) {
            const int c = lane + j * 64;
            const float w = w_qkv[(size_t)o * CCH + c] * g_ln[c];
            const float ws = w * 64.f;
            const h16 hi = (h16)ws;
            wg_h[(size_t)o * CCH + c] = hi;
            wg_l[(size_t)o * CCH + c] = (h16)(ws - (float)hi);
            sum += w;
        }
        sum = waveReduceSum(sum);
        if (lane == 0) s[o] = sum;
    } else {
        const int r = o - OC3;
#pragma unroll
        for (int j = 0; j < 8; ++j) {
            const int c = lane + j * 64;
            const float ws = w_out[(size_t)r * CCH + c] * 64.f;
            const h16 hi = (h16)ws;
            wo_h[(size_t)r * CCH + c] = hi;
            wo_l[(size_t)r * CCH + c] = (h16)(ws - (float)hi);
        }
    }
}

// ---------------------------------------------------------------------------
// fp32 [16][512][4096] -> transposed fp16 [16][4096][512]
// + per-(channel-block, pixel) LN partial sums (deterministic 2-stage stats)
__global__ __launch_bounds__(256) void transpose_cvt(const float* __restrict__ src,
                                                     h16* __restrict__ dhi,
                                                     float* __restrict__ psum,
                                                     float* __restrict__ psq) {
    __shared__ float tile[64][65];
    __shared__ float ps1[4][64], ps2[4][64];
    const int b = blockIdx.z, c0 = blockIdx.y * 64, p0 = blockIdx.x * 64;
    const int t = threadIdx.x;
    const float* sb = src + ((size_t)b * CCH + c0) * HWN + p0;
    const int rc = t >> 4, cc4 = (t & 15) * 4;
#pragma unroll
    for (int ps = 0; ps < 4; ++ps) {
        const float4 v = *(const float4*)(sb + (size_t)(rc + ps * 16) * HWN + cc4);
        tile[rc + ps * 16][cc4 + 0] = v.x;
        tile[rc + ps * 16][cc4 + 1] = v.y;
        tile[rc + ps * 16][cc4 + 2] = v.z;
        tile[rc + ps * 16][cc4 + 3] = v.w;
    }
    __syncthreads();
    {
        const int q = t >> 6, px = t & 63;
        float s1 = 0.f, s2 = 0.f;
#pragma unroll
        for (int c = q * 16; c < q * 16 + 16; ++c) {
            const float v = tile[c][px];
            s1 += v; s2 += v * v;
        }
        ps1[q][px] = s1; ps2[q][px] = s2;
    }
    const int pr0 = t >> 3, cs = (t & 7) * 8;
#pragma unroll
    for (int ps = 0; ps < 2; ++ps) {
        const int pr = pr0 + ps * 32;
        f16x8 vh;
#pragma unroll
        for (int q = 0; q < 8; ++q) vh[q] = (h16)tile[cs + q][pr];
        const size_t o = ((size_t)b * HWN + p0 + pr) * CCH + c0 + cs;
        *(f16x8*)(dhi + o) = vh;
    }
    __syncthreads();
    if (t < 64) {
        const float s1 = ps1[0][t] + ps1[1][t] + ps1[2][t] + ps1[3][t];
        const float s2 = ps2[0][t] + ps2[1][t] + ps2[2][t] + ps2[3][t];
        const size_t gp = (size_t)b * HWN + p0 + t;
        psum[(size_t)(c0 >> 6) * NPIX + gp] = s1;
        psq [(size_t)(c0 >> 6) * NPIX + gp] = s2;
    }
}

__global__ __launch_bounds__(256) void ln_finish(const float* __restrict__ psum,
                                                 const float* __restrict__ psq,
                                                 float* __restrict__ mean,
                                                 float* __restrict__ rstd) {
    const int p = blockIdx.x * 256 + threadIdx.x;
    float s1 = 0.f, s2 = 0.f;
#pragma unroll
    for (int cb = 0; cb < 8; ++cb) {
        s1 += psum[(size_t)cb * NPIX + p];
        s2 += psq [(size_t)cb * NPIX + p];
    }
    const float m = s1 * (1.f / 512.f);
    float var = s2 * (1.f / 512.f) - m * m;
    var = fmaxf(var, 0.f);
    mean[p] = m;
    rstd[p] = rsqrtf(var + LN_EPS);
}

// ---------------------------------------------------------------------------
// QKV GEMM, 8-phase-style counted-vmcnt pipeline.
// Tile 128(ch) x 256(px), BK=64, K=512 (8 K-tiles), 8 waves (2M x 4N).
// LDS: 4 regions x 32KB ring; region(t,ks) = (2t+ks)&3. While computing tile t
// (regions 2t,2t+1 mod 4), tile t+1 stages into the other two (freed at t-1).
// Per K-tile: 4 phases (ksub, colhalf), 16 MFMA each; vmcnt(4) at phases 0/2
// (newest 4 outstanding = next half-tile group); vmcnt(0) only at last tile.
// fp16 split-2: acc += Ah*B + Al*B. Epilogue: fp16 rstd*(acc/64 - mean*s[o]).
__global__ __launch_bounds__(512, 1) void qkv_gemm8(const h16* __restrict__ Ahg,
                                                    const h16* __restrict__ Alg,
                                                    const h16* __restrict__ Bhg,
                                                    const float* __restrict__ sv,
                                                    const float* __restrict__ mean,
                                                    const float* __restrict__ rstd,
                                                    h16* __restrict__ qout) {
    __shared__ __align__(16) h16 lds[65536];   // 128 KiB
    const int tid = threadIdx.x;
    const int om = blockIdx.x * 128;
    const int by0 = blockIdx.y;
    const int by  = (by0 & 7) * 32 + (by0 >> 3);   // bijective XCD chunking (256%8==0)
    const int p0  = by * 256;

    // staging maps (linear dest = wave-uniform base + lane*16B; no swizzle:
    // [row][32k] h16 rows (64B) are already at the 8-access/bank b128 floor)
    const int srow = tid >> 2, ssl = (tid & 3) * 8;
    const size_t aoff  = (size_t)(om + srow) * CCH + ssl;
    const size_t boff0 = (size_t)(p0 + srow) * CCH + ssl;
    const size_t boff1 = (size_t)(p0 + 128 + srow) * CCH + ssl;

    const int lane = tid & 63;
    const int wv = tid >> 6;
    const int wm = (wv >> 2) * 64, wn = (wv & 3) * 64;
    const int lr = lane & 15, kg = lane >> 4;
    const int rbase_a = (wm + lr) * 32 + kg * 8;   // + i*512
    const int rbase_b = (wn + lr) * 32 + kg * 8;   // + ch*1024 + j*512

    f32x4 acc[4][4];
#pragma unroll
    for (int i = 0; i < 4; ++i)
#pragma unroll
        for (int j = 0; j < 4; ++j) acc[i][j] = {0.f, 0.f, 0.f, 0.f};

    f16x8 ah_[4], al_[4];

#define REG(r) (lds + (r) * 16384)
#define ST_A(T, KS)                                                      \
    do {                                                                 \
        const int r_ = (2 * (T) + (KS)) & 3;                             \
        const int kb_ = (T) * 64 + (KS) * 32;                            \
        gl_lds16(Ahg + aoff + kb_, REG(r_) + tid * 8);                   \
        gl_lds16(Alg + aoff + kb_, REG(r_) + 4096 + tid * 8);            \
    } while (0)
#define ST_B(T, KS)                                                      \
    do {                                                                 \
        const int r_ = (2 * (T) + (KS)) & 3;                             \
        const int kb_ = (T) * 64 + (KS) * 32;                            \
        gl_lds16(Bhg + boff0 + kb_, REG(r_) + 8192 + tid * 8);           \
        gl_lds16(Bhg + boff1 + kb_, REG(r_) + 12288 + tid * 8);          \
    } while (0)

#define PHASE(T, P, VM)                                                         \
    do {                                                                        \
        if ((VM) == 4) asm volatile("s_waitcnt vmcnt(4)" ::: "memory");         \
        if ((VM) == 0) asm volatile("s_waitcnt vmcnt(0)" ::: "memory");         \
        __builtin_amdgcn_sched_barrier(0);                                      \
        __builtin_amdgcn_s_barrier();                                           \
        __builtin_amdgcn_sched_barrier(0);                                      \
        const h16* Ra = REG((2 * (T) + ((P) >> 1)) & 3);                        \
        f16x8 bfr0, bfr1;                                                       \
        if (((P) & 1) == 0) {                                                   \
            _Pragma("unroll") for (int i = 0; i < 4; ++i) {                     \
                ah_[i] = *(const f16x8*)(Ra + rbase_a + i * 512);               \
                al_[i] = *(const f16x8*)(Ra + 4096 + rbase_a + i * 512);        \
            }                                                                   \
        }                                                                       \
        bfr0 = *(const f16x8*)(Ra + 8192 + rbase_b + ((P) & 1) * 1024);         \
        bfr1 = *(const f16x8*)(Ra + 8192 + rbase_b + ((P) & 1) * 1024 + 512);   \
        if ((T) < 7) {                                                          \
            if ((P) == 0) ST_A((T) + 1, 0);                                     \
            else if ((P) == 1) ST_B((T) + 1, 0);                                \
            else if ((P) == 2) ST_A((T) + 1, 1);                                \
            else ST_B((T) + 1, 1);                                              \
        }                                                                       \
        __builtin_amdgcn_s_setprio(1);                                          \
        _Pragma("unroll") for (int i = 0; i < 4; ++i) {                         \
            acc[i][((P) & 1) * 2 + 0] = __builtin_amdgcn_mfma_f32_16x16x32_f16( \
                ah_[i], bfr0, acc[i][((P) & 1) * 2 + 0], 0, 0, 0);              \
            acc[i][((P) & 1) * 2 + 0] = __builtin_amdgcn_mfma_f32_16x16x32_f16( \
                al_[i], bfr0, acc[i][((P) & 1) * 2 + 0], 0, 0, 0);              \
            acc[i][((P) & 1) * 2 + 1] = __builtin_amdgcn_mfma_f32_16x16x32_f16( \
                ah_[i], bfr1, acc[i][((P) & 1) * 2 + 1], 0, 0, 0);              \
            acc[i][((P) & 1) * 2 + 1] = __builtin_amdgcn_mfma_f32_16x16x32_f16( \
                al_[i], bfr1, acc[i][((P) & 1) * 2 + 1], 0, 0, 0);              \
        }                                                                       \
        __builtin_amdgcn_s_setprio(0);                                          \
    } while (0)

#define TILE(T, VM2) \
    PHASE(T, 0, 4);  \
    PHASE(T, 1, 9);  \
    PHASE(T, 2, VM2);\
    PHASE(T, 3, 9)

    // prologue: tile 0 fully staged (groups ordered ks0 then ks1)
    ST_A(0, 0); ST_B(0, 0);
    ST_A(0, 1); ST_B(0, 1);

    TILE(0, 4); TILE(1, 4); TILE(2, 4); TILE(3, 4);
    TILE(4, 4); TILE(5, 4); TILE(6, 4); TILE(7, 0);

#undef TILE
#undef PHASE
#undef ST_A
#undef ST_B
#undef REG

    asm volatile("" ::: "memory");   // keep epilogue loads below the pipeline

    const int b = p0 >> 12, hw0 = p0 & 4095;
    float mn[4], rs[4];
#pragma unroll
    for (int j = 0; j < 4; ++j) {
        const int p = p0 + wn + j * 16 + lr;
        mn[j] = mean[p]; rs[j] = rstd[p];
    }
#pragma unroll
    for (int i = 0; i < 4; ++i)
#pragma unroll
        for (int r = 0; r < 4; ++r) {
            const int o = om + wm + i * 16 + kg * 4 + r;
            const float so = sv[o];
            h16* dst = qout + ((size_t)b * OC3 + o) * HWN;
#pragma unroll
            for (int j = 0; j < 4; ++j) {
                const int hw = hw0 + wn + j * 16 + lr;
                dst[hw] = (h16)(rs[j] * (acc[i][j][r] * (1.f / 64.f) - mn[j] * so));
            }
        }
}

// ---------------------------------------------------------------------------
// per-row (over n=4096) max and 1/sum(exp) for k (fp16 input, one wave/row)
__global__ __launch_bounds__(256) void k_stats(const h16* __restrict__ qkv16,
                                               float* __restrict__ kmax,
                                               float* __restrict__ ksc) {
    const int row = blockIdx.x * 4 + (threadIdx.x >> 6);
    const int bh = row >> 6, r = row & 63;
    const int b = bh >> 3, h = bh & 7;
    const h16* rp = qkv16 + ((size_t)b * OC3 + CCH + h * 64 + r) * HWN;
    const int lane = threadIdx.x & 63;
    f16x8 kv[8];
#pragma unroll
    for (int j = 0; j < 8; ++j) kv[j] = *(const f16x8*)(rp + lane * 8 + j * 512);
    float mx = -1e30f;
#pragma unroll
    for (int j = 0; j < 8; ++j)
#pragma unroll
        for (int u = 0; u < 8; ++u) mx = fmaxf(mx, (float)kv[j][u]);
    mx = waveReduceMax(mx);
    float sum = 0.f;
#pragma unroll
    for (int j = 0; j < 8; ++j)
#pragma unroll
        for (int u = 0; u < 8; ++u) sum += __expf((float)kv[j][u] - mx);
    sum = waveReduceSum(sum);
    if (lane == 0) {
        kmax[row] = mx;
        ksc[row]  = 1.0f / sum;
    }
}

// ---------------------------------------------------------------------------
// partial context over an n-chunk of 512: ctp = sum_n ktilde[d,n]*V[e,n]
__global__ __launch_bounds__(256) void ctx_partial(const h16* __restrict__ qkv16,
                                                   const float* __restrict__ kmax,
                                                   const float* __restrict__ ksc,
                                                   float* __restrict__ ctp) {
    __shared__ float kt[64][68];
    __shared__ float vt[64][68];
    __shared__ float kmx[64], kss[64];

    const int bh = blockIdx.y, ci = blockIdx.x;
    const int b = bh >> 3, h = bh & 7;
    const h16* kb = qkv16 + ((size_t)b * OC3 + CCH  + h * 64) * HWN;
    const h16* vb = qkv16 + ((size_t)b * OC3 + 1024 + h * 64) * HWN;
    const int tid = threadIdx.x;
    if (tid < 64) { kmx[tid] = kmax[bh * 64 + tid]; kss[tid] = ksc[bh * 64 + tid]; }

    const int d  = tid >> 2;
    const int td = tid & 15, te = tid >> 4;
    float acc[4][4];
#pragma unroll
    for (int i = 0; i < 4; ++i)
#pragma unroll
        for (int j = 0; j < 4; ++j) acc[i][j] = 0.f;

    for (int t = 0; t < 8; ++t) {
        const int n0 = ci * 512 + t * 64;
        __syncthreads();
        const float m = kmx[d], sc = kss[d];
#pragma unroll
        for (int jj = 0; jj < 2; ++jj) {
            const int nn = (tid & 3) * 8 + jj * 32;
            const f16x8 kv = *(const f16x8*)(kb + (size_t)d * HWN + n0 + nn);
            const f16x8 vv = *(const f16x8*)(vb + (size_t)d * HWN + n0 + nn);
#pragma unroll
            for (int u = 0; u < 8; ++u) {
                kt[nn + u][d] = __expf((float)kv[u] - m) * sc;
                vt[nn + u][d] = (float)vv[u];
            }
        }
        __syncthreads();
#pragma unroll
        for (int nn = 0; nn < 64; ++nn) {
            float kf[4], vf[4];
            *(float4*)kf = *(const float4*)&kt[nn][td * 4];
            *(float4*)vf = *(const float4*)&vt[nn][te * 4];
#pragma unroll
            for (int i = 0; i < 4; ++i)
#pragma unroll
                for (int j = 0; j < 4; ++j)
                    acc[i][j] = fmaf(kf[i], vf[j], acc[i][j]);
        }
    }
    float* dst = ctp + ((size_t)bh * 8 + ci) * 4096;
#pragma unroll
    for (int i = 0; i < 4; ++i) {
        const float4 o4 = make_float4(acc[i][0], acc[i][1], acc[i][2], acc[i][3]);
        *(float4*)(dst + (td * 4 + i) * 64 + te * 4) = o4;
    }
}

__global__ __launch_bounds__(256) void ctx_reduce(const float* __restrict__ ctp,
                                                  float* __restrict__ ct) {
    const int bh = blockIdx.x;
    const int tid = threadIdx.x;
    const float* src = ctp + (size_t)bh * 8 * 4096;
    float* dst = ct + (size_t)bh * 4096;
    for (int e4 = tid * 4; e4 < 4096; e4 += 1024) {
        float4 sum = make_float4(0.f, 0.f, 0.f, 0.f);
#pragma unroll
        for (int ci = 0; ci < 8; ++ci) {
            const float4 v = *(const float4*)(src + (size_t)ci * 4096 + e4);
            sum.x += v.x; sum.y += v.y; sum.z += v.z; sum.w += v.w;
        }
        *(float4*)(dst + e4) = sum;
    }
}

// ---------------------------------------------------------------------------
// q-softmax(d) * (512*SCALE), out'[e,n] = sum_d ct[d,e]*qtilde[d,n];
// writes at = fp16, TRANSPOSED to [b*4096+n][512] (in ws).
__global__ __launch_bounds__(256) void attn_out(const h16* __restrict__ qkv16,
                                                const float* __restrict__ ct,
                                                h16* __restrict__ at) {
    __shared__ float cts[64][68];
    __shared__ float qt[64][68];

    const int bh = blockIdx.y, ci = blockIdx.x;
    const int b = bh >> 3, h = bh & 7;
    const h16* qb = qkv16 + ((size_t)b * OC3 + h * 64) * HWN;
    const int tid = threadIdx.x;

    for (int i4 = tid * 4; i4 < 4096; i4 += 1024) {
        const float4 v = *(const float4*)(ct + (size_t)bh * 4096 + i4);
        *(float4*)&cts[i4 >> 6][i4 & 63] = v;
    }

    const int d  = tid >> 2;
    const int te = tid & 15, tn = tid >> 4;
    const int rn = tid >> 2, d0q = (tid & 3) * 16;

    for (int t = 0; t < 8; ++t) {
        const int n0 = ci * 512 + t * 64;
        __syncthreads();
#pragma unroll
        for (int jj = 0; jj < 2; ++jj) {
            const int nn = (tid & 3) * 8 + jj * 32;
            const f16x8 qv = *(const f16x8*)(qb + (size_t)d * HWN + n0 + nn);
#pragma unroll
            for (int u = 0; u < 8; ++u) qt[nn + u][d] = (float)qv[u];
        }
        __syncthreads();
        {
            float mx = -1e30f;
#pragma unroll
            for (int dd = 0; dd < 16; ++dd) mx = fmaxf(mx, qt[rn][d0q + dd]);
            mx = fmaxf(mx, __shfl_xor(mx, 1));
            mx = fmaxf(mx, __shfl_xor(mx, 2));
            float sm = 0.f;
#pragma unroll
            for (int dd = 0; dd < 16; ++dd) sm += __expf(qt[rn][d0q + dd] - mx);
            sm += __shfl_xor(sm, 1);
            sm += __shfl_xor(sm, 2);
            const float sc = 512.f * QSCALE / sm;
#pragma unroll
            for (int dd = 0; dd < 16; ++dd)
                qt[rn][d0q + dd] = __expf(qt[rn][d0q + dd] - mx) * sc;
        }
        __syncthreads();
        float acc[4][4];
#pragma unroll
        for (int i = 0; i < 4; ++i)
#pragma unroll
            for (int j = 0; j < 4; ++j) acc[i][j] = 0.f;
#pragma unroll
        for (int dd = 0; dd < 64; ++dd) {
            float cv[4];
            *(float4*)cv = *(const float4*)&cts[dd][te * 4];
            const float q0 = qt[tn * 4 + 0][dd];
            const float q1 = qt[tn * 4 + 1][dd];
            const float q2 = qt[tn * 4 + 2][dd];
            const float q3 = qt[tn * 4 + 3][dd];
#pragma unroll
            for (int i = 0; i < 4; ++i) {
                acc[i][0] = fmaf(cv[i], q0, acc[i][0]);
                acc[i][1] = fmaf(cv[i], q1, acc[i][1]);
                acc[i][2] = fmaf(cv[i], q2, acc[i][2]);
                acc[i][3] = fmaf(cv[i], q3, acc[i][3]);
            }
        }
        __syncthreads();
#pragma unroll
        for (int i = 0; i < 4; ++i)
#pragma unroll
            for (int j = 0; j < 4; ++j)
                qt[tn * 4 + j][te * 4 + i] = acc[i][j];
        __syncthreads();
        {
            const int px = tid >> 2, e0 = (tid & 3) * 16;
            f16x8 vh0, vh1;
#pragma unroll
            for (int u = 0; u < 8; ++u) {
                vh0[u] = (h16)qt[px][e0 + u];
                vh1[u] = (h16)qt[px][e0 + 8 + u];
            }
            const size_t o = ((size_t)b * HWN + n0 + px) * CCH + h * 64 + e0;
            *(f16x8*)(at + o)     = vh0;
            *(f16x8*)(at + o + 8) = vh1;
        }
    }
}

// ---------------------------------------------------------------------------
// Fused out-GEMM + channel LN + residual. split-2: (wo_hi,at),(wo_lo,at).
__global__ __launch_bounds__(512) void out_fused(const h16* __restrict__ wo_hi,
                                                 const h16* __restrict__ wo_lo,
                                                 const h16* __restrict__ at,
                                                 const float* __restrict__ b_out,
                                                 const float* __restrict__ g_out,
                                                 const float* __restrict__ x,
                                                 float* __restrict__ out) {
    __shared__ __align__(16) h16 Alds[512 * 32];
    __shared__ __align__(16) h16 Blds[128 * 32];
    __shared__ float red1[4][128], red2[4][128];
    __shared__ float mnS[128], rsS[128];

    const int tid = threadIdx.x;
    const int p0 = blockIdx.x * 128;
    const int b = p0 >> 12, hw0 = p0 & 4095;

    const int trow = tid >> 2;
    const int skh  = ((tid & 3) ^ (trow & 3)) * 8;
    const size_t aoff = (size_t)trow * CCH + skh;
    const size_t boff = (size_t)p0 * CCH + aoff;
    const int wofs = (tid >> 6) * 512;

    const int wv = tid >> 6;
    const int wm = (wv >> 1) * 128, wn = (wv & 1) * 64;
    const int lane = tid & 63;
    const int lr = lane & 15, kg = lane >> 4;
    const int swz = (kg ^ (lr & 3)) * 8;

    f32x4 acc[8][4];
#pragma unroll
    for (int i = 0; i < 8; ++i)
#pragma unroll
        for (int j = 0; j < 4; ++j) acc[i][j] = {0.f, 0.f, 0.f, 0.f};

#define STAGEF(S)                                                       \
    do {                                                                \
        const int kc_ = ((S) & 15) * 32;                                \
        const h16* As_ = ((S) < 16) ? wo_hi : wo_lo;                    \
        gl_lds16(As_ + aoff + kc_,               Alds + wofs);          \
        gl_lds16(As_ + aoff + kc_ + 128 * CCH,   Alds + 4096 + wofs);   \
        gl_lds16(As_ + aoff + kc_ + 256 * CCH,   Alds + 8192 + wofs);   \
        gl_lds16(As_ + aoff + kc_ + 384 * CCH,   Alds + 12288 + wofs);  \
        gl_lds16(at + boff + kc_,                Blds + wofs);          \
    } while (0)

    STAGEF(0);
#pragma unroll 1
    for (int s = 0; s < 32; ++s) {
        __syncthreads();
        f16x8 af[8], bf[4];
#pragma unroll
        for (int i = 0; i < 8; ++i)
            af[i] = *(const f16x8*)(Alds + (wm + i * 16 + lr) * 32 + swz);
#pragma unroll
        for (int j = 0; j < 4; ++j)
            bf[j] = *(const f16x8*)(Blds + (wn + j * 16 + lr) * 32 + swz);
        __syncthreads();
        if (s < 31) STAGEF(s + 1);
#pragma unroll
        for (int i = 0; i < 8; ++i)
#pragma unroll
            for (int j = 0; j < 4; ++j)
                acc[i][j] = __builtin_amdgcn_mfma_f32_16x16x32_f16(af[i], bf[j], acc[i][j], 0, 0, 0);
    }
#undef STAGEF

#pragma unroll
    for (int i = 0; i < 8; ++i) {
        const int o = wm + i * 16 + kg * 4;
        const float4 bb = *(const float4*)(b_out + o);
#pragma unroll
        for (int j = 0; j < 4; ++j) {
            acc[i][j][0] = acc[i][j][0] * (1.f / 134217728.f) + bb.x;
            acc[i][j][1] = acc[i][j][1] * (1.f / 134217728.f) + bb.y;
            acc[i][j][2] = acc[i][j][2] * (1.f / 134217728.f) + bb.z;
            acc[i][j][3] = acc[i][j][3] * (1.f / 134217728.f) + bb.w;
        }
    }
    float s1[4], s2[4];
#pragma unroll
    for (int j = 0; j < 4; ++j) {
        s1[j] = 0.f; s2[j] = 0.f;
#pragma unroll
        for (int i = 0; i < 8; ++i)
#pragma unroll
            for (int r = 0; r < 4; ++r) {
                const float v = acc[i][j][r];
                s1[j] += v; s2[j] += v * v;
            }
        s1[j] += __shfl_xor(s1[j], 16); s1[j] += __shfl_xor(s1[j], 32);
        s2[j] += __shfl_xor(s2[j], 16); s2[j] += __shfl_xor(s2[j], 32);
    }
    if (kg == 0) {
#pragma unroll
        for (int j = 0; j < 4; ++j) {
            red1[wv >> 1][wn + j * 16 + lr] = s1[j];
            red2[wv >> 1][wn + j * 16 + lr] = s2[j];
        }
    }
    __syncthreads();
    if (tid < 128) {
        const float S1 = red1[0][tid] + red1[1][tid] + red1[2][tid] + red1[3][tid];
        const float S2 = red2[0][tid] + red2[1][tid] + red2[2][tid] + red2[3][tid];
        const float m = S1 * (1.f / 512.f);
        float var = S2 * (1.f / 512.f) - m * m;
        var = fmaxf(var, 0.f);
        mnS[tid] = m;
        rsS[tid] = rsqrtf(var + LN_EPS);
    }
    __syncthreads();
    float mj[4], rj[4];
#pragma unroll
    for (int j = 0; j < 4; ++j) {
        const int px = wn + j * 16 + lr;
        mj[j] = mnS[px]; rj[j] = rsS[px];
    }
#pragma unroll
    for (int i = 0; i < 8; ++i) {
        const int o = wm + i * 16 + kg * 4;
        const float4 gg = *(const float4*)(g_out + o);
#pragma unroll
        for (int r = 0; r < 4; ++r) {
            const float g = (r == 0) ? gg.x : (r == 1) ? gg.y : (r == 2) ? gg.z : gg.w;
            const float* xr = x + ((size_t)b * CCH + o + r) * HWN + hw0 + wn;
            float* dr = out + ((size_t)b * CCH + o + r) * HWN + hw0 + wn;
#pragma unroll
            for (int j = 0; j < 4; ++j) {
                const int c = j * 16 + lr;
                dr[c] = (acc[i][j][r] - mj[j]) * rj[j] * g + xr[c];
            }
        }
    }
}

// ---------------------------------------------------------------------------
extern "C" void kernel_launch(void* const* d_in, const int* in_sizes, int n_in,
                              void* d_out, int out_size, void* d_ws, size_t ws_size,
                              hipStream_t stream) {
    (void)in_sizes; (void)n_in; (void)out_size;
    const float* x     = (const float*)d_in[0];
    const float* w_qkv = (const float*)d_in[1];
    const float* w_out = (const float*)d_in[2];
    const float* b_out = (const float*)d_in[3];
    const float* g_out = (const float*)d_in[4];
    const float* g_ln  = (const float*)d_in[5];
    float* out = (float*)d_out;
    float* ws  = (float*)d_ws;

    float* mean = ws;                       // 65536
    float* rstd = mean + NPIX;              // 65536
    float* s    = rstd + NPIX;              // 1536
    float* kmax = s + OC3;                  // 8192
    float* ksc  = kmax + 8192;              // 8192
    float* ct   = ksc + 8192;               // 524288
    float* ctp  = ct + 524288;              // 4194304 (psum/psq alias: pre-ctx use)
    float* psum = ctp;                      // 524288
    float* psq  = psum + 524288;            // 524288
    h16*  wg_hi = (h16*)(ctp + 4194304);    // 786432 halfs
    h16*  wg_lo = wg_hi + 786432;
    h16*  wo_hi = wg_lo + 786432;           // 262144 halfs
    h16*  wo_lo = wo_hi + 262144;
    h16*  qkv16 = wo_lo + 262144;           // 100663296 halfs (fp16 q,k,v)
    h16*  at    = qkv16 + 100663296;        // 33554432 halfs (attn out, transposed)
    // alias of d_out: xt dead after qkv_gemm8 (out_fused is sole d_out writer)
    h16*  xt_hi = (h16*)d_out;

    const size_t need = 73025024ULL * 4ULL;   // ~292.1 MB
    if (ws_size < need) return;

    prep_w       <<<2048, 64, 0, stream>>>(w_qkv, g_ln, w_out,
                                           wg_hi, wg_lo, s, wo_hi, wo_lo);
    transpose_cvt<<<dim3(64, 8, 16), 256, 0, stream>>>(x, xt_hi, psum, psq);
    ln_finish    <<<NPIX / 256, 256, 0, stream>>>(psum, psq, mean, rstd);
    qkv_gemm8    <<<dim3(12, 256), 512, 0, stream>>>(wg_hi, wg_lo, xt_hi,
                                                     s, mean, rstd, qkv16);
    k_stats      <<<2048, 256, 0, stream>>>(qkv16, kmax, ksc);
    ctx_partial  <<<dim3(8, 128), 256, 0, stream>>>(qkv16, kmax, ksc, ctp);
    ctx_reduce   <<<128, 256, 0, stream>>>(ctp, ct);
    attn_out     <<<dim3(8, 128), 256, 0, stream>>>(qkv16, ct, at);
    out_fused    <<<512, 512, 0, stream>>>(wo_hi, wo_lo, at,
                                           b_out, g_out, x, out);
}

// Round 12
// 575.126 us; speedup vs baseline: 1.0115x; 1.0115x over previous
//
#include <hip/hip_runtime.h>
#include <math.h>

#define CCH    512
#define HWN    4096
#define NPIX   65536
#define OC3    1536
#define QSCALE 0.125f
#define LN_EPS 1e-5f

typedef _Float16 h16;
typedef h16  f16x8 __attribute__((ext_vector_type(8)));
typedef float f32x4 __attribute__((ext_vector_type(4)));

__device__ __forceinline__ float waveReduceSum(float v) {
#pragma unroll
    for (int off = 32; off; off >>= 1) v += __shfl_xor(v, off);
    return v;
}
__device__ __forceinline__ float waveReduceMax(float v) {
#pragma unroll
    for (int off = 32; off; off >>= 1) v = fmaxf(v, __shfl_xor(v, off));
    return v;
}

__device__ __forceinline__ void gl_lds16(const void* g, void* l) {
    __builtin_amdgcn_global_load_lds((const __attribute__((address_space(1))) void*)g,
                                     (__attribute__((address_space(3))) void*)l, 16, 0, 0);
}

// ---------------------------------------------------------------------------
// merged weight prep: o<1536 -> wg (w_qkv*g_ln, x64, hi/lo) + row-sum s;
//                     o>=1536 -> wo (w_out, x64, hi/lo)
__global__ __launch_bounds__(64) void prep_w(const float* __restrict__ w_qkv,
                                             const float* __restrict__ g_ln,
                                             const float* __restrict__ w_out,
                                             h16* __restrict__ wg_h, h16* __restrict__ wg_l,
                                             float* __restrict__ s,
                                             h16* __restrict__ wo_h, h16* __restrict__ wo_l) {
    const int o = blockIdx.x, lane = threadIdx.x;
    if (o < OC3) {
        float sum = 0.f;
#pragma unroll
        for (int j = 0; j < 8; ++j) {
            const int c = lane + j * 64;
            const float w = w_qkv[(size_t)o * CCH + c] * g_ln[c];
            const float ws = w * 64.f;
            const h16 hi = (h16)ws;
            wg_h[(size_t)o * CCH + c] = hi;
            wg_l[(size_t)o * CCH + c] = (h16)(ws - (float)hi);
            sum += w;
        }
        sum = waveReduceSum(sum);
        if (lane == 0) s[o] = sum;
    } else {
        const int r = o - OC3;
#pragma unroll
        for (int j = 0; j < 8; ++j) {
            const int c = lane + j * 64;
            const float ws = w_out[(size_t)r * CCH + c] * 64.f;
            const h16 hi = (h16)ws;
            wo_h[(size_t)r * CCH + c] = hi;
            wo_l[(size_t)r * CCH + c] = (h16)(ws - (float)hi);
        }
    }
}

// ---------------------------------------------------------------------------
// fp32 [16][512][4096] -> transposed fp16 [16][4096][512]
// + per-(channel-block, pixel) LN partial sums (deterministic 2-stage stats)
__global__ __launch_bounds__(256) void transpose_cvt(const float* __restrict__ src,
                                                     h16* __restrict__ dhi,
                                                     float* __restrict__ psum,
                                                     float* __restrict__ psq) {
    __shared__ float tile[64][65];
    __shared__ float ps1[4][64], ps2[4][64];
    const int b = blockIdx.z, c0 = blockIdx.y * 64, p0 = blockIdx.x * 64;
    const int t = threadIdx.x;
    const float* sb = src + ((size_t)b * CCH + c0) * HWN + p0;
    const int rc = t >> 4, cc4 = (t & 15) * 4;
#pragma unroll
    for (int ps = 0; ps < 4; ++ps) {
        const float4 v = *(const float4*)(sb + (size_t)(rc + ps * 16) * HWN + cc4);
        tile[rc + ps * 16][cc4 + 0] = v.x;
        tile[rc + ps * 16][cc4 + 1] = v.y;
        tile[rc + ps * 16][cc4 + 2] = v.z;
        tile[rc + ps * 16][cc4 + 3] = v.w;
    }
    __syncthreads();
    {
        const int q = t >> 6, px = t & 63;
        float s1 = 0.f, s2 = 0.f;
#pragma unroll
        for (int c = q * 16; c < q * 16 + 16; ++c) {
            const float v = tile[c][px];
            s1 += v; s2 += v * v;
        }
        ps1[q][px] = s1; ps2[q][px] = s2;
    }
    const int pr0 = t >> 3, cs = (t & 7) * 8;
#pragma unroll
    for (int ps = 0; ps < 2; ++ps) {
        const int pr = pr0 + ps * 32;
        f16x8 vh;
#pragma unroll
        for (int q = 0; q < 8; ++q) vh[q] = (h16)tile[cs + q][pr];
        const size_t o = ((size_t)b * HWN + p0 + pr) * CCH + c0 + cs;
        *(f16x8*)(dhi + o) = vh;
    }
    __syncthreads();
    if (t < 64) {
        const float s1 = ps1[0][t] + ps1[1][t] + ps1[2][t] + ps1[3][t];
        const float s2 = ps2[0][t] + ps2[1][t] + ps2[2][t] + ps2[3][t];
        const size_t gp = (size_t)b * HWN + p0 + t;
        psum[(size_t)(c0 >> 6) * NPIX + gp] = s1;
        psq [(size_t)(c0 >> 6) * NPIX + gp] = s2;
    }
}

// ---------------------------------------------------------------------------
// QKV GEMM: 128x128 MFMA, fp16 split-2 (A hi/lo x B hi), K=512. A = wg (x64).
// LN stats finished in-block from psum/psq (ln_finish fused).
// out fp16 = rstd[p]*(acc/64 - mean[p]*s[o]).
__global__ __launch_bounds__(256) void qkv_gemm(const h16* __restrict__ Ahg,
                                                const h16* __restrict__ Alg,
                                                const h16* __restrict__ Bhg,
                                                const float* __restrict__ sv,
                                                const float* __restrict__ psum,
                                                const float* __restrict__ psq,
                                                h16* __restrict__ qout) {
    __shared__ __align__(16) h16 Ah[4096], Al[4096], Bh[4096];
    __shared__ float mnS[128], rsS[128];
    const int tid = threadIdx.x;
    const int om = blockIdx.x * 128;
    const int by0 = blockIdx.y;
    const int by  = (by0 & 7) * 64 + (by0 >> 3);   // bijective XCD chunking (512%8==0)
    const int p0  = by * 128;

    const int srow = tid >> 2;
    const int skh  = ((tid & 3) ^ (srow & 3)) * 8;
    const size_t a0 = (size_t)(om + srow) * CCH + skh;
    const size_t b0 = (size_t)(p0 + srow) * CCH + skh;
    const int wofs = (tid >> 6) * 512;

    const int lane = tid & 63;
    const int wv = tid >> 6;
    const int wm = (wv >> 1) * 64, wn = (wv & 1) * 64;
    const int lr = lane & 15, kg = lane >> 4;
    const int swz = (kg ^ (lr & 3)) * 8;

    f32x4 acc[4][4];
#pragma unroll
    for (int i = 0; i < 4; ++i)
#pragma unroll
        for (int j = 0; j < 4; ++j) acc[i][j] = {0.f, 0.f, 0.f, 0.f};

#define STAGE(KC)                                               \
    do {                                                        \
        gl_lds16(Ahg + a0 + (KC), Ah + wofs);                   \
        gl_lds16(Ahg + a0 + (KC) + 64 * CCH, Ah + 2048 + wofs); \
        gl_lds16(Alg + a0 + (KC), Al + wofs);                   \
        gl_lds16(Alg + a0 + (KC) + 64 * CCH, Al + 2048 + wofs); \
        gl_lds16(Bhg + b0 + (KC), Bh + wofs);                   \
        gl_lds16(Bhg + b0 + (KC) + 64 * CCH, Bh + 2048 + wofs); \
    } while (0)

    STAGE(0);
    // fused ln_finish: stats for this block's 128 pixels (coalesced reads,
    // overlapped with tile-0 staging; loop barriers make mnS visible to epilogue)
    if (tid < 128) {
        const int gp = p0 + tid;
        float s1 = 0.f, s2 = 0.f;
#pragma unroll
        for (int cb = 0; cb < 8; ++cb) {
            s1 += psum[(size_t)cb * NPIX + gp];
            s2 += psq [(size_t)cb * NPIX + gp];
        }
        const float m = s1 * (1.f / 512.f);
        float var = s2 * (1.f / 512.f) - m * m;
        var = fmaxf(var, 0.f);
        mnS[tid] = m;
        rsS[tid] = rsqrtf(var + LN_EPS);
    }

#pragma unroll 1
    for (int kc = 0; kc < 512; kc += 32) {
        __syncthreads();
        f16x8 ah[4], al[4], bh[4];
#pragma unroll
        for (int i = 0; i < 4; ++i) {
            const int ra = (wm + i * 16 + lr) * 32 + swz;
            ah[i] = *(const f16x8*)(Ah + ra);
            al[i] = *(const f16x8*)(Al + ra);
            const int rb = (wn + i * 16 + lr) * 32 + swz;
            bh[i] = *(const f16x8*)(Bh + rb);
        }
        __syncthreads();
        if (kc + 32 < 512) STAGE(kc + 32);
#pragma unroll
        for (int i = 0; i < 4; ++i)
#pragma unroll
            for (int j = 0; j < 4; ++j) {
                acc[i][j] = __builtin_amdgcn_mfma_f32_16x16x32_f16(ah[i], bh[j], acc[i][j], 0, 0, 0);
                acc[i][j] = __builtin_amdgcn_mfma_f32_16x16x32_f16(al[i], bh[j], acc[i][j], 0, 0, 0);
            }
    }
#undef STAGE

    const int b = p0 >> 12, hw0 = p0 & 4095;
    float mn[4], rs[4];
#pragma unroll
    for (int j = 0; j < 4; ++j) {
        const int px = wn + j * 16 + lr;
        mn[j] = mnS[px]; rs[j] = rsS[px];
    }
#pragma unroll
    for (int i = 0; i < 4; ++i)
#pragma unroll
        for (int r = 0; r < 4; ++r) {
            const int o = om + wm + i * 16 + kg * 4 + r;
            const float so = sv[o];
            h16* dst = qout + ((size_t)b * OC3 + o) * HWN;
#pragma unroll
            for (int j = 0; j < 4; ++j) {
                const int hw = hw0 + wn + j * 16 + lr;
                dst[hw] = (h16)(rs[j] * (acc[i][j][r] * (1.f / 64.f) - mn[j] * so));
            }
        }
}

// ---------------------------------------------------------------------------
// partial context over an n-chunk of 512 with chunk-local softmax max:
// pass 1: m_loc[d] = max over chunk; pass 2 (k L2-warm): pt = sum exp(k-m_loc)*v,
// z[d] = sum exp(k-m_loc). Output per (bh,ci): [64*64 pt][64 z][64 m].
__global__ __launch_bounds__(256) void ctx_partial(const h16* __restrict__ qkv16,
                                                   float* __restrict__ ctp) {
    __shared__ float kt[64][68];
    __shared__ float vt[64][68];

    const int bh = blockIdx.y, ci = blockIdx.x;
    const int b = bh >> 3, h = bh & 7;
    const h16* kb = qkv16 + ((size_t)b * OC3 + CCH  + h * 64) * HWN;
    const h16* vb = qkv16 + ((size_t)b * OC3 + 1024 + h * 64) * HWN;
    const int tid = threadIdx.x;

    const int d  = tid >> 2;
    const int td = tid & 15, te = tid >> 4;

    // pass 1: chunk-local row max (4 threads/row, shfl-combined)
    float mx = -1e30f;
    for (int t = 0; t < 8; ++t) {
        const int n0 = ci * 512 + t * 64;
#pragma unroll
        for (int jj = 0; jj < 2; ++jj) {
            const int nn = (tid & 3) * 8 + jj * 32;
            const f16x8 kv = *(const f16x8*)(kb + (size_t)d * HWN + n0 + nn);
#pragma unroll
            for (int u = 0; u < 8; ++u) mx = fmaxf(mx, (float)kv[u]);
        }
    }
    mx = fmaxf(mx, __shfl_xor(mx, 1));
    mx = fmaxf(mx, __shfl_xor(mx, 2));

    float zt = 0.f;
    float acc[4][4];
#pragma unroll
    for (int i = 0; i < 4; ++i)
#pragma unroll
        for (int j = 0; j < 4; ++j) acc[i][j] = 0.f;

    for (int t = 0; t < 8; ++t) {
        const int n0 = ci * 512 + t * 64;
        __syncthreads();
#pragma unroll
        for (int jj = 0; jj < 2; ++jj) {
            const int nn = (tid & 3) * 8 + jj * 32;
            const f16x8 kv = *(const f16x8*)(kb + (size_t)d * HWN + n0 + nn);
            const f16x8 vv = *(const f16x8*)(vb + (size_t)d * HWN + n0 + nn);
#pragma unroll
            for (int u = 0; u < 8; ++u) {
                const float e = __expf((float)kv[u] - mx);
                zt += e;
                kt[nn + u][d] = e;
                vt[nn + u][d] = (float)vv[u];
            }
        }
        __syncthreads();
#pragma unroll
        for (int nn = 0; nn < 64; ++nn) {
            float kf[4], vf[4];
            *(float4*)kf = *(const float4*)&kt[nn][td * 4];
            *(float4*)vf = *(const float4*)&vt[nn][te * 4];
#pragma unroll
            for (int i = 0; i < 4; ++i)
#pragma unroll
                for (int j = 0; j < 4; ++j)
                    acc[i][j] = fmaf(kf[i], vf[j], acc[i][j]);
        }
    }
    zt += __shfl_xor(zt, 1);
    zt += __shfl_xor(zt, 2);

    float* dst = ctp + ((size_t)bh * 8 + ci) * 4224;
#pragma unroll
    for (int i = 0; i < 4; ++i) {
        const float4 o4 = make_float4(acc[i][0], acc[i][1], acc[i][2], acc[i][3]);
        *(float4*)(dst + (td * 4 + i) * 64 + te * 4) = o4;
    }
    if ((tid & 3) == 0) {
        dst[4096 + d] = zt;
        dst[4160 + d] = mx;
    }
}

// ---------------------------------------------------------------------------
// combine 8 chunk partials with exp(m_loc - M) rescale, normalize:
// ct[d][e] = sum_ci w_ci*pt_ci[d][e] / sum_ci w_ci*z_ci[d],  w = exp(m_loc-M)
__global__ __launch_bounds__(256) void ctx_reduce(const float* __restrict__ ctp,
                                                  float* __restrict__ ct) {
    __shared__ float w[8][64];
    __shared__ float rz[64];
    const int bh = blockIdx.x;
    const int tid = threadIdx.x;
    const float* src = ctp + (size_t)bh * 8 * 4224;
    if (tid < 64) {
        float M = -1e30f;
#pragma unroll
        for (int ci = 0; ci < 8; ++ci)
            M = fmaxf(M, src[(size_t)ci * 4224 + 4160 + tid]);
        float Z = 0.f;
#pragma unroll
        for (int ci = 0; ci < 8; ++ci) {
            const float ww = __expf(src[(size_t)ci * 4224 + 4160 + tid] - M);
            w[ci][tid] = ww;
            Z += ww * src[(size_t)ci * 4224 + 4096 + tid];
        }
        rz[tid] = 1.f / Z;
    }
    __syncthreads();
    float* dst = ct + (size_t)bh * 4096;
    for (int e4 = tid * 4; e4 < 4096; e4 += 1024) {
        const int d = e4 >> 6;
        float4 sum = make_float4(0.f, 0.f, 0.f, 0.f);
#pragma unroll
        for (int ci = 0; ci < 8; ++ci) {
            const float4 v = *(const float4*)(src + (size_t)ci * 4224 + e4);
            const float ww = w[ci][d];
            sum.x += ww * v.x; sum.y += ww * v.y;
            sum.z += ww * v.z; sum.w += ww * v.w;
        }
        const float r = rz[d];
        sum.x *= r; sum.y *= r; sum.z *= r; sum.w *= r;
        *(float4*)(dst + e4) = sum;
    }
}

// ---------------------------------------------------------------------------
// q-softmax(d) * (512*SCALE), out'[e,n] = sum_d ct[d,e]*qtilde[d,n];
// writes at = fp16, TRANSPOSED to [b*4096+n][512] (in ws).
__global__ __launch_bounds__(256) void attn_out(const h16* __restrict__ qkv16,
                                                const float* __restrict__ ct,
                                                h16* __restrict__ at) {
    __shared__ float cts[64][68];
    __shared__ float qt[64][68];

    const int bh = blockIdx.y, ci = blockIdx.x;
    const int b = bh >> 3, h = bh & 7;
    const h16* qb = qkv16 + ((size_t)b * OC3 + h * 64) * HWN;
    const int tid = threadIdx.x;

    for (int i4 = tid * 4; i4 < 4096; i4 += 1024) {
        const float4 v = *(const float4*)(ct + (size_t)bh * 4096 + i4);
        *(float4*)&cts[i4 >> 6][i4 & 63] = v;
    }

    const int d  = tid >> 2;
    const int te = tid & 15, tn = tid >> 4;
    const int rn = tid >> 2, d0q = (tid & 3) * 16;

    for (int t = 0; t < 8; ++t) {
        const int n0 = ci * 512 + t * 64;
        __syncthreads();
#pragma unroll
        for (int jj = 0; jj < 2; ++jj) {
            const int nn = (tid & 3) * 8 + jj * 32;
            const f16x8 qv = *(const f16x8*)(qb + (size_t)d * HWN + n0 + nn);
#pragma unroll
            for (int u = 0; u < 8; ++u) qt[nn + u][d] = (float)qv[u];
        }
        __syncthreads();
        {
            float mx = -1e30f;
#pragma unroll
            for (int dd = 0; dd < 16; ++dd) mx = fmaxf(mx, qt[rn][d0q + dd]);
            mx = fmaxf(mx, __shfl_xor(mx, 1));
            mx = fmaxf(mx, __shfl_xor(mx, 2));
            float sm = 0.f;
#pragma unroll
            for (int dd = 0; dd < 16; ++dd) sm += __expf(qt[rn][d0q + dd] - mx);
            sm += __shfl_xor(sm, 1);
            sm += __shfl_xor(sm, 2);
            const float sc = 512.f * QSCALE / sm;
#pragma unroll
            for (int dd = 0; dd < 16; ++dd)
                qt[rn][d0q + dd] = __expf(qt[rn][d0q + dd] - mx) * sc;
        }
        __syncthreads();
        float acc[4][4];
#pragma unroll
        for (int i = 0; i < 4; ++i)
#pragma unroll
            for (int j = 0; j < 4; ++j) acc[i][j] = 0.f;
#pragma unroll
        for (int dd = 0; dd < 64; ++dd) {
            float cv[4];
            *(float4*)cv = *(const float4*)&cts[dd][te * 4];
            const float q0 = qt[tn * 4 + 0][dd];
            const float q1 = qt[tn * 4 + 1][dd];
            const float q2 = qt[tn * 4 + 2][dd];
            const float q3 = qt[tn * 4 + 3][dd];
#pragma unroll
            for (int i = 0; i < 4; ++i) {
                acc[i][0] = fmaf(cv[i], q0, acc[i][0]);
                acc[i][1] = fmaf(cv[i], q1, acc[i][1]);
                acc[i][2] = fmaf(cv[i], q2, acc[i][2]);
                acc[i][3] = fmaf(cv[i], q3, acc[i][3]);
            }
        }
        __syncthreads();
#pragma unroll
        for (int i = 0; i < 4; ++i)
#pragma unroll
            for (int j = 0; j < 4; ++j)
                qt[tn * 4 + j][te * 4 + i] = acc[i][j];
        __syncthreads();
        {
            const int px = tid >> 2, e0 = (tid & 3) * 16;
            f16x8 vh0, vh1;
#pragma unroll
            for (int u = 0; u < 8; ++u) {
                vh0[u] = (h16)qt[px][e0 + u];
                vh1[u] = (h16)qt[px][e0 + 8 + u];
            }
            const size_t o = ((size_t)b * HWN + n0 + px) * CCH + h * 64 + e0;
            *(f16x8*)(at + o)     = vh0;
            *(f16x8*)(at + o + 8) = vh1;
        }
    }
}

// ---------------------------------------------------------------------------
// Fused out-GEMM + channel LN + residual. split-2: (wo_hi,at),(wo_lo,at).
__global__ __launch_bounds__(512) void out_fused(const h16* __restrict__ wo_hi,
                                                 const h16* __restrict__ wo_lo,
                                                 const h16* __restrict__ at,
                                                 const float* __restrict__ b_out,
                                                 const float* __restrict__ g_out,
                                                 const float* __restrict__ x,
                                                 float* __restrict__ out) {
    __shared__ __align__(16) h16 Alds[512 * 32];
    __shared__ __align__(16) h16 Blds[128 * 32];
    __shared__ float red1[4][128], red2[4][128];
    __shared__ float mnS[128], rsS[128];

    const int tid = threadIdx.x;
    const int p0 = blockIdx.x * 128;
    const int b = p0 >> 12, hw0 = p0 & 4095;

    const int trow = tid >> 2;
    const int skh  = ((tid & 3) ^ (trow & 3)) * 8;
    const size_t aoff = (size_t)trow * CCH + skh;
    const size_t boff = (size_t)p0 * CCH + aoff;
    const int wofs = (tid >> 6) * 512;

    const int wv = tid >> 6;
    const int wm = (wv >> 1) * 128, wn = (wv & 1) * 64;
    const int lane = tid & 63;
    const int lr = lane & 15, kg = lane >> 4;
    const int swz = (kg ^ (lr & 3)) * 8;

    f32x4 acc[8][4];
#pragma unroll
    for (int i = 0; i < 8; ++i)
#pragma unroll
        for (int j = 0; j < 4; ++j) acc[i][j] = {0.f, 0.f, 0.f, 0.f};

#define STAGEF(S)                                                       \
    do {                                                                \
        const int kc_ = ((S) & 15) * 32;                                \
        const h16* As_ = ((S) < 16) ? wo_hi : wo_lo;                    \
        gl_lds16(As_ + aoff + kc_,               Alds + wofs);          \
        gl_lds16(As_ + aoff + kc_ + 128 * CCH,   Alds + 4096 + wofs);   \
        gl_lds16(As_ + aoff + kc_ + 256 * CCH,   Alds + 8192 + wofs);   \
        gl_lds16(As_ + aoff + kc_ + 384 * CCH,   Alds + 12288 + wofs);  \
        gl_lds16(at + boff + kc_,                Blds + wofs);          \
    } while (0)

    STAGEF(0);
#pragma unroll 1
    for (int s = 0; s < 32; ++s) {
        __syncthreads();
        f16x8 af[8], bf[4];
#pragma unroll
        for (int i = 0; i < 8; ++i)
            af[i] = *(const f16x8*)(Alds + (wm + i * 16 + lr) * 32 + swz);
#pragma unroll
        for (int j = 0; j < 4; ++j)
            bf[j] = *(const f16x8*)(Blds + (wn + j * 16 + lr) * 32 + swz);
        __syncthreads();
        if (s < 31) STAGEF(s + 1);
#pragma unroll
        for (int i = 0; i < 8; ++i)
#pragma unroll
            for (int j = 0; j < 4; ++j)
                acc[i][j] = __builtin_amdgcn_mfma_f32_16x16x32_f16(af[i], bf[j], acc[i][j], 0, 0, 0);
    }
#undef STAGEF

#pragma unroll
    for (int i = 0; i < 8; ++i) {
        const int o = wm + i * 16 + kg * 4;
        const float4 bb = *(const float4*)(b_out + o);
#pragma unroll
        for (int j = 0; j < 4; ++j) {
            acc[i][j][0] = acc[i][j][0] * (1.f / 134217728.f) + bb.x;
            acc[i][j][1] = acc[i][j][1] * (1.f / 134217728.f) + bb.y;
            acc[i][j][2] = acc[i][j][2] * (1.f / 134217728.f) + bb.z;
            acc[i][j][3] = acc[i][j][3] * (1.f / 134217728.f) + bb.w;
        }
    }
    float s1[4], s2[4];
#pragma unroll
    for (int j = 0; j < 4; ++j) {
        s1[j] = 0.f; s2[j] = 0.f;
#pragma unroll
        for (int i = 0; i < 8; ++i)
#pragma unroll
            for (int r = 0; r < 4; ++r) {
                const float v = acc[i][j][r];
                s1[j] += v; s2[j] += v * v;
            }
        s1[j] += __shfl_xor(s1[j], 16); s1[j] += __shfl_xor(s1[j], 32);
        s2[j] += __shfl_xor(s2[j], 16); s2[j] += __shfl_xor(s2[j], 32);
    }
    if (kg == 0) {
#pragma unroll
        for (int j = 0; j < 4; ++j) {
            red1[wv >> 1][wn + j * 16 + lr] = s1[j];
            red2[wv >> 1][wn + j * 16 + lr] = s2[j];
        }
    }
    __syncthreads();
    if (tid < 128) {
        const float S1 = red1[0][tid] + red1[1][tid] + red1[2][tid] + red1[3][tid];
        const float S2 = red2[0][tid] + red2[1][tid] + red2[2][tid] + red2[3][tid];
        const float m = S1 * (1.f / 512.f);
        float var = S2 * (1.f / 512.f) - m * m;
        var = fmaxf(var, 0.f);
        mnS[tid] = m;
        rsS[tid] = rsqrtf(var + LN_EPS);
    }
    __syncthreads();
    float mj[4], rj[4];
#pragma unroll
    for (int j = 0; j < 4; ++j) {
        const int px = wn + j * 16 + lr;
        mj[j] = mnS[px]; rj[j] = rsS[px];
    }
#pragma unroll
    for (int i = 0; i < 8; ++i) {
        const int o = wm + i * 16 + kg * 4;
        const float4 gg = *(const float4*)(g_out + o);
#pragma unroll
        for (int r = 0; r < 4; ++r) {
            const float g = (r == 0) ? gg.x : (r == 1) ? gg.y : (r == 2) ? gg.z : gg.w;
            const float* xr = x + ((size_t)b * CCH + o + r) * HWN + hw0 + wn;
            float* dr = out + ((size_t)b * CCH + o + r) * HWN + hw0 + wn;
#pragma unroll
            for (int j = 0; j < 4; ++j) {
                const int c = j * 16 + lr;
                dr[c] = (acc[i][j][r] - mj[j]) * rj[j] * g + xr[c];
            }
        }
    }
}

// ---------------------------------------------------------------------------
extern "C" void kernel_launch(void* const* d_in, const int* in_sizes, int n_in,
                              void* d_out, int out_size, void* d_ws, size_t ws_size,
                              hipStream_t stream) {
    (void)in_sizes; (void)n_in; (void)out_size;
    const float* x     = (const float*)d_in[0];
    const float* w_qkv = (const float*)d_in[1];
    const float* w_out = (const float*)d_in[2];
    const float* b_out = (const float*)d_in[3];
    const float* g_out = (const float*)d_in[4];
    const float* g_ln  = (const float*)d_in[5];
    float* out = (float*)d_out;
    float* ws  = (float*)d_ws;

    float* s    = ws;                       // 1536
    float* ct   = s + OC3;                  // 524288
    float* ctp  = ct + 524288;              // 4325376 (128 bh x 8 ci x 4224)
    float* psum = ctp;                      // 524288 (alias: dead before ctx)
    float* psq  = psum + 524288;            // 524288
    h16*  wg_hi = (h16*)(ctp + 4325376);    // 786432 halfs
    h16*  wg_lo = wg_hi + 786432;
    h16*  wo_hi = wg_lo + 786432;           // 262144 halfs
    h16*  wo_lo = wo_hi + 262144;
    h16*  qkv16 = wo_lo + 262144;           // 100663296 halfs (fp16 q,k,v)
    h16*  at    = qkv16 + 100663296;        // 33554432 halfs (attn out, transposed)
    // alias of d_out: xt dead after qkv_gemm (out_fused is sole d_out writer)
    h16*  xt_hi = (h16*)d_out;

    const size_t need = 73008640ULL * 4ULL;   // ~292.0 MB
    if (ws_size < need) return;

    prep_w       <<<2048, 64, 0, stream>>>(w_qkv, g_ln, w_out,
                                           wg_hi, wg_lo, s, wo_hi, wo_lo);
    transpose_cvt<<<dim3(64, 8, 16), 256, 0, stream>>>(x, xt_hi, psum, psq);
    qkv_gemm     <<<dim3(12, 512), 256, 0, stream>>>(wg_hi, wg_lo, xt_hi,
                                                     s, psum, psq, qkv16);
    ctx_partial  <<<dim3(8, 128), 256, 0, stream>>>(qkv16, ctp);
    ctx_reduce   <<<128, 256, 0, stream>>>(ctp, ct);
    attn_out     <<<dim3(8, 128), 256, 0, stream>>>(qkv16, ct, at);
    out_fused    <<<512, 512, 0, stream>>>(wo_hi, wo_lo, at,
                                           b_out, g_out, x, out);
}

// Round 13
// 474.659 us; speedup vs baseline: 1.2255x; 1.2117x over previous
//
#include <hip/hip_runtime.h>
#include <math.h>

#define CCH    512
#define HWN    4096
#define NPIX   65536
#define OC3    1536
#define QSCALE 0.125f
#define LN_EPS 1e-5f

typedef _Float16 h16;
typedef h16  f16x8 __attribute__((ext_vector_type(8)));
typedef float f32x4 __attribute__((ext_vector_type(4)));

__device__ __forceinline__ float waveReduceSum(float v) {
#pragma unroll
    for (int off = 32; off; off >>= 1) v += __shfl_xor(v, off);
    return v;
}

__device__ __forceinline__ void gl_lds16(const void* g, void* l) {
    __builtin_amdgcn_global_load_lds((const __attribute__((address_space(1))) void*)g,
                                     (__attribute__((address_space(3))) void*)l, 16, 0, 0);
}

// ---------------------------------------------------------------------------
// merged weight prep (single fp16, x64 scaled):
// o<1536 -> wg = w_qkv*g_ln + row-sum s;  o>=1536 -> wo = w_out
__global__ __launch_bounds__(64) void prep_w(const float* __restrict__ w_qkv,
                                             const float* __restrict__ g_ln,
                                             const float* __restrict__ w_out,
                                             h16* __restrict__ wg_h,
                                             float* __restrict__ s,
                                             h16* __restrict__ wo_h) {
    const int o = blockIdx.x, lane = threadIdx.x;
    if (o < OC3) {
        float sum = 0.f;
#pragma unroll
        for (int j = 0; j < 8; ++j) {
            const int c = lane + j * 64;
            const float w = w_qkv[(size_t)o * CCH + c] * g_ln[c];
            wg_h[(size_t)o * CCH + c] = (h16)(w * 64.f);
            sum += w;
        }
        sum = waveReduceSum(sum);
        if (lane == 0) s[o] = sum;
    } else {
        const int r = o - OC3;
#pragma unroll
        for (int j = 0; j < 8; ++j) {
            const int c = lane + j * 64;
            wo_h[(size_t)r * CCH + c] = (h16)(w_out[(size_t)r * CCH + c] * 64.f);
        }
    }
}

// ---------------------------------------------------------------------------
// fp32 [16][512][4096] -> transposed fp16 [16][4096][512]
// + per-(channel-block, pixel) LN partial sums (deterministic 2-stage stats)
__global__ __launch_bounds__(256) void transpose_cvt(const float* __restrict__ src,
                                                     h16* __restrict__ dhi,
                                                     float* __restrict__ psum,
                                                     float* __restrict__ psq) {
    __shared__ float tile[64][65];
    __shared__ float ps1[4][64], ps2[4][64];
    const int b = blockIdx.z, c0 = blockIdx.y * 64, p0 = blockIdx.x * 64;
    const int t = threadIdx.x;
    const float* sb = src + ((size_t)b * CCH + c0) * HWN + p0;
    const int rc = t >> 4, cc4 = (t & 15) * 4;
#pragma unroll
    for (int ps = 0; ps < 4; ++ps) {
        const float4 v = *(const float4*)(sb + (size_t)(rc + ps * 16) * HWN + cc4);
        tile[rc + ps * 16][cc4 + 0] = v.x;
        tile[rc + ps * 16][cc4 + 1] = v.y;
        tile[rc + ps * 16][cc4 + 2] = v.z;
        tile[rc + ps * 16][cc4 + 3] = v.w;
    }
    __syncthreads();
    {
        const int q = t >> 6, px = t & 63;
        float s1 = 0.f, s2 = 0.f;
#pragma unroll
        for (int c = q * 16; c < q * 16 + 16; ++c) {
            const float v = tile[c][px];
            s1 += v; s2 += v * v;
        }
        ps1[q][px] = s1; ps2[q][px] = s2;
    }
    const int pr0 = t >> 3, cs = (t & 7) * 8;
#pragma unroll
    for (int ps = 0; ps < 2; ++ps) {
        const int pr = pr0 + ps * 32;
        f16x8 vh;
#pragma unroll
        for (int q = 0; q < 8; ++q) vh[q] = (h16)tile[cs + q][pr];
        const size_t o = ((size_t)b * HWN + p0 + pr) * CCH + c0 + cs;
        *(f16x8*)(dhi + o) = vh;
    }
    __syncthreads();
    if (t < 64) {
        const float s1 = ps1[0][t] + ps1[1][t] + ps1[2][t] + ps1[3][t];
        const float s2 = ps2[0][t] + ps2[1][t] + ps2[2][t] + ps2[3][t];
        const size_t gp = (size_t)b * HWN + p0 + t;
        psum[(size_t)(c0 >> 6) * NPIX + gp] = s1;
        psq [(size_t)(c0 >> 6) * NPIX + gp] = s2;
    }
}

// ---------------------------------------------------------------------------
// QKV GEMM: 128x128 MFMA, single fp16 (A x64 scaled), K=512.
// LN stats finished in-block from psum/psq.
// out fp16 = rstd[p]*(acc/64 - mean[p]*s[o]).
__global__ __launch_bounds__(256) void qkv_gemm(const h16* __restrict__ Ahg,
                                                const h16* __restrict__ Bhg,
                                                const float* __restrict__ sv,
                                                const float* __restrict__ psum,
                                                const float* __restrict__ psq,
                                                h16* __restrict__ qout) {
    __shared__ __align__(16) h16 Ah[4096], Bh[4096];
    __shared__ float mnS[128], rsS[128];
    const int tid = threadIdx.x;
    const int om = blockIdx.x * 128;
    const int by0 = blockIdx.y;
    const int by  = (by0 & 7) * 64 + (by0 >> 3);   // bijective XCD chunking (512%8==0)
    const int p0  = by * 128;

    const int srow = tid >> 2;
    const int skh  = ((tid & 3) ^ (srow & 3)) * 8;
    const size_t a0 = (size_t)(om + srow) * CCH + skh;
    const size_t b0 = (size_t)(p0 + srow) * CCH + skh;
    const int wofs = (tid >> 6) * 512;

    const int lane = tid & 63;
    const int wv = tid >> 6;
    const int wm = (wv >> 1) * 64, wn = (wv & 1) * 64;
    const int lr = lane & 15, kg = lane >> 4;
    const int swz = (kg ^ (lr & 3)) * 8;

    f32x4 acc[4][4];
#pragma unroll
    for (int i = 0; i < 4; ++i)
#pragma unroll
        for (int j = 0; j < 4; ++j) acc[i][j] = {0.f, 0.f, 0.f, 0.f};

#define STAGE(KC)                                               \
    do {                                                        \
        gl_lds16(Ahg + a0 + (KC), Ah + wofs);                   \
        gl_lds16(Ahg + a0 + (KC) + 64 * CCH, Ah + 2048 + wofs); \
        gl_lds16(Bhg + b0 + (KC), Bh + wofs);                   \
        gl_lds16(Bhg + b0 + (KC) + 64 * CCH, Bh + 2048 + wofs); \
    } while (0)

    STAGE(0);
    // fused ln_finish: stats for this block's 128 pixels (coalesced reads,
    // overlapped with tile-0 staging; loop barriers make mnS visible to epilogue)
    if (tid < 128) {
        const int gp = p0 + tid;
        float s1 = 0.f, s2 = 0.f;
#pragma unroll
        for (int cb = 0; cb < 8; ++cb) {
            s1 += psum[(size_t)cb * NPIX + gp];
            s2 += psq [(size_t)cb * NPIX + gp];
        }
        const float m = s1 * (1.f / 512.f);
        float var = s2 * (1.f / 512.f) - m * m;
        var = fmaxf(var, 0.f);
        mnS[tid] = m;
        rsS[tid] = rsqrtf(var + LN_EPS);
    }

#pragma unroll 1
    for (int kc = 0; kc < 512; kc += 32) {
        __syncthreads();
        f16x8 ah[4], bh[4];
#pragma unroll
        for (int i = 0; i < 4; ++i) {
            const int ra = (wm + i * 16 + lr) * 32 + swz;
            ah[i] = *(const f16x8*)(Ah + ra);
            const int rb = (wn + i * 16 + lr) * 32 + swz;
            bh[i] = *(const f16x8*)(Bh + rb);
        }
        __syncthreads();
        if (kc + 32 < 512) STAGE(kc + 32);
#pragma unroll
        for (int i = 0; i < 4; ++i)
#pragma unroll
            for (int j = 0; j < 4; ++j)
                acc[i][j] = __builtin_amdgcn_mfma_f32_16x16x32_f16(ah[i], bh[j], acc[i][j], 0, 0, 0);
    }
#undef STAGE

    const int b = p0 >> 12, hw0 = p0 & 4095;
    float mn[4], rs[4];
#pragma unroll
    for (int j = 0; j < 4; ++j) {
        const int px = wn + j * 16 + lr;
        mn[j] = mnS[px]; rs[j] = rsS[px];
    }
#pragma unroll
    for (int i = 0; i < 4; ++i)
#pragma unroll
        for (int r = 0; r < 4; ++r) {
            const int o = om + wm + i * 16 + kg * 4 + r;
            const float so = sv[o];
            h16* dst = qout + ((size_t)b * OC3 + o) * HWN;
#pragma unroll
            for (int j = 0; j < 4; ++j) {
                const int hw = hw0 + wn + j * 16 + lr;
                dst[hw] = (h16)(rs[j] * (acc[i][j][r] * (1.f / 64.f) - mn[j] * so));
            }
        }
}

// ---------------------------------------------------------------------------
// partial context over an n-chunk of 512 with chunk-local softmax max:
// pass 1: m_loc[d] = max over chunk; pass 2 (k L2-warm): pt = sum exp(k-m_loc)*v,
// z[d] = sum exp(k-m_loc). Output per (bh,ci): [64*64 pt][64 z][64 m].
__global__ __launch_bounds__(256) void ctx_partial(const h16* __restrict__ qkv16,
                                                   float* __restrict__ ctp) {
    __shared__ float kt[64][68];
    __shared__ float vt[64][68];

    const int bh = blockIdx.y, ci = blockIdx.x;
    const int b = bh >> 3, h = bh & 7;
    const h16* kb = qkv16 + ((size_t)b * OC3 + CCH  + h * 64) * HWN;
    const h16* vb = qkv16 + ((size_t)b * OC3 + 1024 + h * 64) * HWN;
    const int tid = threadIdx.x;

    const int d  = tid >> 2;
    const int td = tid & 15, te = tid >> 4;

    // pass 1: chunk-local row max (4 threads/row, shfl-combined)
    float mx = -1e30f;
    for (int t = 0; t < 8; ++t) {
        const int n0 = ci * 512 + t * 64;
#pragma unroll
        for (int jj = 0; jj < 2; ++jj) {
            const int nn = (tid & 3) * 8 + jj * 32;
            const f16x8 kv = *(const f16x8*)(kb + (size_t)d * HWN + n0 + nn);
#pragma unroll
            for (int u = 0; u < 8; ++u) mx = fmaxf(mx, (float)kv[u]);
        }
    }
    mx = fmaxf(mx, __shfl_xor(mx, 1));
    mx = fmaxf(mx, __shfl_xor(mx, 2));

    float zt = 0.f;
    float acc[4][4];
#pragma unroll
    for (int i = 0; i < 4; ++i)
#pragma unroll
        for (int j = 0; j < 4; ++j) acc[i][j] = 0.f;

    for (int t = 0; t < 8; ++t) {
        const int n0 = ci * 512 + t * 64;
        __syncthreads();
#pragma unroll
        for (int jj = 0; jj < 2; ++jj) {
            const int nn = (tid & 3) * 8 + jj * 32;
            const f16x8 kv = *(const f16x8*)(kb + (size_t)d * HWN + n0 + nn);
            const f16x8 vv = *(const f16x8*)(vb + (size_t)d * HWN + n0 + nn);
#pragma unroll
            for (int u = 0; u < 8; ++u) {
                const float e = __expf((float)kv[u] - mx);
                zt += e;
                kt[nn + u][d] = e;
                vt[nn + u][d] = (float)vv[u];
            }
        }
        __syncthreads();
#pragma unroll
        for (int nn = 0; nn < 64; ++nn) {
            float kf[4], vf[4];
            *(float4*)kf = *(const float4*)&kt[nn][td * 4];
            *(float4*)vf = *(const float4*)&vt[nn][te * 4];
#pragma unroll
            for (int i = 0; i < 4; ++i)
#pragma unroll
                for (int j = 0; j < 4; ++j)
                    acc[i][j] = fmaf(kf[i], vf[j], acc[i][j]);
        }
    }
    zt += __shfl_xor(zt, 1);
    zt += __shfl_xor(zt, 2);

    float* dst = ctp + ((size_t)bh * 8 + ci) * 4224;
#pragma unroll
    for (int i = 0; i < 4; ++i) {
        const float4 o4 = make_float4(acc[i][0], acc[i][1], acc[i][2], acc[i][3]);
        *(float4*)(dst + (td * 4 + i) * 64 + te * 4) = o4;
    }
    if ((tid & 3) == 0) {
        dst[4096 + d] = zt;
        dst[4160 + d] = mx;
    }
}

// ---------------------------------------------------------------------------
// combine 8 chunk partials with exp(m_loc - M) rescale, normalize:
// ct[d][e] = sum_ci w_ci*pt_ci[d][e] / sum_ci w_ci*z_ci[d],  w = exp(m_loc-M)
__global__ __launch_bounds__(256) void ctx_reduce(const float* __restrict__ ctp,
                                                  float* __restrict__ ct) {
    __shared__ float w[8][64];
    __shared__ float rz[64];
    const int bh = blockIdx.x;
    const int tid = threadIdx.x;
    const float* src = ctp + (size_t)bh * 8 * 4224;
    if (tid < 64) {
        float M = -1e30f;
#pragma unroll
        for (int ci = 0; ci < 8; ++ci)
            M = fmaxf(M, src[(size_t)ci * 4224 + 4160 + tid]);
        float Z = 0.f;
#pragma unroll
        for (int ci = 0; ci < 8; ++ci) {
            const float ww = __expf(src[(size_t)ci * 4224 + 4160 + tid] - M);
            w[ci][tid] = ww;
            Z += ww * src[(size_t)ci * 4224 + 4096 + tid];
        }
        rz[tid] = 1.f / Z;
    }
    __syncthreads();
    float* dst = ct + (size_t)bh * 4096;
    for (int e4 = tid * 4; e4 < 4096; e4 += 1024) {
        const int d = e4 >> 6;
        float4 sum = make_float4(0.f, 0.f, 0.f, 0.f);
#pragma unroll
        for (int ci = 0; ci < 8; ++ci) {
            const float4 v = *(const float4*)(src + (size_t)ci * 4224 + e4);
            const float ww = w[ci][d];
            sum.x += ww * v.x; sum.y += ww * v.y;
            sum.z += ww * v.z; sum.w += ww * v.w;
        }
        const float r = rz[d];
        sum.x *= r; sum.y *= r; sum.z *= r; sum.w *= r;
        *(float4*)(dst + e4) = sum;
    }
}

// ---------------------------------------------------------------------------
// q-softmax(d) * (512*SCALE), out'[e,n] = sum_d ct[d,e]*qtilde[d,n];
// writes at = fp16, TRANSPOSED to [b*4096+n][512] (in ws).
__global__ __launch_bounds__(256) void attn_out(const h16* __restrict__ qkv16,
                                                const float* __restrict__ ct,
                                                h16* __restrict__ at) {
    __shared__ float cts[64][68];
    __shared__ float qt[64][68];

    const int bh = blockIdx.y, ci = blockIdx.x;
    const int b = bh >> 3, h = bh & 7;
    const h16* qb = qkv16 + ((size_t)b * OC3 + h * 64) * HWN;
    const int tid = threadIdx.x;

    for (int i4 = tid * 4; i4 < 4096; i4 += 1024) {
        const float4 v = *(const float4*)(ct + (size_t)bh * 4096 + i4);
        *(float4*)&cts[i4 >> 6][i4 & 63] = v;
    }

    const int d  = tid >> 2;
    const int te = tid & 15, tn = tid >> 4;
    const int rn = tid >> 2, d0q = (tid & 3) * 16;

    for (int t = 0; t < 8; ++t) {
        const int n0 = ci * 512 + t * 64;
        __syncthreads();
#pragma unroll
        for (int jj = 0; jj < 2; ++jj) {
            const int nn = (tid & 3) * 8 + jj * 32;
            const f16x8 qv = *(const f16x8*)(qb + (size_t)d * HWN + n0 + nn);
#pragma unroll
            for (int u = 0; u < 8; ++u) qt[nn + u][d] = (float)qv[u];
        }
        __syncthreads();
        {
            float mx = -1e30f;
#pragma unroll
            for (int dd = 0; dd < 16; ++dd) mx = fmaxf(mx, qt[rn][d0q + dd]);
            mx = fmaxf(mx, __shfl_xor(mx, 1));
            mx = fmaxf(mx, __shfl_xor(mx, 2));
            float sm = 0.f;
#pragma unroll
            for (int dd = 0; dd < 16; ++dd) sm += __expf(qt[rn][d0q + dd] - mx);
            sm += __shfl_xor(sm, 1);
            sm += __shfl_xor(sm, 2);
            const float sc = 512.f * QSCALE / sm;
#pragma unroll
            for (int dd = 0; dd < 16; ++dd)
                qt[rn][d0q + dd] = __expf(qt[rn][d0q + dd] - mx) * sc;
        }
        __syncthreads();
        float acc[4][4];
#pragma unroll
        for (int i = 0; i < 4; ++i)
#pragma unroll
            for (int j = 0; j < 4; ++j) acc[i][j] = 0.f;
#pragma unroll
        for (int dd = 0; dd < 64; ++dd) {
            float cv[4];
            *(float4*)cv = *(const float4*)&cts[dd][te * 4];
            const float q0 = qt[tn * 4 + 0][dd];
            const float q1 = qt[tn * 4 + 1][dd];
            const float q2 = qt[tn * 4 + 2][dd];
            const float q3 = qt[tn * 4 + 3][dd];
#pragma unroll
            for (int i = 0; i < 4; ++i) {
                acc[i][0] = fmaf(cv[i], q0, acc[i][0]);
                acc[i][1] = fmaf(cv[i], q1, acc[i][1]);
                acc[i][2] = fmaf(cv[i], q2, acc[i][2]);
                acc[i][3] = fmaf(cv[i], q3, acc[i][3]);
            }
        }
        __syncthreads();
#pragma unroll
        for (int i = 0; i < 4; ++i)
#pragma unroll
            for (int j = 0; j < 4; ++j)
                qt[tn * 4 + j][te * 4 + i] = acc[i][j];
        __syncthreads();
        {
            const int px = tid >> 2, e0 = (tid & 3) * 16;
            f16x8 vh0, vh1;
#pragma unroll
            for (int u = 0; u < 8; ++u) {
                vh0[u] = (h16)qt[px][e0 + u];
                vh1[u] = (h16)qt[px][e0 + 8 + u];
            }
            const size_t o = ((size_t)b * HWN + n0 + px) * CCH + h * 64 + e0;
            *(f16x8*)(at + o)     = vh0;
            *(f16x8*)(at + o + 8) = vh1;
        }
    }
}

// ---------------------------------------------------------------------------
// Fused out-GEMM + channel LN + residual. Single fp16: (wo_hi, at), K=512.
__global__ __launch_bounds__(512) void out_fused(const h16* __restrict__ wo_hi,
                                                 const h16* __restrict__ at,
                                                 const float* __restrict__ b_out,
                                                 const float* __restrict__ g_out,
                                                 const float* __restrict__ x,
                                                 float* __restrict__ out) {
    __shared__ __align__(16) h16 Alds[512 * 32];
    __shared__ __align__(16) h16 Blds[128 * 32];
    __shared__ float red1[4][128], red2[4][128];
    __shared__ float mnS[128], rsS[128];

    const int tid = threadIdx.x;
    const int p0 = blockIdx.x * 128;
    const int b = p0 >> 12, hw0 = p0 & 4095;

    const int trow = tid >> 2;
    const int skh  = ((tid & 3) ^ (trow & 3)) * 8;
    const size_t aoff = (size_t)trow * CCH + skh;
    const size_t boff = (size_t)p0 * CCH + aoff;
    const int wofs = (tid >> 6) * 512;

    const int wv = tid >> 6;
    const int wm = (wv >> 1) * 128, wn = (wv & 1) * 64;
    const int lane = tid & 63;
    const int lr = lane & 15, kg = lane >> 4;
    const int swz = (kg ^ (lr & 3)) * 8;

    f32x4 acc[8][4];
#pragma unroll
    for (int i = 0; i < 8; ++i)
#pragma unroll
        for (int j = 0; j < 4; ++j) acc[i][j] = {0.f, 0.f, 0.f, 0.f};

#define STAGEF(S)                                                           \
    do {                                                                    \
        const int kc_ = (S) * 32;                                           \
        gl_lds16(wo_hi + aoff + kc_,               Alds + wofs);            \
        gl_lds16(wo_hi + aoff + kc_ + 128 * CCH,   Alds + 4096 + wofs);     \
        gl_lds16(wo_hi + aoff + kc_ + 256 * CCH,   Alds + 8192 + wofs);     \
        gl_lds16(wo_hi + aoff + kc_ + 384 * CCH,   Alds + 12288 + wofs);    \
        gl_lds16(at + boff + kc_,                  Blds + wofs);            \
    } while (0)

    STAGEF(0);
#pragma unroll 1
    for (int s = 0; s < 16; ++s) {
        __syncthreads();
        f16x8 af[8], bf[4];
#pragma unroll
        for (int i = 0; i < 8; ++i)
            af[i] = *(const f16x8*)(Alds + (wm + i * 16 + lr) * 32 + swz);
#pragma unroll
        for (int j = 0; j < 4; ++j)
            bf[j] = *(const f16x8*)(Blds + (wn + j * 16 + lr) * 32 + swz);
        __syncthreads();
        if (s < 15) STAGEF(s + 1);
#pragma unroll
        for (int i = 0; i < 8; ++i)
#pragma unroll
            for (int j = 0; j < 4; ++j)
                acc[i][j] = __builtin_amdgcn_mfma_f32_16x16x32_f16(af[i], bf[j], acc[i][j], 0, 0, 0);
    }
#undef STAGEF

#pragma unroll
    for (int i = 0; i < 8; ++i) {
        const int o = wm + i * 16 + kg * 4;
        const float4 bb = *(const float4*)(b_out + o);
#pragma unroll
        for (int j = 0; j < 4; ++j) {
            acc[i][j][0] = acc[i][j][0] * (1.f / 134217728.f) + bb.x;
            acc[i][j][1] = acc[i][j][1] * (1.f / 134217728.f) + bb.y;
            acc[i][j][2] = acc[i][j][2] * (1.f / 134217728.f) + bb.z;
            acc[i][j][3] = acc[i][j][3] * (1.f / 134217728.f) + bb.w;
        }
    }
    float s1[4], s2[4];
#pragma unroll
    for (int j = 0; j < 4; ++j) {
        s1[j] = 0.f; s2[j] = 0.f;
#pragma unroll
        for (int i = 0; i < 8; ++i)
#pragma unroll
            for (int r = 0; r < 4; ++r) {
                const float v = acc[i][j][r];
                s1[j] += v; s2[j] += v * v;
            }
        s1[j] += __shfl_xor(s1[j], 16); s1[j] += __shfl_xor(s1[j], 32);
        s2[j] += __shfl_xor(s2[j], 16); s2[j] += __shfl_xor(s2[j], 32);
    }
    if (kg == 0) {
#pragma unroll
        for (int j = 0; j < 4; ++j) {
            red1[wv >> 1][wn + j * 16 + lr] = s1[j];
            red2[wv >> 1][wn + j * 16 + lr] = s2[j];
        }
    }
    __syncthreads();
    if (tid < 128) {
        const float S1 = red1[0][tid] + red1[1][tid] + red1[2][tid] + red1[3][tid];
        const float S2 = red2[0][tid] + red2[1][tid] + red2[2][tid] + red2[3][tid];
        const float m = S1 * (1.f / 512.f);
        float var = S2 * (1.f / 512.f) - m * m;
        var = fmaxf(var, 0.f);
        mnS[tid] = m;
        rsS[tid] = rsqrtf(var + LN_EPS);
    }
    __syncthreads();
    float mj[4], rj[4];
#pragma unroll
    for (int j = 0; j < 4; ++j) {
        const int px = wn + j * 16 + lr;
        mj[j] = mnS[px]; rj[j] = rsS[px];
    }
#pragma unroll
    for (int i = 0; i < 8; ++i) {
        const int o = wm + i * 16 + kg * 4;
        const float4 gg = *(const float4*)(g_out + o);
#pragma unroll
        for (int r = 0; r < 4; ++r) {
            const float g = (r == 0) ? gg.x : (r == 1) ? gg.y : (r == 2) ? gg.z : gg.w;
            const float* xr = x + ((size_t)b * CCH + o + r) * HWN + hw0 + wn;
            float* dr = out + ((size_t)b * CCH + o + r) * HWN + hw0 + wn;
#pragma unroll
            for (int j = 0; j < 4; ++j) {
                const int c = j * 16 + lr;
                dr[c] = (acc[i][j][r] - mj[j]) * rj[j] * g + xr[c];
            }
        }
    }
}

// ---------------------------------------------------------------------------
extern "C" void kernel_launch(void* const* d_in, const int* in_sizes, int n_in,
                              void* d_out, int out_size, void* d_ws, size_t ws_size,
                              hipStream_t stream) {
    (void)in_sizes; (void)n_in; (void)out_size;
    const float* x     = (const float*)d_in[0];
    const float* w_qkv = (const float*)d_in[1];
    const float* w_out = (const float*)d_in[2];
    const float* b_out = (const float*)d_in[3];
    const float* g_out = (const float*)d_in[4];
    const float* g_ln  = (const float*)d_in[5];
    float* out = (float*)d_out;
    float* ws  = (float*)d_ws;

    float* s    = ws;                       // 1536
    float* ct   = s + OC3;                  // 524288
    float* ctp  = ct + 524288;              // 4325376 (128 bh x 8 ci x 4224)
    float* psum = ctp;                      // 524288 (alias: dead before ctx)
    float* psq  = psum + 524288;            // 524288
    h16*  wg_hi = (h16*)(ctp + 4325376);    // 786432 halfs
    h16*  wo_hi = wg_hi + 786432;           // 262144 halfs
    h16*  qkv16 = wo_hi + 262144;           // 100663296 halfs (fp16 q,k,v)
    h16*  at    = qkv16 + 100663296;        // 33554432 halfs (attn out, transposed)
    // alias of d_out: xt dead after qkv_gemm (out_fused is sole d_out writer)
    h16*  xt_hi = (h16*)d_out;

    const size_t need = 72484352ULL * 4ULL;   // ~290.0 MB
    if (ws_size < need) return;

    prep_w       <<<2048, 64, 0, stream>>>(w_qkv, g_ln, w_out, wg_hi, s, wo_hi);
    transpose_cvt<<<dim3(64, 8, 16), 256, 0, stream>>>(x, xt_hi, psum, psq);
    qkv_gemm     <<<dim3(12, 512), 256, 0, stream>>>(wg_hi, xt_hi,
                                                     s, psum, psq, qkv16);
    ctx_partial  <<<dim3(8, 128), 256, 0, stream>>>(qkv16, ctp);
    ctx_reduce   <<<128, 256, 0, stream>>>(ctp, ct);
    attn_out     <<<dim3(8, 128), 256, 0, stream>>>(qkv16, ct, at);
    out_fused    <<<512, 512, 0, stream>>>(wo_hi, at,
                                           b_out, g_out, x, out);
}

// Round 14
// 460.872 us; speedup vs baseline: 1.2622x; 1.0299x over previous
//
#include <hip/hip_runtime.h>
#include <math.h>

#define CCH    512
#define HWN    4096
#define NPIX   65536
#define OC3    1536
#define QSCALE 0.125f
#define LN_EPS 1e-5f

typedef _Float16 h16;
typedef h16  f16x8 __attribute__((ext_vector_type(8)));
typedef float f32x4 __attribute__((ext_vector_type(4)));

__device__ __forceinline__ float waveReduceSum(float v) {
#pragma unroll
    for (int off = 32; off; off >>= 1) v += __shfl_xor(v, off);
    return v;
}

__device__ __forceinline__ void gl_lds16(const void* g, void* l) {
    __builtin_amdgcn_global_load_lds((const __attribute__((address_space(1))) void*)g,
                                     (__attribute__((address_space(3))) void*)l, 16, 0, 0);
}

// ---------------------------------------------------------------------------
// merged weight prep (single fp16, x64 scaled):
// o<1536 -> wg = w_qkv*g_ln + row-sum s;  o>=1536 -> wo = w_out
__global__ __launch_bounds__(64) void prep_w(const float* __restrict__ w_qkv,
                                             const float* __restrict__ g_ln,
                                             const float* __restrict__ w_out,
                                             h16* __restrict__ wg_h,
                                             float* __restrict__ s,
                                             h16* __restrict__ wo_h) {
    const int o = blockIdx.x, lane = threadIdx.x;
    if (o < OC3) {
        float sum = 0.f;
#pragma unroll
        for (int j = 0; j < 8; ++j) {
            const int c = lane + j * 64;
            const float w = w_qkv[(size_t)o * CCH + c] * g_ln[c];
            wg_h[(size_t)o * CCH + c] = (h16)(w * 64.f);
            sum += w;
        }
        sum = waveReduceSum(sum);
        if (lane == 0) s[o] = sum;
    } else {
        const int r = o - OC3;
#pragma unroll
        for (int j = 0; j < 8; ++j) {
            const int c = lane + j * 64;
            wo_h[(size_t)r * CCH + c] = (h16)(w_out[(size_t)r * CCH + c] * 64.f);
        }
    }
}

// ---------------------------------------------------------------------------
// fp32 [16][512][4096] -> transposed fp16 [16][4096][512]
// + per-(channel-block, pixel) LN partial sums (deterministic 2-stage stats)
__global__ __launch_bounds__(256) void transpose_cvt(const float* __restrict__ src,
                                                     h16* __restrict__ dhi,
                                                     float* __restrict__ psum,
                                                     float* __restrict__ psq) {
    __shared__ float tile[64][65];
    __shared__ float ps1[4][64], ps2[4][64];
    const int b = blockIdx.z, c0 = blockIdx.y * 64, p0 = blockIdx.x * 64;
    const int t = threadIdx.x;
    const float* sb = src + ((size_t)b * CCH + c0) * HWN + p0;
    const int rc = t >> 4, cc4 = (t & 15) * 4;
#pragma unroll
    for (int ps = 0; ps < 4; ++ps) {
        const float4 v = *(const float4*)(sb + (size_t)(rc + ps * 16) * HWN + cc4);
        tile[rc + ps * 16][cc4 + 0] = v.x;
        tile[rc + ps * 16][cc4 + 1] = v.y;
        tile[rc + ps * 16][cc4 + 2] = v.z;
        tile[rc + ps * 16][cc4 + 3] = v.w;
    }
    __syncthreads();
    {
        const int q = t >> 6, px = t & 63;
        float s1 = 0.f, s2 = 0.f;
#pragma unroll
        for (int c = q * 16; c < q * 16 + 16; ++c) {
            const float v = tile[c][px];
            s1 += v; s2 += v * v;
        }
        ps1[q][px] = s1; ps2[q][px] = s2;
    }
    const int pr0 = t >> 3, cs = (t & 7) * 8;
#pragma unroll
    for (int ps = 0; ps < 2; ++ps) {
        const int pr = pr0 + ps * 32;
        f16x8 vh;
#pragma unroll
        for (int q = 0; q < 8; ++q) vh[q] = (h16)tile[cs + q][pr];
        const size_t o = ((size_t)b * HWN + p0 + pr) * CCH + c0 + cs;
        *(f16x8*)(dhi + o) = vh;
    }
    __syncthreads();
    if (t < 64) {
        const float s1 = ps1[0][t] + ps1[1][t] + ps1[2][t] + ps1[3][t];
        const float s2 = ps2[0][t] + ps2[1][t] + ps2[2][t] + ps2[3][t];
        const size_t gp = (size_t)b * HWN + p0 + t;
        psum[(size_t)(c0 >> 6) * NPIX + gp] = s1;
        psq [(size_t)(c0 >> 6) * NPIX + gp] = s2;
    }
}

// ---------------------------------------------------------------------------
// QKV GEMM: 128x128 MFMA, single fp16 (A x64 scaled), BK=64 two-plane LDS
// (each 32-K plane identical layout+swizzle to proven BK=32 buffer; 32 MFMA
// per barrier pair). LN stats finished in-block from psum/psq.
// out fp16 = rstd[p]*(acc/64 - mean[p]*s[o]).
__global__ __launch_bounds__(256) void qkv_gemm(const h16* __restrict__ Ahg,
                                                const h16* __restrict__ Bhg,
                                                const float* __restrict__ sv,
                                                const float* __restrict__ psum,
                                                const float* __restrict__ psq,
                                                h16* __restrict__ qout) {
    __shared__ __align__(16) h16 Ah[8192], Bh[8192];   // 2 planes x [128][32]
    __shared__ float mnS[128], rsS[128];
    const int tid = threadIdx.x;
    const int om = blockIdx.x * 128;
    const int by0 = blockIdx.y;
    const int by  = (by0 & 7) * 64 + (by0 >> 3);   // bijective XCD chunking (512%8==0)
    const int p0  = by * 128;

    const int srow = tid >> 2;
    const int skh  = ((tid & 3) ^ (srow & 3)) * 8;
    const size_t a0 = (size_t)(om + srow) * CCH + skh;
    const size_t b0 = (size_t)(p0 + srow) * CCH + skh;
    const int wofs = (tid >> 6) * 512;

    const int lane = tid & 63;
    const int wv = tid >> 6;
    const int wm = (wv >> 1) * 64, wn = (wv & 1) * 64;
    const int lr = lane & 15, kg = lane >> 4;
    const int swz = (kg ^ (lr & 3)) * 8;

    f32x4 acc[4][4];
#pragma unroll
    for (int i = 0; i < 4; ++i)
#pragma unroll
        for (int j = 0; j < 4; ++j) acc[i][j] = {0.f, 0.f, 0.f, 0.f};

#define STAGE(KC)                                                     \
    do {                                                              \
        gl_lds16(Ahg + a0 + (KC), Ah + wofs);                         \
        gl_lds16(Ahg + a0 + (KC) + 64 * CCH, Ah + 2048 + wofs);       \
        gl_lds16(Ahg + a0 + (KC) + 32, Ah + 4096 + wofs);             \
        gl_lds16(Ahg + a0 + (KC) + 32 + 64 * CCH, Ah + 6144 + wofs);  \
        gl_lds16(Bhg + b0 + (KC), Bh + wofs);                         \
        gl_lds16(Bhg + b0 + (KC) + 64 * CCH, Bh + 2048 + wofs);       \
        gl_lds16(Bhg + b0 + (KC) + 32, Bh + 4096 + wofs);             \
        gl_lds16(Bhg + b0 + (KC) + 32 + 64 * CCH, Bh + 6144 + wofs);  \
    } while (0)

    STAGE(0);
    // fused ln_finish: stats for this block's 128 pixels (coalesced reads,
    // overlapped with tile-0 staging; loop barriers make mnS visible to epilogue)
    if (tid < 128) {
        const int gp = p0 + tid;
        float s1 = 0.f, s2 = 0.f;
#pragma unroll
        for (int cb = 0; cb < 8; ++cb) {
            s1 += psum[(size_t)cb * NPIX + gp];
            s2 += psq [(size_t)cb * NPIX + gp];
        }
        const float m = s1 * (1.f / 512.f);
        float var = s2 * (1.f / 512.f) - m * m;
        var = fmaxf(var, 0.f);
        mnS[tid] = m;
        rsS[tid] = rsqrtf(var + LN_EPS);
    }

#pragma unroll 1
    for (int kc = 0; kc < 512; kc += 64) {
        __syncthreads();
        f16x8 ah[2][4], bh[2][4];
#pragma unroll
        for (int ks = 0; ks < 2; ++ks)
#pragma unroll
            for (int i = 0; i < 4; ++i) {
                const int ra = ks * 4096 + (wm + i * 16 + lr) * 32 + swz;
                ah[ks][i] = *(const f16x8*)(Ah + ra);
                const int rb = ks * 4096 + (wn + i * 16 + lr) * 32 + swz;
                bh[ks][i] = *(const f16x8*)(Bh + rb);
            }
        __syncthreads();
        if (kc + 64 < 512) STAGE(kc + 64);
#pragma unroll
        for (int ks = 0; ks < 2; ++ks)
#pragma unroll
            for (int i = 0; i < 4; ++i)
#pragma unroll
                for (int j = 0; j < 4; ++j)
                    acc[i][j] = __builtin_amdgcn_mfma_f32_16x16x32_f16(ah[ks][i], bh[ks][j], acc[i][j], 0, 0, 0);
    }
#undef STAGE

    const int b = p0 >> 12, hw0 = p0 & 4095;
    float mn[4], rs[4];
#pragma unroll
    for (int j = 0; j < 4; ++j) {
        const int px = wn + j * 16 + lr;
        mn[j] = mnS[px]; rs[j] = rsS[px];
    }
#pragma unroll
    for (int i = 0; i < 4; ++i)
#pragma unroll
        for (int r = 0; r < 4; ++r) {
            const int o = om + wm + i * 16 + kg * 4 + r;
            const float so = sv[o];
            h16* dst = qout + ((size_t)b * OC3 + o) * HWN;
#pragma unroll
            for (int j = 0; j < 4; ++j) {
                const int hw = hw0 + wn + j * 16 + lr;
                dst[hw] = (h16)(rs[j] * (acc[i][j][r] * (1.f / 64.f) - mn[j] * so));
            }
        }
}

// ---------------------------------------------------------------------------
// partial context over an n-chunk of 512 with chunk-local softmax max:
// pass 1: m_loc[d] = max over chunk; pass 2 (k L2-warm): pt = sum exp(k-m_loc)*v,
// z[d] = sum exp(k-m_loc). Output per (bh,ci): [64*64 pt][64 z][64 m].
__global__ __launch_bounds__(256) void ctx_partial(const h16* __restrict__ qkv16,
                                                   float* __restrict__ ctp) {
    __shared__ float kt[64][68];
    __shared__ float vt[64][68];

    const int bh = blockIdx.y, ci = blockIdx.x;
    const int b = bh >> 3, h = bh & 7;
    const h16* kb = qkv16 + ((size_t)b * OC3 + CCH  + h * 64) * HWN;
    const h16* vb = qkv16 + ((size_t)b * OC3 + 1024 + h * 64) * HWN;
    const int tid = threadIdx.x;

    const int d  = tid >> 2;
    const int td = tid & 15, te = tid >> 4;

    // pass 1: chunk-local row max (4 threads/row, shfl-combined)
    float mx = -1e30f;
    for (int t = 0; t < 8; ++t) {
        const int n0 = ci * 512 + t * 64;
#pragma unroll
        for (int jj = 0; jj < 2; ++jj) {
            const int nn = (tid & 3) * 8 + jj * 32;
            const f16x8 kv = *(const f16x8*)(kb + (size_t)d * HWN + n0 + nn);
#pragma unroll
            for (int u = 0; u < 8; ++u) mx = fmaxf(mx, (float)kv[u]);
        }
    }
    mx = fmaxf(mx, __shfl_xor(mx, 1));
    mx = fmaxf(mx, __shfl_xor(mx, 2));

    float zt = 0.f;
    float acc[4][4];
#pragma unroll
    for (int i = 0; i < 4; ++i)
#pragma unroll
        for (int j = 0; j < 4; ++j) acc[i][j] = 0.f;

    for (int t = 0; t < 8; ++t) {
        const int n0 = ci * 512 + t * 64;
        __syncthreads();
#pragma unroll
        for (int jj = 0; jj < 2; ++jj) {
            const int nn = (tid & 3) * 8 + jj * 32;
            const f16x8 kv = *(const f16x8*)(kb + (size_t)d * HWN + n0 + nn);
            const f16x8 vv = *(const f16x8*)(vb + (size_t)d * HWN + n0 + nn);
#pragma unroll
            for (int u = 0; u < 8; ++u) {
                const float e = __expf((float)kv[u] - mx);
                zt += e;
                kt[nn + u][d] = e;
                vt[nn + u][d] = (float)vv[u];
            }
        }
        __syncthreads();
#pragma unroll
        for (int nn = 0; nn < 64; ++nn) {
            float kf[4], vf[4];
            *(float4*)kf = *(const float4*)&kt[nn][td * 4];
            *(float4*)vf = *(const float4*)&vt[nn][te * 4];
#pragma unroll
            for (int i = 0; i < 4; ++i)
#pragma unroll
                for (int j = 0; j < 4; ++j)
                    acc[i][j] = fmaf(kf[i], vf[j], acc[i][j]);
        }
    }
    zt += __shfl_xor(zt, 1);
    zt += __shfl_xor(zt, 2);

    float* dst = ctp + ((size_t)bh * 8 + ci) * 4224;
#pragma unroll
    for (int i = 0; i < 4; ++i) {
        const float4 o4 = make_float4(acc[i][0], acc[i][1], acc[i][2], acc[i][3]);
        *(float4*)(dst + (td * 4 + i) * 64 + te * 4) = o4;
    }
    if ((tid & 3) == 0) {
        dst[4096 + d] = zt;
        dst[4160 + d] = mx;
    }
}

// ---------------------------------------------------------------------------
// combine 8 chunk partials with exp(m_loc - M) rescale, normalize:
// ct[d][e] = sum_ci w_ci*pt_ci[d][e] / sum_ci w_ci*z_ci[d],  w = exp(m_loc-M)
__global__ __launch_bounds__(256) void ctx_reduce(const float* __restrict__ ctp,
                                                  float* __restrict__ ct) {
    __shared__ float w[8][64];
    __shared__ float rz[64];
    const int bh = blockIdx.x;
    const int tid = threadIdx.x;
    const float* src = ctp + (size_t)bh * 8 * 4224;
    if (tid < 64) {
        float M = -1e30f;
#pragma unroll
        for (int ci = 0; ci < 8; ++ci)
            M = fmaxf(M, src[(size_t)ci * 4224 + 4160 + tid]);
        float Z = 0.f;
#pragma unroll
        for (int ci = 0; ci < 8; ++ci) {
            const float ww = __expf(src[(size_t)ci * 4224 + 4160 + tid] - M);
            w[ci][tid] = ww;
            Z += ww * src[(size_t)ci * 4224 + 4096 + tid];
        }
        rz[tid] = 1.f / Z;
    }
    __syncthreads();
    float* dst = ct + (size_t)bh * 4096;
    for (int e4 = tid * 4; e4 < 4096; e4 += 1024) {
        const int d = e4 >> 6;
        float4 sum = make_float4(0.f, 0.f, 0.f, 0.f);
#pragma unroll
        for (int ci = 0; ci < 8; ++ci) {
            const float4 v = *(const float4*)(src + (size_t)ci * 4224 + e4);
            const float ww = w[ci][d];
            sum.x += ww * v.x; sum.y += ww * v.y;
            sum.z += ww * v.z; sum.w += ww * v.w;
        }
        const float r = rz[d];
        sum.x *= r; sum.y *= r; sum.z *= r; sum.w *= r;
        *(float4*)(dst + e4) = sum;
    }
}

// ---------------------------------------------------------------------------
// q-softmax(d) * (512*SCALE), out'[e,n] = sum_d ct[d,e]*qtilde[d,n];
// writes at = fp16, TRANSPOSED to [b*4096+n][512] (in ws).
__global__ __launch_bounds__(256) void attn_out(const h16* __restrict__ qkv16,
                                                const float* __restrict__ ct,
                                                h16* __restrict__ at) {
    __shared__ float cts[64][68];
    __shared__ float qt[64][68];

    const int bh = blockIdx.y, ci = blockIdx.x;
    const int b = bh >> 3, h = bh & 7;
    const h16* qb = qkv16 + ((size_t)b * OC3 + h * 64) * HWN;
    const int tid = threadIdx.x;

    for (int i4 = tid * 4; i4 < 4096; i4 += 1024) {
        const float4 v = *(const float4*)(ct + (size_t)bh * 4096 + i4);
        *(float4*)&cts[i4 >> 6][i4 & 63] = v;
    }

    const int d  = tid >> 2;
    const int te = tid & 15, tn = tid >> 4;
    const int rn = tid >> 2, d0q = (tid & 3) * 16;

    for (int t = 0; t < 8; ++t) {
        const int n0 = ci * 512 + t * 64;
        __syncthreads();
#pragma unroll
        for (int jj = 0; jj < 2; ++jj) {
            const int nn = (tid & 3) * 8 + jj * 32;
            const f16x8 qv = *(const f16x8*)(qb + (size_t)d * HWN + n0 + nn);
#pragma unroll
            for (int u = 0; u < 8; ++u) qt[nn + u][d] = (float)qv[u];
        }
        __syncthreads();
        {
            float mx = -1e30f;
#pragma unroll
            for (int dd = 0; dd < 16; ++dd) mx = fmaxf(mx, qt[rn][d0q + dd]);
            mx = fmaxf(mx, __shfl_xor(mx, 1));
            mx = fmaxf(mx, __shfl_xor(mx, 2));
            float sm = 0.f;
#pragma unroll
            for (int dd = 0; dd < 16; ++dd) sm += __expf(qt[rn][d0q + dd] - mx);
            sm += __shfl_xor(sm, 1);
            sm += __shfl_xor(sm, 2);
            const float sc = 512.f * QSCALE / sm;
#pragma unroll
            for (int dd = 0; dd < 16; ++dd)
                qt[rn][d0q + dd] = __expf(qt[rn][d0q + dd] - mx) * sc;
        }
        __syncthreads();
        float acc[4][4];
#pragma unroll
        for (int i = 0; i < 4; ++i)
#pragma unroll
            for (int j = 0; j < 4; ++j) acc[i][j] = 0.f;
#pragma unroll
        for (int dd = 0; dd < 64; ++dd) {
            float cv[4];
            *(float4*)cv = *(const float4*)&cts[dd][te * 4];
            const float q0 = qt[tn * 4 + 0][dd];
            const float q1 = qt[tn * 4 + 1][dd];
            const float q2 = qt[tn * 4 + 2][dd];
            const float q3 = qt[tn * 4 + 3][dd];
#pragma unroll
            for (int i = 0; i < 4; ++i) {
                acc[i][0] = fmaf(cv[i], q0, acc[i][0]);
                acc[i][1] = fmaf(cv[i], q1, acc[i][1]);
                acc[i][2] = fmaf(cv[i], q2, acc[i][2]);
                acc[i][3] = fmaf(cv[i], q3, acc[i][3]);
            }
        }
        __syncthreads();
#pragma unroll
        for (int i = 0; i < 4; ++i)
#pragma unroll
            for (int j = 0; j < 4; ++j)
                qt[tn * 4 + j][te * 4 + i] = acc[i][j];
        __syncthreads();
        {
            const int px = tid >> 2, e0 = (tid & 3) * 16;
            f16x8 vh0, vh1;
#pragma unroll
            for (int u = 0; u < 8; ++u) {
                vh0[u] = (h16)qt[px][e0 + u];
                vh1[u] = (h16)qt[px][e0 + 8 + u];
            }
            const size_t o = ((size_t)b * HWN + n0 + px) * CCH + h * 64 + e0;
            *(f16x8*)(at + o)     = vh0;
            *(f16x8*)(at + o + 8) = vh1;
        }
    }
}

// ---------------------------------------------------------------------------
// Fused out-GEMM + channel LN + residual. Single fp16: (wo_hi, at), K=512.
__global__ __launch_bounds__(512) void out_fused(const h16* __restrict__ wo_hi,
                                                 const h16* __restrict__ at,
                                                 const float* __restrict__ b_out,
                                                 const float* __restrict__ g_out,
                                                 const float* __restrict__ x,
                                                 float* __restrict__ out) {
    __shared__ __align__(16) h16 Alds[512 * 32];
    __shared__ __align__(16) h16 Blds[128 * 32];
    __shared__ float red1[4][128], red2[4][128];
    __shared__ float mnS[128], rsS[128];

    const int tid = threadIdx.x;
    const int p0 = blockIdx.x * 128;
    const int b = p0 >> 12, hw0 = p0 & 4095;

    const int trow = tid >> 2;
    const int skh  = ((tid & 3) ^ (trow & 3)) * 8;
    const size_t aoff = (size_t)trow * CCH + skh;
    const size_t boff = (size_t)p0 * CCH + aoff;
    const int wofs = (tid >> 6) * 512;

    const int wv = tid >> 6;
    const int wm = (wv >> 1) * 128, wn = (wv & 1) * 64;
    const int lane = tid & 63;
    const int lr = lane & 15, kg = lane >> 4;
    const int swz = (kg ^ (lr & 3)) * 8;

    f32x4 acc[8][4];
#pragma unroll
    for (int i = 0; i < 8; ++i)
#pragma unroll
        for (int j = 0; j < 4; ++j) acc[i][j] = {0.f, 0.f, 0.f, 0.f};

#define STAGEF(S)                                                           \
    do {                                                                    \
        const int kc_ = (S) * 32;                                           \
        gl_lds16(wo_hi + aoff + kc_,               Alds + wofs);            \
        gl_lds16(wo_hi + aoff + kc_ + 128 * CCH,   Alds + 4096 + wofs);     \
        gl_lds16(wo_hi + aoff + kc_ + 256 * CCH,   Alds + 8192 + wofs);     \
        gl_lds16(wo_hi + aoff + kc_ + 384 * CCH,   Alds + 12288 + wofs);    \
        gl_lds16(at + boff + kc_,                  Blds + wofs);            \
    } while (0)

    STAGEF(0);
#pragma unroll 1
    for (int s = 0; s < 16; ++s) {
        __syncthreads();
        f16x8 af[8], bf[4];
#pragma unroll
        for (int i = 0; i < 8; ++i)
            af[i] = *(const f16x8*)(Alds + (wm + i * 16 + lr) * 32 + swz);
#pragma unroll
        for (int j = 0; j < 4; ++j)
            bf[j] = *(const f16x8*)(Blds + (wn + j * 16 + lr) * 32 + swz);
        __syncthreads();
        if (s < 15) STAGEF(s + 1);
#pragma unroll
        for (int i = 0; i < 8; ++i)
#pragma unroll
            for (int j = 0; j < 4; ++j)
                acc[i][j] = __builtin_amdgcn_mfma_f32_16x16x32_f16(af[i], bf[j], acc[i][j], 0, 0, 0);
    }
#undef STAGEF

#pragma unroll
    for (int i = 0; i < 8; ++i) {
        const int o = wm + i * 16 + kg * 4;
        const float4 bb = *(const float4*)(b_out + o);
#pragma unroll
        for (int j = 0; j < 4; ++j) {
            acc[i][j][0] = acc[i][j][0] * (1.f / 134217728.f) + bb.x;
            acc[i][j][1] = acc[i][j][1] * (1.f / 134217728.f) + bb.y;
            acc[i][j][2] = acc[i][j][2] * (1.f / 134217728.f) + bb.z;
            acc[i][j][3] = acc[i][j][3] * (1.f / 134217728.f) + bb.w;
        }
    }
    float s1[4], s2[4];
#pragma unroll
    for (int j = 0; j < 4; ++j) {
        s1[j] = 0.f; s2[j] = 0.f;
#pragma unroll
        for (int i = 0; i < 8; ++i)
#pragma unroll
            for (int r = 0; r < 4; ++r) {
                const float v = acc[i][j][r];
                s1[j] += v; s2[j] += v * v;
            }
        s1[j] += __shfl_xor(s1[j], 16); s1[j] += __shfl_xor(s1[j], 32);
        s2[j] += __shfl_xor(s2[j], 16); s2[j] += __shfl_xor(s2[j], 32);
    }
    if (kg == 0) {
#pragma unroll
        for (int j = 0; j < 4; ++j) {
            red1[wv >> 1][wn + j * 16 + lr] = s1[j];
            red2[wv >> 1][wn + j * 16 + lr] = s2[j];
        }
    }
    __syncthreads();
    if (tid < 128) {
        const float S1 = red1[0][tid] + red1[1][tid] + red1[2][tid] + red1[3][tid];
        const float S2 = red2[0][tid] + red2[1][tid] + red2[2][tid] + red2[3][tid];
        const float m = S1 * (1.f / 512.f);
        float var = S2 * (1.f / 512.f) - m * m;
        var = fmaxf(var, 0.f);
        mnS[tid] = m;
        rsS[tid] = rsqrtf(var + LN_EPS);
    }
    __syncthreads();
    float mj[4], rj[4];
#pragma unroll
    for (int j = 0; j < 4; ++j) {
        const int px = wn + j * 16 + lr;
        mj[j] = mnS[px]; rj[j] = rsS[px];
    }
#pragma unroll
    for (int i = 0; i < 8; ++i) {
        const int o = wm + i * 16 + kg * 4;
        const float4 gg = *(const float4*)(g_out + o);
#pragma unroll
        for (int r = 0; r < 4; ++r) {
            const float g = (r == 0) ? gg.x : (r == 1) ? gg.y : (r == 2) ? gg.z : gg.w;
            const float* xr = x + ((size_t)b * CCH + o + r) * HWN + hw0 + wn;
            float* dr = out + ((size_t)b * CCH + o + r) * HWN + hw0 + wn;
#pragma unroll
            for (int j = 0; j < 4; ++j) {
                const int c = j * 16 + lr;
                dr[c] = (acc[i][j][r] - mj[j]) * rj[j] * g + xr[c];
            }
        }
    }
}

// ---------------------------------------------------------------------------
extern "C" void kernel_launch(void* const* d_in, const int* in_sizes, int n_in,
                              void* d_out, int out_size, void* d_ws, size_t ws_size,
                              hipStream_t stream) {
    (void)in_sizes; (void)n_in; (void)out_size;
    const float* x     = (const float*)d_in[0];
    const float* w_qkv = (const float*)d_in[1];
    const float* w_out = (const float*)d_in[2];
    const float* b_out = (const float*)d_in[3];
    const float* g_out = (const float*)d_in[4];
    const float* g_ln  = (const float*)d_in[5];
    float* out = (float*)d_out;
    float* ws  = (float*)d_ws;

    float* s    = ws;                       // 1536
    float* ct   = s + OC3;                  // 524288
    float* ctp  = ct + 524288;              // 4325376 (128 bh x 8 ci x 4224)
    float* psum = ctp;                      // 524288 (alias: dead before ctx)
    float* psq  = psum + 524288;            // 524288
    h16*  wg_hi = (h16*)(ctp + 4325376);    // 786432 halfs
    h16*  wo_hi = wg_hi + 786432;           // 262144 halfs
    h16*  qkv16 = wo_hi + 262144;           // 100663296 halfs (fp16 q,k,v)
    h16*  at    = qkv16 + 100663296;        // 33554432 halfs (attn out, transposed)
    // alias of d_out: xt dead after qkv_gemm (out_fused is sole d_out writer)
    h16*  xt_hi = (h16*)d_out;

    const size_t need = 72484352ULL * 4ULL;   // ~290.0 MB
    if (ws_size < need) return;

    prep_w       <<<2048, 64, 0, stream>>>(w_qkv, g_ln, w_out, wg_hi, s, wo_hi);
    transpose_cvt<<<dim3(64, 8, 16), 256, 0, stream>>>(x, xt_hi, psum, psq);
    qkv_gemm     <<<dim3(12, 512), 256, 0, stream>>>(wg_hi, xt_hi,
                                                     s, psum, psq, qkv16);
    ctx_partial  <<<dim3(8, 128), 256, 0, stream>>>(qkv16, ctp);
    ctx_reduce   <<<128, 256, 0, stream>>>(ctp, ct);
    attn_out     <<<dim3(8, 128), 256, 0, stream>>>(qkv16, ct, at);
    out_fused    <<<512, 512, 0, stream>>>(wo_hi, at,
                                           b_out, g_out, x, out);
}

// Round 15
// 452.471 us; speedup vs baseline: 1.2856x; 1.0186x over previous
//
#include <hip/hip_runtime.h>
#include <math.h>

#define CCH    512
#define HWN    4096
#define NPIX   65536
#define OC3    1536
#define QSCALE 0.125f
#define LN_EPS 1e-5f

typedef _Float16 h16;
typedef h16  f16x8 __attribute__((ext_vector_type(8)));
typedef float f32x4 __attribute__((ext_vector_type(4)));

__device__ __forceinline__ float waveReduceSum(float v) {
#pragma unroll
    for (int off = 32; off; off >>= 1) v += __shfl_xor(v, off);
    return v;
}

__device__ __forceinline__ void gl_lds16(const void* g, void* l) {
    __builtin_amdgcn_global_load_lds((const __attribute__((address_space(1))) void*)g,
                                     (__attribute__((address_space(3))) void*)l, 16, 0, 0);
}

// ---------------------------------------------------------------------------
// merged weight prep (single fp16, x64 scaled):
// o<1536 -> wg = w_qkv*g_ln + row-sum s;  o>=1536 -> wo = w_out
__global__ __launch_bounds__(64) void prep_w(const float* __restrict__ w_qkv,
                                             const float* __restrict__ g_ln,
                                             const float* __restrict__ w_out,
                                             h16* __restrict__ wg_h,
                                             float* __restrict__ s,
                                             h16* __restrict__ wo_h) {
    const int o = blockIdx.x, lane = threadIdx.x;
    if (o < OC3) {
        float sum = 0.f;
#pragma unroll
        for (int j = 0; j < 8; ++j) {
            const int c = lane + j * 64;
            const float w = w_qkv[(size_t)o * CCH + c] * g_ln[c];
            wg_h[(size_t)o * CCH + c] = (h16)(w * 64.f);
            sum += w;
        }
        sum = waveReduceSum(sum);
        if (lane == 0) s[o] = sum;
    } else {
        const int r = o - OC3;
#pragma unroll
        for (int j = 0; j < 8; ++j) {
            const int c = lane + j * 64;
            wo_h[(size_t)r * CCH + c] = (h16)(w_out[(size_t)r * CCH + c] * 64.f);
        }
    }
}

// ---------------------------------------------------------------------------
// fp32 [16][512][4096] -> transposed fp16 [16][4096][512]
// + per-(channel-block, pixel) LN partial sums (deterministic 2-stage stats)
__global__ __launch_bounds__(256) void transpose_cvt(const float* __restrict__ src,
                                                     h16* __restrict__ dhi,
                                                     float* __restrict__ psum,
                                                     float* __restrict__ psq) {
    __shared__ float tile[64][65];
    __shared__ float ps1[4][64], ps2[4][64];
    const int b = blockIdx.z, c0 = blockIdx.y * 64, p0 = blockIdx.x * 64;
    const int t = threadIdx.x;
    const float* sb = src + ((size_t)b * CCH + c0) * HWN + p0;
    const int rc = t >> 4, cc4 = (t & 15) * 4;
#pragma unroll
    for (int ps = 0; ps < 4; ++ps) {
        const float4 v = *(const float4*)(sb + (size_t)(rc + ps * 16) * HWN + cc4);
        tile[rc + ps * 16][cc4 + 0] = v.x;
        tile[rc + ps * 16][cc4 + 1] = v.y;
        tile[rc + ps * 16][cc4 + 2] = v.z;
        tile[rc + ps * 16][cc4 + 3] = v.w;
    }
    __syncthreads();
    {
        const int q = t >> 6, px = t & 63;
        float s1 = 0.f, s2 = 0.f;
#pragma unroll
        for (int c = q * 16; c < q * 16 + 16; ++c) {
            const float v = tile[c][px];
            s1 += v; s2 += v * v;
        }
        ps1[q][px] = s1; ps2[q][px] = s2;
    }
    const int pr0 = t >> 3, cs = (t & 7) * 8;
#pragma unroll
    for (int ps = 0; ps < 2; ++ps) {
        const int pr = pr0 + ps * 32;
        f16x8 vh;
#pragma unroll
        for (int q = 0; q < 8; ++q) vh[q] = (h16)tile[cs + q][pr];
        const size_t o = ((size_t)b * HWN + p0 + pr) * CCH + c0 + cs;
        *(f16x8*)(dhi + o) = vh;
    }
    __syncthreads();
    if (t < 64) {
        const float s1 = ps1[0][t] + ps1[1][t] + ps1[2][t] + ps1[3][t];
        const float s2 = ps2[0][t] + ps2[1][t] + ps2[2][t] + ps2[3][t];
        const size_t gp = (size_t)b * HWN + p0 + t;
        psum[(size_t)(c0 >> 6) * NPIX + gp] = s1;
        psq [(size_t)(c0 >> 6) * NPIX + gp] = s2;
    }
}

// ---------------------------------------------------------------------------
// QKV GEMM: 128x256 tile, BK=64 two-plane LDS, 512 threads (8 waves of 64x64).
// Single fp16 (A x64 scaled). Per-plane layout/swizzle identical to proven
// BK=32 buffer. ks1 MFMA runs after barrier2 to overlap next-tile staging.
// LN stats finished in-block from psum/psq.
// out fp16 = rstd[p]*(acc/64 - mean[p]*s[o]).
__global__ __launch_bounds__(512) void qkv_gemm(const h16* __restrict__ Ahg,
                                                const h16* __restrict__ Bhg,
                                                const float* __restrict__ sv,
                                                const float* __restrict__ psum,
                                                const float* __restrict__ psq,
                                                h16* __restrict__ qout) {
    __shared__ __align__(16) h16 Ah[8192];    // 2 planes x [128][32]
    __shared__ __align__(16) h16 Bh[16384];   // 2 planes x [256][32]
    __shared__ float mnS[256], rsS[256];
    const int tid = threadIdx.x;
    const int om = blockIdx.x * 128;
    const int by0 = blockIdx.y;
    const int by  = (by0 & 7) * 32 + (by0 >> 3);   // bijective XCD chunking (256%8==0)
    const int p0  = by * 256;

    const int srow = tid >> 2;                       // 0..127
    const int skh  = ((tid & 3) ^ (srow & 3)) * 8;   // pre-swizzled source slot
    const size_t a0 = (size_t)(om + srow) * CCH + skh;
    const size_t b0 = (size_t)(p0 + srow) * CCH + skh;

    const int lane = tid & 63;
    const int wv = tid >> 6;
    const int wm = (wv >> 2) * 64, wn = (wv & 3) * 64;
    const int lr = lane & 15, kg = lane >> 4;
    const int swz = (kg ^ (lr & 3)) * 8;

    f32x4 acc[4][4];
#pragma unroll
    for (int i = 0; i < 4; ++i)
#pragma unroll
        for (int j = 0; j < 4; ++j) acc[i][j] = {0.f, 0.f, 0.f, 0.f};

#define STAGE(KC)                                                          \
    do {                                                                   \
        gl_lds16(Ahg + a0 + (KC),                 Ah + tid * 8);           \
        gl_lds16(Ahg + a0 + (KC) + 32,            Ah + 4096 + tid * 8);    \
        gl_lds16(Bhg + b0 + (KC),                 Bh + tid * 8);           \
        gl_lds16(Bhg + b0 + (KC) + 128 * CCH,     Bh + 4096 + tid * 8);    \
        gl_lds16(Bhg + b0 + (KC) + 32,            Bh + 8192 + tid * 8);    \
        gl_lds16(Bhg + b0 + (KC) + 32 + 128 * CCH, Bh + 12288 + tid * 8);  \
    } while (0)

    STAGE(0);
    // fused ln_finish: stats for this block's 256 pixels (coalesced reads,
    // overlapped with tile-0 staging; loop barriers make mnS visible to epilogue)
    if (tid < 256) {
        const int gp = p0 + tid;
        float s1 = 0.f, s2 = 0.f;
#pragma unroll
        for (int cb = 0; cb < 8; ++cb) {
            s1 += psum[(size_t)cb * NPIX + gp];
            s2 += psq [(size_t)cb * NPIX + gp];
        }
        const float m = s1 * (1.f / 512.f);
        float var = s2 * (1.f / 512.f) - m * m;
        var = fmaxf(var, 0.f);
        mnS[tid] = m;
        rsS[tid] = rsqrtf(var + LN_EPS);
    }

#pragma unroll 1
    for (int kc = 0; kc < 512; kc += 64) {
        __syncthreads();   // staged tile visible
        f16x8 a0f[4], b0f[4], a1f[4], b1f[4];
#pragma unroll
        for (int i = 0; i < 4; ++i) {
            a0f[i] = *(const f16x8*)(Ah + (wm + i * 16 + lr) * 32 + swz);
            b0f[i] = *(const f16x8*)(Bh + (wn + i * 16 + lr) * 32 + swz);
        }
#pragma unroll
        for (int i = 0; i < 4; ++i)
#pragma unroll
            for (int j = 0; j < 4; ++j)
                acc[i][j] = __builtin_amdgcn_mfma_f32_16x16x32_f16(a0f[i], b0f[j], acc[i][j], 0, 0, 0);
#pragma unroll
        for (int i = 0; i < 4; ++i) {
            a1f[i] = *(const f16x8*)(Ah + 4096 + (wm + i * 16 + lr) * 32 + swz);
            b1f[i] = *(const f16x8*)(Bh + 8192 + (wn + i * 16 + lr) * 32 + swz);
        }
        __syncthreads();   // all frag reads drained; LDS free to overwrite
        if (kc + 64 < 512) STAGE(kc + 64);   // staging overlaps ks1 MFMA below
#pragma unroll
        for (int i = 0; i < 4; ++i)
#pragma unroll
            for (int j = 0; j < 4; ++j)
                acc[i][j] = __builtin_amdgcn_mfma_f32_16x16x32_f16(a1f[i], b1f[j], acc[i][j], 0, 0, 0);
    }
#undef STAGE

    const int b = p0 >> 12, hw0 = p0 & 4095;
    float mn[4], rs[4];
#pragma unroll
    for (int j = 0; j < 4; ++j) {
        const int px = wn + j * 16 + lr;
        mn[j] = mnS[px]; rs[j] = rsS[px];
    }
#pragma unroll
    for (int i = 0; i < 4; ++i)
#pragma unroll
        for (int r = 0; r < 4; ++r) {
            const int o = om + wm + i * 16 + kg * 4 + r;
            const float so = sv[o];
            h16* dst = qout + ((size_t)b * OC3 + o) * HWN;
#pragma unroll
            for (int j = 0; j < 4; ++j) {
                const int hw = hw0 + wn + j * 16 + lr;
                dst[hw] = (h16)(rs[j] * (acc[i][j][r] * (1.f / 64.f) - mn[j] * so));
            }
        }
}

// ---------------------------------------------------------------------------
// partial context over an n-chunk of 512 with chunk-local softmax max:
// pass 1: m_loc[d] = max over chunk; pass 2 (k L2-warm): pt = sum exp(k-m_loc)*v,
// z[d] = sum exp(k-m_loc). Output per (bh,ci): [64*64 pt][64 z][64 m].
__global__ __launch_bounds__(256) void ctx_partial(const h16* __restrict__ qkv16,
                                                   float* __restrict__ ctp) {
    __shared__ float kt[64][68];
    __shared__ float vt[64][68];

    const int bh = blockIdx.y, ci = blockIdx.x;
    const int b = bh >> 3, h = bh & 7;
    const h16* kb = qkv16 + ((size_t)b * OC3 + CCH  + h * 64) * HWN;
    const h16* vb = qkv16 + ((size_t)b * OC3 + 1024 + h * 64) * HWN;
    const int tid = threadIdx.x;

    const int d  = tid >> 2;
    const int td = tid & 15, te = tid >> 4;

    // pass 1: chunk-local row max (4 threads/row, shfl-combined)
    float mx = -1e30f;
    for (int t = 0; t < 8; ++t) {
        const int n0 = ci * 512 + t * 64;
#pragma unroll
        for (int jj = 0; jj < 2; ++jj) {
            const int nn = (tid & 3) * 8 + jj * 32;
            const f16x8 kv = *(const f16x8*)(kb + (size_t)d * HWN + n0 + nn);
#pragma unroll
            for (int u = 0; u < 8; ++u) mx = fmaxf(mx, (float)kv[u]);
        }
    }
    mx = fmaxf(mx, __shfl_xor(mx, 1));
    mx = fmaxf(mx, __shfl_xor(mx, 2));

    float zt = 0.f;
    float acc[4][4];
#pragma unroll
    for (int i = 0; i < 4; ++i)
#pragma unroll
        for (int j = 0; j < 4; ++j) acc[i][j] = 0.f;

    for (int t = 0; t < 8; ++t) {
        const int n0 = ci * 512 + t * 64;
        __syncthreads();
#pragma unroll
        for (int jj = 0; jj < 2; ++jj) {
            const int nn = (tid & 3) * 8 + jj * 32;
            const f16x8 kv = *(const f16x8*)(kb + (size_t)d * HWN + n0 + nn);
            const f16x8 vv = *(const f16x8*)(vb + (size_t)d * HWN + n0 + nn);
#pragma unroll
            for (int u = 0; u < 8; ++u) {
                const float e = __expf((float)kv[u] - mx);
                zt += e;
                kt[nn + u][d] = e;
                vt[nn + u][d] = (float)vv[u];
            }
        }
        __syncthreads();
#pragma unroll
        for (int nn = 0; nn < 64; ++nn) {
            float kf[4], vf[4];
            *(float4*)kf = *(const float4*)&kt[nn][td * 4];
            *(float4*)vf = *(const float4*)&vt[nn][te * 4];
#pragma unroll
            for (int i = 0; i < 4; ++i)
#pragma unroll
                for (int j = 0; j < 4; ++j)
                    acc[i][j] = fmaf(kf[i], vf[j], acc[i][j]);
        }
    }
    zt += __shfl_xor(zt, 1);
    zt += __shfl_xor(zt, 2);

    float* dst = ctp + ((size_t)bh * 8 + ci) * 4224;
#pragma unroll
    for (int i = 0; i < 4; ++i) {
        const float4 o4 = make_float4(acc[i][0], acc[i][1], acc[i][2], acc[i][3]);
        *(float4*)(dst + (td * 4 + i) * 64 + te * 4) = o4;
    }
    if ((tid & 3) == 0) {
        dst[4096 + d] = zt;
        dst[4160 + d] = mx;
    }
}

// ---------------------------------------------------------------------------
// combine 8 chunk partials with exp(m_loc - M) rescale, normalize:
// ct[d][e] = sum_ci w_ci*pt_ci[d][e] / sum_ci w_ci*z_ci[d],  w = exp(m_loc-M)
__global__ __launch_bounds__(256) void ctx_reduce(const float* __restrict__ ctp,
                                                  float* __restrict__ ct) {
    __shared__ float w[8][64];
    __shared__ float rz[64];
    const int bh = blockIdx.x;
    const int tid = threadIdx.x;
    const float* src = ctp + (size_t)bh * 8 * 4224;
    if (tid < 64) {
        float M = -1e30f;
#pragma unroll
        for (int ci = 0; ci < 8; ++ci)
            M = fmaxf(M, src[(size_t)ci * 4224 + 4160 + tid]);
        float Z = 0.f;
#pragma unroll
        for (int ci = 0; ci < 8; ++ci) {
            const float ww = __expf(src[(size_t)ci * 4224 + 4160 + tid] - M);
            w[ci][tid] = ww;
            Z += ww * src[(size_t)ci * 4224 + 4096 + tid];
        }
        rz[tid] = 1.f / Z;
    }
    __syncthreads();
    float* dst = ct + (size_t)bh * 4096;
    for (int e4 = tid * 4; e4 < 4096; e4 += 1024) {
        const int d = e4 >> 6;
        float4 sum = make_float4(0.f, 0.f, 0.f, 0.f);
#pragma unroll
        for (int ci = 0; ci < 8; ++ci) {
            const float4 v = *(const float4*)(src + (size_t)ci * 4224 + e4);
            const float ww = w[ci][d];
            sum.x += ww * v.x; sum.y += ww * v.y;
            sum.z += ww * v.z; sum.w += ww * v.w;
        }
        const float r = rz[d];
        sum.x *= r; sum.y *= r; sum.z *= r; sum.w *= r;
        *(float4*)(dst + e4) = sum;
    }
}

// ---------------------------------------------------------------------------
// q-softmax(d) * (512*SCALE), out'[e,n] = sum_d ct[d,e]*qtilde[d,n];
// writes at = fp16, TRANSPOSED to [b*4096+n][512] (in ws).
__global__ __launch_bounds__(256) void attn_out(const h16* __restrict__ qkv16,
                                                const float* __restrict__ ct,
                                                h16* __restrict__ at) {
    __shared__ float cts[64][68];
    __shared__ float qt[64][68];

    const int bh = blockIdx.y, ci = blockIdx.x;
    const int b = bh >> 3, h = bh & 7;
    const h16* qb = qkv16 + ((size_t)b * OC3 + h * 64) * HWN;
    const int tid = threadIdx.x;

    for (int i4 = tid * 4; i4 < 4096; i4 += 1024) {
        const float4 v = *(const float4*)(ct + (size_t)bh * 4096 + i4);
        *(float4*)&cts[i4 >> 6][i4 & 63] = v;
    }

    const int d  = tid >> 2;
    const int te = tid & 15, tn = tid >> 4;
    const int rn = tid >> 2, d0q = (tid & 3) * 16;

    for (int t = 0; t < 8; ++t) {
        const int n0 = ci * 512 + t * 64;
        __syncthreads();
#pragma unroll
        for (int jj = 0; jj < 2; ++jj) {
            const int nn = (tid & 3) * 8 + jj * 32;
            const f16x8 qv = *(const f16x8*)(qb + (size_t)d * HWN + n0 + nn);
#pragma unroll
            for (int u = 0; u < 8; ++u) qt[nn + u][d] = (float)qv[u];
        }
        __syncthreads();
        {
            float mx = -1e30f;
#pragma unroll
            for (int dd = 0; dd < 16; ++dd) mx = fmaxf(mx, qt[rn][d0q + dd]);
            mx = fmaxf(mx, __shfl_xor(mx, 1));
            mx = fmaxf(mx, __shfl_xor(mx, 2));
            float sm = 0.f;
#pragma unroll
            for (int dd = 0; dd < 16; ++dd) sm += __expf(qt[rn][d0q + dd] - mx);
            sm += __shfl_xor(sm, 1);
            sm += __shfl_xor(sm, 2);
            const float sc = 512.f * QSCALE / sm;
#pragma unroll
            for (int dd = 0; dd < 16; ++dd)
                qt[rn][d0q + dd] = __expf(qt[rn][d0q + dd] - mx) * sc;
        }
        __syncthreads();
        float acc[4][4];
#pragma unroll
        for (int i = 0; i < 4; ++i)
#pragma unroll
            for (int j = 0; j < 4; ++j) acc[i][j] = 0.f;
#pragma unroll
        for (int dd = 0; dd < 64; ++dd) {
            float cv[4];
            *(float4*)cv = *(const float4*)&cts[dd][te * 4];
            const float q0 = qt[tn * 4 + 0][dd];
            const float q1 = qt[tn * 4 + 1][dd];
            const float q2 = qt[tn * 4 + 2][dd];
            const float q3 = qt[tn * 4 + 3][dd];
#pragma unroll
            for (int i = 0; i < 4; ++i) {
                acc[i][0] = fmaf(cv[i], q0, acc[i][0]);
                acc[i][1] = fmaf(cv[i], q1, acc[i][1]);
                acc[i][2] = fmaf(cv[i], q2, acc[i][2]);
                acc[i][3] = fmaf(cv[i], q3, acc[i][3]);
            }
        }
        __syncthreads();
#pragma unroll
        for (int i = 0; i < 4; ++i)
#pragma unroll
            for (int j = 0; j < 4; ++j)
                qt[tn * 4 + j][te * 4 + i] = acc[i][j];
        __syncthreads();
        {
            const int px = tid >> 2, e0 = (tid & 3) * 16;
            f16x8 vh0, vh1;
#pragma unroll
            for (int u = 0; u < 8; ++u) {
                vh0[u] = (h16)qt[px][e0 + u];
                vh1[u] = (h16)qt[px][e0 + 8 + u];
            }
            const size_t o = ((size_t)b * HWN + n0 + px) * CCH + h * 64 + e0;
            *(f16x8*)(at + o)     = vh0;
            *(f16x8*)(at + o + 8) = vh1;
        }
    }
}

// ---------------------------------------------------------------------------
// Fused out-GEMM + channel LN + residual. Single fp16: (wo_hi, at), K=512.
__global__ __launch_bounds__(512) void out_fused(const h16* __restrict__ wo_hi,
                                                 const h16* __restrict__ at,
                                                 const float* __restrict__ b_out,
                                                 const float* __restrict__ g_out,
                                                 const float* __restrict__ x,
                                                 float* __restrict__ out) {
    __shared__ __align__(16) h16 Alds[512 * 32];
    __shared__ __align__(16) h16 Blds[128 * 32];
    __shared__ float red1[4][128], red2[4][128];
    __shared__ float mnS[128], rsS[128];

    const int tid = threadIdx.x;
    const int p0 = blockIdx.x * 128;
    const int b = p0 >> 12, hw0 = p0 & 4095;

    const int trow = tid >> 2;
    const int skh  = ((tid & 3) ^ (trow & 3)) * 8;
    const size_t aoff = (size_t)trow * CCH + skh;
    const size_t boff = (size_t)p0 * CCH + aoff;
    const int wofs = (tid >> 6) * 512;

    const int wv = tid >> 6;
    const int wm = (wv >> 1) * 128, wn = (wv & 1) * 64;
    const int lane = tid & 63;
    const int lr = lane & 15, kg = lane >> 4;
    const int swz = (kg ^ (lr & 3)) * 8;

    f32x4 acc[8][4];
#pragma unroll
    for (int i = 0; i < 8; ++i)
#pragma unroll
        for (int j = 0; j < 4; ++j) acc[i][j] = {0.f, 0.f, 0.f, 0.f};

#define STAGEF(S)                                                           \
    do {                                                                    \
        const int kc_ = (S) * 32;                                           \
        gl_lds16(wo_hi + aoff + kc_,               Alds + wofs);            \
        gl_lds16(wo_hi + aoff + kc_ + 128 * CCH,   Alds + 4096 + wofs);     \
        gl_lds16(wo_hi + aoff + kc_ + 256 * CCH,   Alds + 8192 + wofs);     \
        gl_lds16(wo_hi + aoff + kc_ + 384 * CCH,   Alds + 12288 + wofs);    \
        gl_lds16(at + boff + kc_,                  Blds + wofs);            \
    } while (0)

    STAGEF(0);
#pragma unroll 1
    for (int s = 0; s < 16; ++s) {
        __syncthreads();
        f16x8 af[8], bf[4];
#pragma unroll
        for (int i = 0; i < 8; ++i)
            af[i] = *(const f16x8*)(Alds + (wm + i * 16 + lr) * 32 + swz);
#pragma unroll
        for (int j = 0; j < 4; ++j)
            bf[j] = *(const f16x8*)(Blds + (wn + j * 16 + lr) * 32 + swz);
        __syncthreads();
        if (s < 15) STAGEF(s + 1);
#pragma unroll
        for (int i = 0; i < 8; ++i)
#pragma unroll
            for (int j = 0; j < 4; ++j)
                acc[i][j] = __builtin_amdgcn_mfma_f32_16x16x32_f16(af[i], bf[j], acc[i][j], 0, 0, 0);
    }
#undef STAGEF

#pragma unroll
    for (int i = 0; i < 8; ++i) {
        const int o = wm + i * 16 + kg * 4;
        const float4 bb = *(const float4*)(b_out + o);
#pragma unroll
        for (int j = 0; j < 4; ++j) {
            acc[i][j][0] = acc[i][j][0] * (1.f / 134217728.f) + bb.x;
            acc[i][j][1] = acc[i][j][1] * (1.f / 134217728.f) + bb.y;
            acc[i][j][2] = acc[i][j][2] * (1.f / 134217728.f) + bb.z;
            acc[i][j][3] = acc[i][j][3] * (1.f / 134217728.f) + bb.w;
        }
    }
    float s1[4], s2[4];
#pragma unroll
    for (int j = 0; j < 4; ++j) {
        s1[j] = 0.f; s2[j] = 0.f;
#pragma unroll
        for (int i = 0; i < 8; ++i)
#pragma unroll
            for (int r = 0; r < 4; ++r) {
                const float v = acc[i][j][r];
                s1[j] += v; s2[j] += v * v;
            }
        s1[j] += __shfl_xor(s1[j], 16); s1[j] += __shfl_xor(s1[j], 32);
        s2[j] += __shfl_xor(s2[j], 16); s2[j] += __shfl_xor(s2[j], 32);
    }
    if (kg == 0) {
#pragma unroll
        for (int j = 0; j < 4; ++j) {
            red1[wv >> 1][wn + j * 16 + lr] = s1[j];
            red2[wv >> 1][wn + j * 16 + lr] = s2[j];
        }
    }
    __syncthreads();
    if (tid < 128) {
        const float S1 = red1[0][tid] + red1[1][tid] + red1[2][tid] + red1[3][tid];
        const float S2 = red2[0][tid] + red2[1][tid] + red2[2][tid] + red2[3][tid];
        const float m = S1 * (1.f / 512.f);
        float var = S2 * (1.f / 512.f) - m * m;
        var = fmaxf(var, 0.f);
        mnS[tid] = m;
        rsS[tid] = rsqrtf(var + LN_EPS);
    }
    __syncthreads();
    float mj[4], rj[4];
#pragma unroll
    for (int j = 0; j < 4; ++j) {
        const int px = wn + j * 16 + lr;
        mj[j] = mnS[px]; rj[j] = rsS[px];
    }
#pragma unroll
    for (int i = 0; i < 8; ++i) {
        const int o = wm + i * 16 + kg * 4;
        const float4 gg = *(const float4*)(g_out + o);
#pragma unroll
        for (int r = 0; r < 4; ++r) {
            const float g = (r == 0) ? gg.x : (r == 1) ? gg.y : (r == 2) ? gg.z : gg.w;
            const float* xr = x + ((size_t)b * CCH + o + r) * HWN + hw0 + wn;
            float* dr = out + ((size_t)b * CCH + o + r) * HWN + hw0 + wn;
#pragma unroll
            for (int j = 0; j < 4; ++j) {
                const int c = j * 16 + lr;
                dr[c] = (acc[i][j][r] - mj[j]) * rj[j] * g + xr[c];
            }
        }
    }
}

// ---------------------------------------------------------------------------
extern "C" void kernel_launch(void* const* d_in, const int* in_sizes, int n_in,
                              void* d_out, int out_size, void* d_ws, size_t ws_size,
                              hipStream_t stream) {
    (void)in_sizes; (void)n_in; (void)out_size;
    const float* x     = (const float*)d_in[0];
    const float* w_qkv = (const float*)d_in[1];
    const float* w_out = (const float*)d_in[2];
    const float* b_out = (const float*)d_in[3];
    const float* g_out = (const float*)d_in[4];
    const float* g_ln  = (const float*)d_in[5];
    float* out = (float*)d_out;
    float* ws  = (float*)d_ws;

    float* s    = ws;                       // 1536
    float* ct   = s + OC3;                  // 524288
    float* ctp  = ct + 524288;              // 4325376 (128 bh x 8 ci x 4224)
    float* psum = ctp;                      // 524288 (alias: dead before ctx)
    float* psq  = psum + 524288;            // 524288
    h16*  wg_hi = (h16*)(ctp + 4325376);    // 786432 halfs
    h16*  wo_hi = wg_hi + 786432;           // 262144 halfs
    h16*  qkv16 = wo_hi + 262144;           // 100663296 halfs (fp16 q,k,v)
    h16*  at    = qkv16 + 100663296;        // 33554432 halfs (attn out, transposed)
    // alias of d_out: xt dead after qkv_gemm (out_fused is sole d_out writer)
    h16*  xt_hi = (h16*)d_out;

    const size_t need = 72484352ULL * 4ULL;   // ~290.0 MB
    if (ws_size < need) return;

    prep_w       <<<2048, 64, 0, stream>>>(w_qkv, g_ln, w_out, wg_hi, s, wo_hi);
    transpose_cvt<<<dim3(64, 8, 16), 256, 0, stream>>>(x, xt_hi, psum, psq);
    qkv_gemm     <<<dim3(12, 256), 512, 0, stream>>>(wg_hi, xt_hi,
                                                     s, psum, psq, qkv16);
    ctx_partial  <<<dim3(8, 128), 256, 0, stream>>>(qkv16, ctp);
    ctx_reduce   <<<128, 256, 0, stream>>>(ctp, ct);
    attn_out     <<<dim3(8, 128), 256, 0, stream>>>(qkv16, ct, at);
    out_fused    <<<512, 512, 0, stream>>>(wo_hi, at,
                                           b_out, g_out, x, out);
}

// Round 16
// 442.538 us; speedup vs baseline: 1.3145x; 1.0224x over previous
//
#include <hip/hip_runtime.h>
#include <math.h>

#define CCH    512
#define HWN    4096
#define NPIX   65536
#define OC3    1536
#define QSCALE 0.125f
#define LN_EPS 1e-5f

typedef _Float16 h16;
typedef h16  f16x8 __attribute__((ext_vector_type(8)));
typedef float f32x4 __attribute__((ext_vector_type(4)));

__device__ __forceinline__ float waveReduceSum(float v) {
#pragma unroll
    for (int off = 32; off; off >>= 1) v += __shfl_xor(v, off);
    return v;
}

__device__ __forceinline__ void gl_lds16(const void* g, void* l) {
    __builtin_amdgcn_global_load_lds((const __attribute__((address_space(1))) void*)g,
                                     (__attribute__((address_space(3))) void*)l, 16, 0, 0);
}

// ---------------------------------------------------------------------------
// merged weight prep (single fp16, x64 scaled):
// o<1536 -> wg = w_qkv*g_ln + row-sum s;  o>=1536 -> wo = w_out
__global__ __launch_bounds__(64) void prep_w(const float* __restrict__ w_qkv,
                                             const float* __restrict__ g_ln,
                                             const float* __restrict__ w_out,
                                             h16* __restrict__ wg_h,
                                             float* __restrict__ s,
                                             h16* __restrict__ wo_h) {
    const int o = blockIdx.x, lane = threadIdx.x;
    if (o < OC3) {
        float sum = 0.f;
#pragma unroll
        for (int j = 0; j < 8; ++j) {
            const int c = lane + j * 64;
            const float w = w_qkv[(size_t)o * CCH + c] * g_ln[c];
            wg_h[(size_t)o * CCH + c] = (h16)(w * 64.f);
            sum += w;
        }
        sum = waveReduceSum(sum);
        if (lane == 0) s[o] = sum;
    } else {
        const int r = o - OC3;
#pragma unroll
        for (int j = 0; j < 8; ++j) {
            const int c = lane + j * 64;
            wo_h[(size_t)r * CCH + c] = (h16)(w_out[(size_t)r * CCH + c] * 64.f);
        }
    }
}

// ---------------------------------------------------------------------------
// fp32 [16][512][4096] -> transposed fp16 [16][4096][512]
// + per-(channel-block, pixel) LN partial sums (deterministic 2-stage stats)
__global__ __launch_bounds__(256) void transpose_cvt(const float* __restrict__ src,
                                                     h16* __restrict__ dhi,
                                                     float* __restrict__ psum,
                                                     float* __restrict__ psq) {
    __shared__ float tile[64][65];
    __shared__ float ps1[4][64], ps2[4][64];
    const int b = blockIdx.z, c0 = blockIdx.y * 64, p0 = blockIdx.x * 64;
    const int t = threadIdx.x;
    const float* sb = src + ((size_t)b * CCH + c0) * HWN + p0;
    const int rc = t >> 4, cc4 = (t & 15) * 4;
#pragma unroll
    for (int ps = 0; ps < 4; ++ps) {
        const float4 v = *(const float4*)(sb + (size_t)(rc + ps * 16) * HWN + cc4);
        tile[rc + ps * 16][cc4 + 0] = v.x;
        tile[rc + ps * 16][cc4 + 1] = v.y;
        tile[rc + ps * 16][cc4 + 2] = v.z;
        tile[rc + ps * 16][cc4 + 3] = v.w;
    }
    __syncthreads();
    {
        const int q = t >> 6, px = t & 63;
        float s1 = 0.f, s2 = 0.f;
#pragma unroll
        for (int c = q * 16; c < q * 16 + 16; ++c) {
            const float v = tile[c][px];
            s1 += v; s2 += v * v;
        }
        ps1[q][px] = s1; ps2[q][px] = s2;
    }
    const int pr0 = t >> 3, cs = (t & 7) * 8;
#pragma unroll
    for (int ps = 0; ps < 2; ++ps) {
        const int pr = pr0 + ps * 32;
        f16x8 vh;
#pragma unroll
        for (int q = 0; q < 8; ++q) vh[q] = (h16)tile[cs + q][pr];
        const size_t o = ((size_t)b * HWN + p0 + pr) * CCH + c0 + cs;
        *(f16x8*)(dhi + o) = vh;
    }
    __syncthreads();
    if (t < 64) {
        const float s1 = ps1[0][t] + ps1[1][t] + ps1[2][t] + ps1[3][t];
        const float s2 = ps2[0][t] + ps2[1][t] + ps2[2][t] + ps2[3][t];
        const size_t gp = (size_t)b * HWN + p0 + t;
        psum[(size_t)(c0 >> 6) * NPIX + gp] = s1;
        psq [(size_t)(c0 >> 6) * NPIX + gp] = s2;
    }
}

// ---------------------------------------------------------------------------
// QKV GEMM: 128x256 tile, BK=64 two-plane LDS, 512 threads (8 waves of 64x64).
// Single fp16 (A x64 scaled). LN stats finished in-block from psum/psq.
// out fp16 = rstd[p]*(acc/64 - mean[p]*s[o]).
// k-blocks (blockIdx.x in [4,8)) additionally emit per-row max over each
// 64-pixel group: km[b*512 + kchan][pxblk64]  (consumed by ctx_partial).
__global__ __launch_bounds__(512) void qkv_gemm(const h16* __restrict__ Ahg,
                                                const h16* __restrict__ Bhg,
                                                const float* __restrict__ sv,
                                                const float* __restrict__ psum,
                                                const float* __restrict__ psq,
                                                h16* __restrict__ qout,
                                                float* __restrict__ km) {
    __shared__ __align__(16) h16 Ah[8192];    // 2 planes x [128][32]
    __shared__ __align__(16) h16 Bh[16384];   // 2 planes x [256][32]
    __shared__ float mnS[256], rsS[256];
    const int tid = threadIdx.x;
    const int om = blockIdx.x * 128;
    const int by0 = blockIdx.y;
    const int by  = (by0 & 7) * 32 + (by0 >> 3);   // bijective XCD chunking (256%8==0)
    const int p0  = by * 256;

    const int srow = tid >> 2;
    const int skh  = ((tid & 3) ^ (srow & 3)) * 8;
    const size_t a0 = (size_t)(om + srow) * CCH + skh;
    const size_t b0 = (size_t)(p0 + srow) * CCH + skh;

    const int lane = tid & 63;
    const int wv = tid >> 6;
    const int wm = (wv >> 2) * 64, wn = (wv & 3) * 64;
    const int lr = lane & 15, kg = lane >> 4;
    const int swz = (kg ^ (lr & 3)) * 8;

    f32x4 acc[4][4];
#pragma unroll
    for (int i = 0; i < 4; ++i)
#pragma unroll
        for (int j = 0; j < 4; ++j) acc[i][j] = {0.f, 0.f, 0.f, 0.f};

#define STAGE(KC)                                                          \
    do {                                                                   \
        gl_lds16(Ahg + a0 + (KC),                 Ah + tid * 8);           \
        gl_lds16(Ahg + a0 + (KC) + 32,            Ah + 4096 + tid * 8);    \
        gl_lds16(Bhg + b0 + (KC),                 Bh + tid * 8);           \
        gl_lds16(Bhg + b0 + (KC) + 128 * CCH,     Bh + 4096 + tid * 8);    \
        gl_lds16(Bhg + b0 + (KC) + 32,            Bh + 8192 + tid * 8);    \
        gl_lds16(Bhg + b0 + (KC) + 32 + 128 * CCH, Bh + 12288 + tid * 8);  \
    } while (0)

    STAGE(0);
    if (tid < 256) {
        const int gp = p0 + tid;
        float s1 = 0.f, s2 = 0.f;
#pragma unroll
        for (int cb = 0; cb < 8; ++cb) {
            s1 += psum[(size_t)cb * NPIX + gp];
            s2 += psq [(size_t)cb * NPIX + gp];
        }
        const float m = s1 * (1.f / 512.f);
        float var = s2 * (1.f / 512.f) - m * m;
        var = fmaxf(var, 0.f);
        mnS[tid] = m;
        rsS[tid] = rsqrtf(var + LN_EPS);
    }

#pragma unroll 1
    for (int kc = 0; kc < 512; kc += 64) {
        __syncthreads();
        f16x8 a0f[4], b0f[4], a1f[4], b1f[4];
#pragma unroll
        for (int i = 0; i < 4; ++i) {
            a0f[i] = *(const f16x8*)(Ah + (wm + i * 16 + lr) * 32 + swz);
            b0f[i] = *(const f16x8*)(Bh + (wn + i * 16 + lr) * 32 + swz);
        }
#pragma unroll
        for (int i = 0; i < 4; ++i)
#pragma unroll
            for (int j = 0; j < 4; ++j)
                acc[i][j] = __builtin_amdgcn_mfma_f32_16x16x32_f16(a0f[i], b0f[j], acc[i][j], 0, 0, 0);
#pragma unroll
        for (int i = 0; i < 4; ++i) {
            a1f[i] = *(const f16x8*)(Ah + 4096 + (wm + i * 16 + lr) * 32 + swz);
            b1f[i] = *(const f16x8*)(Bh + 8192 + (wn + i * 16 + lr) * 32 + swz);
        }
        __syncthreads();
        if (kc + 64 < 512) STAGE(kc + 64);
#pragma unroll
        for (int i = 0; i < 4; ++i)
#pragma unroll
            for (int j = 0; j < 4; ++j)
                acc[i][j] = __builtin_amdgcn_mfma_f32_16x16x32_f16(a1f[i], b1f[j], acc[i][j], 0, 0, 0);
    }
#undef STAGE

    const int b = p0 >> 12, hw0 = p0 & 4095;
    const bool isK = (blockIdx.x >= 4 && blockIdx.x < 8);
    float mn[4], rs[4];
#pragma unroll
    for (int j = 0; j < 4; ++j) {
        const int px = wn + j * 16 + lr;
        mn[j] = mnS[px]; rs[j] = rsS[px];
    }
#pragma unroll
    for (int i = 0; i < 4; ++i)
#pragma unroll
        for (int r = 0; r < 4; ++r) {
            const int o = om + wm + i * 16 + kg * 4 + r;
            const float so = sv[o];
            h16* dst = qout + ((size_t)b * OC3 + o) * HWN;
            float mx = -1e30f;
#pragma unroll
            for (int j = 0; j < 4; ++j) {
                const int hw = hw0 + wn + j * 16 + lr;
                const float val = rs[j] * (acc[i][j][r] * (1.f / 64.f) - mn[j] * so);
                dst[hw] = (h16)val;
                mx = fmaxf(mx, val);
            }
            if (isK) {
                mx = fmaxf(mx, __shfl_xor(mx, 1));
                mx = fmaxf(mx, __shfl_xor(mx, 2));
                mx = fmaxf(mx, __shfl_xor(mx, 4));
                mx = fmaxf(mx, __shfl_xor(mx, 8));
                if (lr == 0)
                    km[(size_t)(b * 512 + (o - CCH)) * 64 + (p0 >> 6) + (wn >> 6)] = mx;
            }
        }
}

// ---------------------------------------------------------------------------
// MFMA context partial over a 256-pixel chunk (1 wave, no LDS, no barriers):
// pt[d][e] = sum_n exp16(k[d][n]-m[d]) * v[e][n];  z[d] = sum exp (f32).
// m[d] = max of 4 km entries (64-px row maxes from qkv epilogue).
// Output per (bh,ci): [4096 pt][64 z][64 m], stride 4224.
__global__ __launch_bounds__(64) void ctx_partial(const h16* __restrict__ qkv16,
                                                  const float* __restrict__ km,
                                                  float* __restrict__ ctp) {
    const int bh = blockIdx.y, ci = blockIdx.x;   // ci 0..15
    const int b = bh >> 3, h = bh & 7;
    const h16* kb = qkv16 + ((size_t)b * OC3 + CCH  + h * 64) * HWN;
    const h16* vb = qkv16 + ((size_t)b * OC3 + 1024 + h * 64) * HWN;
    const int lane = threadIdx.x;
    const int lr = lane & 15, kg = lane >> 4;

    float m[4];
#pragma unroll
    for (int i = 0; i < 4; ++i) {
        const float* kmr = km + ((size_t)bh * 64 + i * 16 + lr) * 64 + ci * 4;
        m[i] = fmaxf(fmaxf(kmr[0], kmr[1]), fmaxf(kmr[2], kmr[3]));
    }
    float z[4] = {0.f, 0.f, 0.f, 0.f};
    f32x4 acc[4][4];
#pragma unroll
    for (int i = 0; i < 4; ++i)
#pragma unroll
        for (int j = 0; j < 4; ++j) acc[i][j] = {0.f, 0.f, 0.f, 0.f};

    const int nbase = ci * 256 + kg * 8;
#pragma unroll 1
    for (int c = 0; c < 8; ++c) {
        const int n0 = nbase + c * 32;
        f16x8 ke[4], vf[4];
#pragma unroll
        for (int j = 0; j < 4; ++j)
            vf[j] = *(const f16x8*)(vb + (size_t)(j * 16 + lr) * HWN + n0);
#pragma unroll
        for (int i = 0; i < 4; ++i) {
            const f16x8 kv = *(const f16x8*)(kb + (size_t)(i * 16 + lr) * HWN + n0);
            f16x8 t;
#pragma unroll
            for (int u = 0; u < 8; ++u) {
                const float e = __expf((float)kv[u] - m[i]);
                z[i] += e;
                t[u] = (h16)e;
            }
            ke[i] = t;
        }
#pragma unroll
        for (int i = 0; i < 4; ++i)
#pragma unroll
            for (int j = 0; j < 4; ++j)
                acc[i][j] = __builtin_amdgcn_mfma_f32_16x16x32_f16(ke[i], vf[j], acc[i][j], 0, 0, 0);
    }
#pragma unroll
    for (int i = 0; i < 4; ++i) {
        z[i] += __shfl_xor(z[i], 16);
        z[i] += __shfl_xor(z[i], 32);
    }
    float* dst = ctp + ((size_t)bh * 16 + ci) * 4224;
#pragma unroll
    for (int i = 0; i < 4; ++i)
#pragma unroll
        for (int j = 0; j < 4; ++j)
#pragma unroll
            for (int r = 0; r < 4; ++r)
                dst[(i * 16 + kg * 4 + r) * 64 + j * 16 + lr] = acc[i][j][r];
    if (kg == 0)
#pragma unroll
        for (int i = 0; i < 4; ++i) {
            dst[4096 + i * 16 + lr] = z[i];
            dst[4160 + i * 16 + lr] = m[i];
        }
}

// ---------------------------------------------------------------------------
// combine 16 chunk partials with exp(m_loc - M) rescale, normalize:
// ct[d][e] = sum_ci w_ci*pt_ci[d][e] / sum_ci w_ci*z_ci[d],  w = exp(m_loc-M)
__global__ __launch_bounds__(256) void ctx_reduce(const float* __restrict__ ctp,
                                                  float* __restrict__ ct) {
    __shared__ float w[16][64];
    __shared__ float rz[64];
    const int bh = blockIdx.x;
    const int tid = threadIdx.x;
    const float* src = ctp + (size_t)bh * 16 * 4224;
    if (tid < 64) {
        float M = -1e30f;
#pragma unroll
        for (int ci = 0; ci < 16; ++ci)
            M = fmaxf(M, src[(size_t)ci * 4224 + 4160 + tid]);
        float Z = 0.f;
#pragma unroll
        for (int ci = 0; ci < 16; ++ci) {
            const float ww = __expf(src[(size_t)ci * 4224 + 4160 + tid] - M);
            w[ci][tid] = ww;
            Z += ww * src[(size_t)ci * 4224 + 4096 + tid];
        }
        rz[tid] = 1.f / Z;
    }
    __syncthreads();
    float* dst = ct + (size_t)bh * 4096;
    for (int e4 = tid * 4; e4 < 4096; e4 += 1024) {
        const int d = e4 >> 6;
        float4 sum = make_float4(0.f, 0.f, 0.f, 0.f);
#pragma unroll
        for (int ci = 0; ci < 16; ++ci) {
            const float4 v = *(const float4*)(src + (size_t)ci * 4224 + e4);
            const float ww = w[ci][d];
            sum.x += ww * v.x; sum.y += ww * v.y;
            sum.z += ww * v.z; sum.w += ww * v.w;
        }
        const float r = rz[d];
        sum.x *= r; sum.y *= r; sum.z *= r; sum.w *= r;
        *(float4*)(dst + e4) = sum;
    }
}

// ---------------------------------------------------------------------------
// q-softmax(d) * (512*SCALE), out'[e,n] = sum_d ct[d,e]*qtilde[d,n];
// writes at = fp16, TRANSPOSED to [b*4096+n][512] (in ws).
__global__ __launch_bounds__(256) void attn_out(const h16* __restrict__ qkv16,
                                                const float* __restrict__ ct,
                                                h16* __restrict__ at) {
    __shared__ float cts[64][68];
    __shared__ float qt[64][68];

    const int bh = blockIdx.y, ci = blockIdx.x;
    const int b = bh >> 3, h = bh & 7;
    const h16* qb = qkv16 + ((size_t)b * OC3 + h * 64) * HWN;
    const int tid = threadIdx.x;

    for (int i4 = tid * 4; i4 < 4096; i4 += 1024) {
        const float4 v = *(const float4*)(ct + (size_t)bh * 4096 + i4);
        *(float4*)&cts[i4 >> 6][i4 & 63] = v;
    }

    const int d  = tid >> 2;
    const int te = tid & 15, tn = tid >> 4;
    const int rn = tid >> 2, d0q = (tid & 3) * 16;

    for (int t = 0; t < 8; ++t) {
        const int n0 = ci * 512 + t * 64;
        __syncthreads();
#pragma unroll
        for (int jj = 0; jj < 2; ++jj) {
            const int nn = (tid & 3) * 8 + jj * 32;
            const f16x8 qv = *(const f16x8*)(qb + (size_t)d * HWN + n0 + nn);
#pragma unroll
            for (int u = 0; u < 8; ++u) qt[nn + u][d] = (float)qv[u];
        }
        __syncthreads();
        {
            float mx = -1e30f;
#pragma unroll
            for (int dd = 0; dd < 16; ++dd) mx = fmaxf(mx, qt[rn][d0q + dd]);
            mx = fmaxf(mx, __shfl_xor(mx, 1));
            mx = fmaxf(mx, __shfl_xor(mx, 2));
            float sm = 0.f;
#pragma unroll
            for (int dd = 0; dd < 16; ++dd) sm += __expf(qt[rn][d0q + dd] - mx);
            sm += __shfl_xor(sm, 1);
            sm += __shfl_xor(sm, 2);
            const float sc = 512.f * QSCALE / sm;
#pragma unroll
            for (int dd = 0; dd < 16; ++dd)
                qt[rn][d0q + dd] = __expf(qt[rn][d0q + dd] - mx) * sc;
        }
        __syncthreads();
        float acc[4][4];
#pragma unroll
        for (int i = 0; i < 4; ++i)
#pragma unroll
            for (int j = 0; j < 4; ++j) acc[i][j] = 0.f;
#pragma unroll
        for (int dd = 0; dd < 64; ++dd) {
            float cv[4];
            *(float4*)cv = *(const float4*)&cts[dd][te * 4];
            const float q0 = qt[tn * 4 + 0][dd];
            const float q1 = qt[tn * 4 + 1][dd];
            const float q2 = qt[tn * 4 + 2][dd];
            const float q3 = qt[tn * 4 + 3][dd];
#pragma unroll
            for (int i = 0; i < 4; ++i) {
                acc[i][0] = fmaf(cv[i], q0, acc[i][0]);
                acc[i][1] = fmaf(cv[i], q1, acc[i][1]);
                acc[i][2] = fmaf(cv[i], q2, acc[i][2]);
                acc[i][3] = fmaf(cv[i], q3, acc[i][3]);
            }
        }
        __syncthreads();
#pragma unroll
        for (int i = 0; i < 4; ++i)
#pragma unroll
            for (int j = 0; j < 4; ++j)
                qt[tn * 4 + j][te * 4 + i] = acc[i][j];
        __syncthreads();
        {
            const int px = tid >> 2, e0 = (tid & 3) * 16;
            f16x8 vh0, vh1;
#pragma unroll
            for (int u = 0; u < 8; ++u) {
                vh0[u] = (h16)qt[px][e0 + u];
                vh1[u] = (h16)qt[px][e0 + 8 + u];
            }
            const size_t o = ((size_t)b * HWN + n0 + px) * CCH + h * 64 + e0;
            *(f16x8*)(at + o)     = vh0;
            *(f16x8*)(at + o + 8) = vh1;
        }
    }
}

// ---------------------------------------------------------------------------
// Fused out-GEMM + channel LN + residual. Single fp16: (wo_hi, at), K=512.
__global__ __launch_bounds__(512) void out_fused(const h16* __restrict__ wo_hi,
                                                 const h16* __restrict__ at,
                                                 const float* __restrict__ b_out,
                                                 const float* __restrict__ g_out,
                                                 const float* __restrict__ x,
                                                 float* __restrict__ out) {
    __shared__ __align__(16) h16 Alds[512 * 32];
    __shared__ __align__(16) h16 Blds[128 * 32];
    __shared__ float red1[4][128], red2[4][128];
    __shared__ float mnS[128], rsS[128];

    const int tid = threadIdx.x;
    const int p0 = blockIdx.x * 128;
    const int b = p0 >> 12, hw0 = p0 & 4095;

    const int trow = tid >> 2;
    const int skh  = ((tid & 3) ^ (trow & 3)) * 8;
    const size_t aoff = (size_t)trow * CCH + skh;
    const size_t boff = (size_t)p0 * CCH + aoff;
    const int wofs = (tid >> 6) * 512;

    const int wv = tid >> 6;
    const int wm = (wv >> 1) * 128, wn = (wv & 1) * 64;
    const int lane = tid & 63;
    const int lr = lane & 15, kg = lane >> 4;
    const int swz = (kg ^ (lr & 3)) * 8;

    f32x4 acc[8][4];
#pragma unroll
    for (int i = 0; i < 8; ++i)
#pragma unroll
        for (int j = 0; j < 4; ++j) acc[i][j] = {0.f, 0.f, 0.f, 0.f};

#define STAGEF(S)                                                           \
    do {                                                                    \
        const int kc_ = (S) * 32;                                           \
        gl_lds16(wo_hi + aoff + kc_,               Alds + wofs);            \
        gl_lds16(wo_hi + aoff + kc_ + 128 * CCH,   Alds + 4096 + wofs);     \
        gl_lds16(wo_hi + aoff + kc_ + 256 * CCH,   Alds + 8192 + wofs);     \
        gl_lds16(wo_hi + aoff + kc_ + 384 * CCH,   Alds + 12288 + wofs);    \
        gl_lds16(at + boff + kc_,                  Blds + wofs);            \
    } while (0)

    STAGEF(0);
#pragma unroll 1
    for (int s = 0; s < 16; ++s) {
        __syncthreads();
        f16x8 af[8], bf[4];
#pragma unroll
        for (int i = 0; i < 8; ++i)
            af[i] = *(const f16x8*)(Alds + (wm + i * 16 + lr) * 32 + swz);
#pragma unroll
        for (int j = 0; j < 4; ++j)
            bf[j] = *(const f16x8*)(Blds + (wn + j * 16 + lr) * 32 + swz);
        __syncthreads();
        if (s < 15) STAGEF(s + 1);
#pragma unroll
        for (int i = 0; i < 8; ++i)
#pragma unroll
            for (int j = 0; j < 4; ++j)
                acc[i][j] = __builtin_amdgcn_mfma_f32_16x16x32_f16(af[i], bf[j], acc[i][j], 0, 0, 0);
    }
#undef STAGEF

#pragma unroll
    for (int i = 0; i < 8; ++i) {
        const int o = wm + i * 16 + kg * 4;
        const float4 bb = *(const float4*)(b_out + o);
#pragma unroll
        for (int j = 0; j < 4; ++j) {
            acc[i][j][0] = acc[i][j][0] * (1.f / 134217728.f) + bb.x;
            acc[i][j][1] = acc[i][j][1] * (1.f / 134217728.f) + bb.y;
            acc[i][j][2] = acc[i][j][2] * (1.f / 134217728.f) + bb.z;
            acc[i][j][3] = acc[i][j][3] * (1.f / 134217728.f) + bb.w;
        }
    }
    float s1[4], s2[4];
#pragma unroll
    for (int j = 0; j < 4; ++j) {
        s1[j] = 0.f; s2[j] = 0.f;
#pragma unroll
        for (int i = 0; i < 8; ++i)
#pragma unroll
            for (int r = 0; r < 4; ++r) {
                const float v = acc[i][j][r];
                s1[j] += v; s2[j] += v * v;
            }
        s1[j] += __shfl_xor(s1[j], 16); s1[j] += __shfl_xor(s1[j], 32);
        s2[j] += __shfl_xor(s2[j], 16); s2[j] += __shfl_xor(s2[j], 32);
    }
    if (kg == 0) {
#pragma unroll
        for (int j = 0; j < 4; ++j) {
            red1[wv >> 1][wn + j * 16 + lr] = s1[j];
            red2[wv >> 1][wn + j * 16 + lr] = s2[j];
        }
    }
    __syncthreads();
    if (tid < 128) {
        const float S1 = red1[0][tid] + red1[1][tid] + red1[2][tid] + red1[3][tid];
        const float S2 = red2[0][tid] + red2[1][tid] + red2[2][tid] + red2[3][tid];
        const float m = S1 * (1.f / 512.f);
        float var = S2 * (1.f / 512.f) - m * m;
        var = fmaxf(var, 0.f);
        mnS[tid] = m;
        rsS[tid] = rsqrtf(var + LN_EPS);
    }
    __syncthreads();
    float mj[4], rj[4];
#pragma unroll
    for (int j = 0; j < 4; ++j) {
        const int px = wn + j * 16 + lr;
        mj[j] = mnS[px]; rj[j] = rsS[px];
    }
#pragma unroll
    for (int i = 0; i < 8; ++i) {
        const int o = wm + i * 16 + kg * 4;
        const float4 gg = *(const float4*)(g_out + o);
#pragma unroll
        for (int r = 0; r < 4; ++r) {
            const float g = (r == 0) ? gg.x : (r == 1) ? gg.y : (r == 2) ? gg.z : gg.w;
            const float* xr = x + ((size_t)b * CCH + o + r) * HWN + hw0 + wn;
            float* dr = out + ((size_t)b * CCH + o + r) * HWN + hw0 + wn;
#pragma unroll
            for (int j = 0; j < 4; ++j) {
                const int c = j * 16 + lr;
                dr[c] = (acc[i][j][r] - mj[j]) * rj[j] * g + xr[c];
            }
        }
    }
}

// ---------------------------------------------------------------------------
extern "C" void kernel_launch(void* const* d_in, const int* in_sizes, int n_in,
                              void* d_out, int out_size, void* d_ws, size_t ws_size,
                              hipStream_t stream) {
    (void)in_sizes; (void)n_in; (void)out_size;
    const float* x     = (const float*)d_in[0];
    const float* w_qkv = (const float*)d_in[1];
    const float* w_out = (const float*)d_in[2];
    const float* b_out = (const float*)d_in[3];
    const float* g_out = (const float*)d_in[4];
    const float* g_ln  = (const float*)d_in[5];
    float* out = (float*)d_out;
    float* ws  = (float*)d_ws;

    float* s    = ws;                       // 1536
    float* ct   = s + OC3;                  // 524288
    float* km   = ct + 524288;              // 524288 (128 bh x 64 d x 64 pxblk)
    float* ctp  = km + 524288;              // 8650752 (128 bh x 16 ci x 4224)
    float* psum = ctp;                      // 524288 (alias: dead before ctx)
    float* psq  = psum + 524288;            // 524288
    h16*  wg_hi = (h16*)(ctp + 8650752);    // 786432 halfs
    h16*  wo_hi = wg_hi + 786432;           // 262144 halfs
    h16*  qkv16 = wo_hi + 262144;           // 100663296 halfs (fp16 q,k,v)
    h16*  at    = qkv16 + 100663296;        // 33554432 halfs (attn out, transposed)
    // alias of d_out: xt dead after qkv_gemm (out_fused is sole d_out writer)
    h16*  xt_hi = (h16*)d_out;

    const size_t need = 77334016ULL * 4ULL;   // ~309.3 MB
    if (ws_size < need) return;

    prep_w       <<<2048, 64, 0, stream>>>(w_qkv, g_ln, w_out, wg_hi, s, wo_hi);
    transpose_cvt<<<dim3(64, 8, 16), 256, 0, stream>>>(x, xt_hi, psum, psq);
    qkv_gemm     <<<dim3(12, 256), 512, 0, stream>>>(wg_hi, xt_hi,
                                                     s, psum, psq, qkv16, km);
    ctx_partial  <<<dim3(16, 128), 64, 0, stream>>>(qkv16, km, ctp);
    ctx_reduce   <<<128, 256, 0, stream>>>(ctp, ct);
    attn_out     <<<dim3(8, 128), 256, 0, stream>>>(qkv16, ct, at);
    out_fused    <<<512, 512, 0, stream>>>(wo_hi, at,
                                           b_out, g_out, x, out);
}

// Round 17
// 433.432 us; speedup vs baseline: 1.3421x; 1.0210x over previous
//
#include <hip/hip_runtime.h>
#include <math.h>

#define CCH    512
#define HWN    4096
#define NPIX   65536
#define OC3    1536
#define QSCALE 0.125f
#define LN_EPS 1e-5f

typedef _Float16 h16;
typedef h16  f16x8 __attribute__((ext_vector_type(8)));
typedef float f32x4 __attribute__((ext_vector_type(4)));

__device__ __forceinline__ float waveReduceSum(float v) {
#pragma unroll
    for (int off = 32; off; off >>= 1) v += __shfl_xor(v, off);
    return v;
}

__device__ __forceinline__ void gl_lds16(const void* g, void* l) {
    __builtin_amdgcn_global_load_lds((const __attribute__((address_space(1))) void*)g,
                                     (__attribute__((address_space(3))) void*)l, 16, 0, 0);
}

// ---------------------------------------------------------------------------
// merged weight prep (single fp16, x64 scaled):
// o<1536 -> wg = w_qkv*g_ln + row-sum s;  o>=1536 -> wo = w_out
__global__ __launch_bounds__(64) void prep_w(const float* __restrict__ w_qkv,
                                             const float* __restrict__ g_ln,
                                             const float* __restrict__ w_out,
                                             h16* __restrict__ wg_h,
                                             float* __restrict__ s,
                                             h16* __restrict__ wo_h) {
    const int o = blockIdx.x, lane = threadIdx.x;
    if (o < OC3) {
        float sum = 0.f;
#pragma unroll
        for (int j = 0; j < 8; ++j) {
            const int c = lane + j * 64;
            const float w = w_qkv[(size_t)o * CCH + c] * g_ln[c];
            wg_h[(size_t)o * CCH + c] = (h16)(w * 64.f);
            sum += w;
        }
        sum = waveReduceSum(sum);
        if (lane == 0) s[o] = sum;
    } else {
        const int r = o - OC3;
#pragma unroll
        for (int j = 0; j < 8; ++j) {
            const int c = lane + j * 64;
            wo_h[(size_t)r * CCH + c] = (h16)(w_out[(size_t)r * CCH + c] * 64.f);
        }
    }
}

// ---------------------------------------------------------------------------
// fp32 [16][512][4096] -> transposed fp16 [16][4096][512]
// + per-(channel-block, pixel) LN partial sums (deterministic 2-stage stats)
__global__ __launch_bounds__(256) void transpose_cvt(const float* __restrict__ src,
                                                     h16* __restrict__ dhi,
                                                     float* __restrict__ psum,
                                                     float* __restrict__ psq) {
    __shared__ float tile[64][65];
    __shared__ float ps1[4][64], ps2[4][64];
    const int b = blockIdx.z, c0 = blockIdx.y * 64, p0 = blockIdx.x * 64;
    const int t = threadIdx.x;
    const float* sb = src + ((size_t)b * CCH + c0) * HWN + p0;
    const int rc = t >> 4, cc4 = (t & 15) * 4;
#pragma unroll
    for (int ps = 0; ps < 4; ++ps) {
        const float4 v = *(const float4*)(sb + (size_t)(rc + ps * 16) * HWN + cc4);
        tile[rc + ps * 16][cc4 + 0] = v.x;
        tile[rc + ps * 16][cc4 + 1] = v.y;
        tile[rc + ps * 16][cc4 + 2] = v.z;
        tile[rc + ps * 16][cc4 + 3] = v.w;
    }
    __syncthreads();
    {
        const int q = t >> 6, px = t & 63;
        float s1 = 0.f, s2 = 0.f;
#pragma unroll
        for (int c = q * 16; c < q * 16 + 16; ++c) {
            const float v = tile[c][px];
            s1 += v; s2 += v * v;
        }
        ps1[q][px] = s1; ps2[q][px] = s2;
    }
    const int pr0 = t >> 3, cs = (t & 7) * 8;
#pragma unroll
    for (int ps = 0; ps < 2; ++ps) {
        const int pr = pr0 + ps * 32;
        f16x8 vh;
#pragma unroll
        for (int q = 0; q < 8; ++q) vh[q] = (h16)tile[cs + q][pr];
        const size_t o = ((size_t)b * HWN + p0 + pr) * CCH + c0 + cs;
        *(f16x8*)(dhi + o) = vh;
    }
    __syncthreads();
    if (t < 64) {
        const float s1 = ps1[0][t] + ps1[1][t] + ps1[2][t] + ps1[3][t];
        const float s2 = ps2[0][t] + ps2[1][t] + ps2[2][t] + ps2[3][t];
        const size_t gp = (size_t)b * HWN + p0 + t;
        psum[(size_t)(c0 >> 6) * NPIX + gp] = s1;
        psq [(size_t)(c0 >> 6) * NPIX + gp] = s2;
    }
}

// ---------------------------------------------------------------------------
// QKV GEMM: 128x256 tile, BK=64 two-plane LDS, 512 threads (8 waves of 64x64).
// Single fp16 (A x64 scaled). LN stats finished in-block from psum/psq.
// out fp16 = rstd[p]*(acc/64 - mean[p]*s[o]).
__global__ __launch_bounds__(512) void qkv_gemm(const h16* __restrict__ Ahg,
                                                const h16* __restrict__ Bhg,
                                                const float* __restrict__ sv,
                                                const float* __restrict__ psum,
                                                const float* __restrict__ psq,
                                                h16* __restrict__ qout) {
    __shared__ __align__(16) h16 Ah[8192];    // 2 planes x [128][32]
    __shared__ __align__(16) h16 Bh[16384];   // 2 planes x [256][32]
    __shared__ float mnS[256], rsS[256];
    const int tid = threadIdx.x;
    const int om = blockIdx.x * 128;
    const int by0 = blockIdx.y;
    const int by  = (by0 & 7) * 32 + (by0 >> 3);   // bijective XCD chunking (256%8==0)
    const int p0  = by * 256;

    const int srow = tid >> 2;
    const int skh  = ((tid & 3) ^ (srow & 3)) * 8;
    const size_t a0 = (size_t)(om + srow) * CCH + skh;
    const size_t b0 = (size_t)(p0 + srow) * CCH + skh;

    const int lane = tid & 63;
    const int wv = tid >> 6;
    const int wm = (wv >> 2) * 64, wn = (wv & 3) * 64;
    const int lr = lane & 15, kg = lane >> 4;
    const int swz = (kg ^ (lr & 3)) * 8;

    f32x4 acc[4][4];
#pragma unroll
    for (int i = 0; i < 4; ++i)
#pragma unroll
        for (int j = 0; j < 4; ++j) acc[i][j] = {0.f, 0.f, 0.f, 0.f};

#define STAGE(KC)                                                          \
    do {                                                                   \
        gl_lds16(Ahg + a0 + (KC),                 Ah + tid * 8);           \
        gl_lds16(Ahg + a0 + (KC) + 32,            Ah + 4096 + tid * 8);    \
        gl_lds16(Bhg + b0 + (KC),                 Bh + tid * 8);           \
        gl_lds16(Bhg + b0 + (KC) + 128 * CCH,     Bh + 4096 + tid * 8);    \
        gl_lds16(Bhg + b0 + (KC) + 32,            Bh + 8192 + tid * 8);    \
        gl_lds16(Bhg + b0 + (KC) + 32 + 128 * CCH, Bh + 12288 + tid * 8);  \
    } while (0)

    STAGE(0);
    if (tid < 256) {
        const int gp = p0 + tid;
        float s1 = 0.f, s2 = 0.f;
#pragma unroll
        for (int cb = 0; cb < 8; ++cb) {
            s1 += psum[(size_t)cb * NPIX + gp];
            s2 += psq [(size_t)cb * NPIX + gp];
        }
        const float m = s1 * (1.f / 512.f);
        float var = s2 * (1.f / 512.f) - m * m;
        var = fmaxf(var, 0.f);
        mnS[tid] = m;
        rsS[tid] = rsqrtf(var + LN_EPS);
    }

#pragma unroll 1
    for (int kc = 0; kc < 512; kc += 64) {
        __syncthreads();
        f16x8 a0f[4], b0f[4], a1f[4], b1f[4];
#pragma unroll
        for (int i = 0; i < 4; ++i) {
            a0f[i] = *(const f16x8*)(Ah + (wm + i * 16 + lr) * 32 + swz);
            b0f[i] = *(const f16x8*)(Bh + (wn + i * 16 + lr) * 32 + swz);
        }
#pragma unroll
        for (int i = 0; i < 4; ++i)
#pragma unroll
            for (int j = 0; j < 4; ++j)
                acc[i][j] = __builtin_amdgcn_mfma_f32_16x16x32_f16(a0f[i], b0f[j], acc[i][j], 0, 0, 0);
#pragma unroll
        for (int i = 0; i < 4; ++i) {
            a1f[i] = *(const f16x8*)(Ah + 4096 + (wm + i * 16 + lr) * 32 + swz);
            b1f[i] = *(const f16x8*)(Bh + 8192 + (wn + i * 16 + lr) * 32 + swz);
        }
        __syncthreads();
        if (kc + 64 < 512) STAGE(kc + 64);
#pragma unroll
        for (int i = 0; i < 4; ++i)
#pragma unroll
            for (int j = 0; j < 4; ++j)
                acc[i][j] = __builtin_amdgcn_mfma_f32_16x16x32_f16(a1f[i], b1f[j], acc[i][j], 0, 0, 0);
    }
#undef STAGE

    const int b = p0 >> 12, hw0 = p0 & 4095;
    float mn[4], rs[4];
#pragma unroll
    for (int j = 0; j < 4; ++j) {
        const int px = wn + j * 16 + lr;
        mn[j] = mnS[px]; rs[j] = rsS[px];
    }
#pragma unroll
    for (int i = 0; i < 4; ++i)
#pragma unroll
        for (int r = 0; r < 4; ++r) {
            const int o = om + wm + i * 16 + kg * 4 + r;
            const float so = sv[o];
            h16* dst = qout + ((size_t)b * OC3 + o) * HWN;
#pragma unroll
            for (int j = 0; j < 4; ++j) {
                const int hw = hw0 + wn + j * 16 + lr;
                dst[hw] = (h16)(rs[j] * (acc[i][j][r] * (1.f / 64.f) - mn[j] * so));
            }
        }
}

// ---------------------------------------------------------------------------
// MFMA context partial over a 256-pixel chunk (1 wave, no LDS, no barriers):
// pass 1: chunk-local row max from k (32KB, leaves it L2-warm);
// pass 2: pt[d][e] = sum_n exp16(k-m) * v[e][n] via MFMA; z[d] = sum exp (f32).
// Output per (bh,ci): [4096 pt][64 z][64 m], stride 4224.
__global__ __launch_bounds__(64) void ctx_partial(const h16* __restrict__ qkv16,
                                                  float* __restrict__ ctp) {
    const int bh = blockIdx.y, ci = blockIdx.x;   // ci 0..15
    const int b = bh >> 3, h = bh & 7;
    const h16* kb = qkv16 + ((size_t)b * OC3 + CCH  + h * 64) * HWN;
    const h16* vb = qkv16 + ((size_t)b * OC3 + 1024 + h * 64) * HWN;
    const int lane = threadIdx.x;
    const int lr = lane & 15, kg = lane >> 4;
    const int nbase = ci * 256 + kg * 8;

    // pass 1: chunk-local row max (each lane covers rows i*16+lr, kg n-slices)
    float m[4] = {-1e30f, -1e30f, -1e30f, -1e30f};
#pragma unroll 1
    for (int c = 0; c < 8; ++c) {
        const int n0 = nbase + c * 32;
#pragma unroll
        for (int i = 0; i < 4; ++i) {
            const f16x8 kv = *(const f16x8*)(kb + (size_t)(i * 16 + lr) * HWN + n0);
#pragma unroll
            for (int u = 0; u < 8; ++u) m[i] = fmaxf(m[i], (float)kv[u]);
        }
    }
#pragma unroll
    for (int i = 0; i < 4; ++i) {
        m[i] = fmaxf(m[i], __shfl_xor(m[i], 16));
        m[i] = fmaxf(m[i], __shfl_xor(m[i], 32));
    }

    float z[4] = {0.f, 0.f, 0.f, 0.f};
    f32x4 acc[4][4];
#pragma unroll
    for (int i = 0; i < 4; ++i)
#pragma unroll
        for (int j = 0; j < 4; ++j) acc[i][j] = {0.f, 0.f, 0.f, 0.f};

#pragma unroll 1
    for (int c = 0; c < 8; ++c) {
        const int n0 = nbase + c * 32;
        f16x8 ke[4], vf[4];
#pragma unroll
        for (int j = 0; j < 4; ++j)
            vf[j] = *(const f16x8*)(vb + (size_t)(j * 16 + lr) * HWN + n0);
#pragma unroll
        for (int i = 0; i < 4; ++i) {
            const f16x8 kv = *(const f16x8*)(kb + (size_t)(i * 16 + lr) * HWN + n0);
            f16x8 t;
#pragma unroll
            for (int u = 0; u < 8; ++u) {
                const float e = __expf((float)kv[u] - m[i]);
                z[i] += e;
                t[u] = (h16)e;
            }
            ke[i] = t;
        }
#pragma unroll
        for (int i = 0; i < 4; ++i)
#pragma unroll
            for (int j = 0; j < 4; ++j)
                acc[i][j] = __builtin_amdgcn_mfma_f32_16x16x32_f16(ke[i], vf[j], acc[i][j], 0, 0, 0);
    }
#pragma unroll
    for (int i = 0; i < 4; ++i) {
        z[i] += __shfl_xor(z[i], 16);
        z[i] += __shfl_xor(z[i], 32);
    }
    float* dst = ctp + ((size_t)bh * 16 + ci) * 4224;
#pragma unroll
    for (int i = 0; i < 4; ++i)
#pragma unroll
        for (int j = 0; j < 4; ++j)
#pragma unroll
            for (int r = 0; r < 4; ++r)
                dst[(i * 16 + kg * 4 + r) * 64 + j * 16 + lr] = acc[i][j][r];
    if (kg == 0)
#pragma unroll
        for (int i = 0; i < 4; ++i) {
            dst[4096 + i * 16 + lr] = z[i];
            dst[4160 + i * 16 + lr] = m[i];
        }
}

// ---------------------------------------------------------------------------
// combine 16 chunk partials with exp(m_loc - M) rescale, normalize:
// ct[d][e] = sum_ci w_ci*pt_ci[d][e] / sum_ci w_ci*z_ci[d],  w = exp(m_loc-M)
__global__ __launch_bounds__(256) void ctx_reduce(const float* __restrict__ ctp,
                                                  float* __restrict__ ct) {
    __shared__ float w[16][64];
    __shared__ float rz[64];
    const int bh = blockIdx.x;
    const int tid = threadIdx.x;
    const float* src = ctp + (size_t)bh * 16 * 4224;
    if (tid < 64) {
        float M = -1e30f;
#pragma unroll
        for (int ci = 0; ci < 16; ++ci)
            M = fmaxf(M, src[(size_t)ci * 4224 + 4160 + tid]);
        float Z = 0.f;
#pragma unroll
        for (int ci = 0; ci < 16; ++ci) {
            const float ww = __expf(src[(size_t)ci * 4224 + 4160 + tid] - M);
            w[ci][tid] = ww;
            Z += ww * src[(size_t)ci * 4224 + 4096 + tid];
        }
        rz[tid] = 1.f / Z;
    }
    __syncthreads();
    float* dst = ct + (size_t)bh * 4096;
    for (int e4 = tid * 4; e4 < 4096; e4 += 1024) {
        const int d = e4 >> 6;
        float4 sum = make_float4(0.f, 0.f, 0.f, 0.f);
#pragma unroll
        for (int ci = 0; ci < 16; ++ci) {
            const float4 v = *(const float4*)(src + (size_t)ci * 4224 + e4);
            const float ww = w[ci][d];
            sum.x += ww * v.x; sum.y += ww * v.y;
            sum.z += ww * v.z; sum.w += ww * v.w;
        }
        const float r = rz[d];
        sum.x *= r; sum.y *= r; sum.z *= r; sum.w *= r;
        *(float4*)(dst + e4) = sum;
    }
}

// ---------------------------------------------------------------------------
// q-softmax(d) * (512*SCALE), out'[e,n] = sum_d ct[d,e]*qtilde[d,n];
// writes at = fp16, TRANSPOSED to [b*4096+n][512] (in ws).
__global__ __launch_bounds__(256) void attn_out(const h16* __restrict__ qkv16,
                                                const float* __restrict__ ct,
                                                h16* __restrict__ at) {
    __shared__ float cts[64][68];
    __shared__ float qt[64][68];

    const int bh = blockIdx.y, ci = blockIdx.x;
    const int b = bh >> 3, h = bh & 7;
    const h16* qb = qkv16 + ((size_t)b * OC3 + h * 64) * HWN;
    const int tid = threadIdx.x;

    for (int i4 = tid * 4; i4 < 4096; i4 += 1024) {
        const float4 v = *(const float4*)(ct + (size_t)bh * 4096 + i4);
        *(float4*)&cts[i4 >> 6][i4 & 63] = v;
    }

    const int d  = tid >> 2;
    const int te = tid & 15, tn = tid >> 4;
    const int rn = tid >> 2, d0q = (tid & 3) * 16;

    for (int t = 0; t < 8; ++t) {
        const int n0 = ci * 512 + t * 64;
        __syncthreads();
#pragma unroll
        for (int jj = 0; jj < 2; ++jj) {
            const int nn = (tid & 3) * 8 + jj * 32;
            const f16x8 qv = *(const f16x8*)(qb + (size_t)d * HWN + n0 + nn);
#pragma unroll
            for (int u = 0; u < 8; ++u) qt[nn + u][d] = (float)qv[u];
        }
        __syncthreads();
        {
            float mx = -1e30f;
#pragma unroll
            for (int dd = 0; dd < 16; ++dd) mx = fmaxf(mx, qt[rn][d0q + dd]);
            mx = fmaxf(mx, __shfl_xor(mx, 1));
            mx = fmaxf(mx, __shfl_xor(mx, 2));
            float sm = 0.f;
#pragma unroll
            for (int dd = 0; dd < 16; ++dd) sm += __expf(qt[rn][d0q + dd] - mx);
            sm += __shfl_xor(sm, 1);
            sm += __shfl_xor(sm, 2);
            const float sc = 512.f * QSCALE / sm;
#pragma unroll
            for (int dd = 0; dd < 16; ++dd)
                qt[rn][d0q + dd] = __expf(qt[rn][d0q + dd] - mx) * sc;
        }
        __syncthreads();
        float acc[4][4];
#pragma unroll
        for (int i = 0; i < 4; ++i)
#pragma unroll
            for (int j = 0; j < 4; ++j) acc[i][j] = 0.f;
#pragma unroll
        for (int dd = 0; dd < 64; ++dd) {
            float cv[4];
            *(float4*)cv = *(const float4*)&cts[dd][te * 4];
            const float q0 = qt[tn * 4 + 0][dd];
            const float q1 = qt[tn * 4 + 1][dd];
            const float q2 = qt[tn * 4 + 2][dd];
            const float q3 = qt[tn * 4 + 3][dd];
#pragma unroll
            for (int i = 0; i < 4; ++i) {
                acc[i][0] = fmaf(cv[i], q0, acc[i][0]);
                acc[i][1] = fmaf(cv[i], q1, acc[i][1]);
                acc[i][2] = fmaf(cv[i], q2, acc[i][2]);
                acc[i][3] = fmaf(cv[i], q3, acc[i][3]);
            }
        }
        __syncthreads();
#pragma unroll
        for (int i = 0; i < 4; ++i)
#pragma unroll
            for (int j = 0; j < 4; ++j)
                qt[tn * 4 + j][te * 4 + i] = acc[i][j];
        __syncthreads();
        {
            const int px = tid >> 2, e0 = (tid & 3) * 16;
            f16x8 vh0, vh1;
#pragma unroll
            for (int u = 0; u < 8; ++u) {
                vh0[u] = (h16)qt[px][e0 + u];
                vh1[u] = (h16)qt[px][e0 + 8 + u];
            }
            const size_t o = ((size_t)b * HWN + n0 + px) * CCH + h * 64 + e0;
            *(f16x8*)(at + o)     = vh0;
            *(f16x8*)(at + o + 8) = vh1;
        }
    }
}

// ---------------------------------------------------------------------------
// Fused out-GEMM + channel LN + residual. Single fp16: (wo_hi, at), K=512.
__global__ __launch_bounds__(512) void out_fused(const h16* __restrict__ wo_hi,
                                                 const h16* __restrict__ at,
                                                 const float* __restrict__ b_out,
                                                 const float* __restrict__ g_out,
                                                 const float* __restrict__ x,
                                                 float* __restrict__ out) {
    __shared__ __align__(16) h16 Alds[512 * 32];
    __shared__ __align__(16) h16 Blds[128 * 32];
    __shared__ float red1[4][128], red2[4][128];
    __shared__ float mnS[128], rsS[128];

    const int tid = threadIdx.x;
    const int p0 = blockIdx.x * 128;
    const int b = p0 >> 12, hw0 = p0 & 4095;

    const int trow = tid >> 2;
    const int skh  = ((tid & 3) ^ (trow & 3)) * 8;
    const size_t aoff = (size_t)trow * CCH + skh;
    const size_t boff = (size_t)p0 * CCH + aoff;
    const int wofs = (tid >> 6) * 512;

    const int wv = tid >> 6;
    const int wm = (wv >> 1) * 128, wn = (wv & 1) * 64;
    const int lane = tid & 63;
    const int lr = lane & 15, kg = lane >> 4;
    const int swz = (kg ^ (lr & 3)) * 8;

    f32x4 acc[8][4];
#pragma unroll
    for (int i = 0; i < 8; ++i)
#pragma unroll
        for (int j = 0; j < 4; ++j) acc[i][j] = {0.f, 0.f, 0.f, 0.f};

#define STAGEF(S)                                                           \
    do {                                                                    \
        const int kc_ = (S) * 32;                                           \
        gl_lds16(wo_hi + aoff + kc_,               Alds + wofs);            \
        gl_lds16(wo_hi + aoff + kc_ + 128 * CCH,   Alds + 4096 + wofs);     \
        gl_lds16(wo_hi + aoff + kc_ + 256 * CCH,   Alds + 8192 + wofs);     \
        gl_lds16(wo_hi + aoff + kc_ + 384 * CCH,   Alds + 12288 + wofs);    \
        gl_lds16(at + boff + kc_,                  Blds + wofs);            \
    } while (0)

    STAGEF(0);
#pragma unroll 1
    for (int s = 0; s < 16; ++s) {
        __syncthreads();
        f16x8 af[8], bf[4];
#pragma unroll
        for (int i = 0; i < 8; ++i)
            af[i] = *(const f16x8*)(Alds + (wm + i * 16 + lr) * 32 + swz);
#pragma unroll
        for (int j = 0; j < 4; ++j)
            bf[j] = *(const f16x8*)(Blds + (wn + j * 16 + lr) * 32 + swz);
        __syncthreads();
        if (s < 15) STAGEF(s + 1);
#pragma unroll
        for (int i = 0; i < 8; ++i)
#pragma unroll
            for (int j = 0; j < 4; ++j)
                acc[i][j] = __builtin_amdgcn_mfma_f32_16x16x32_f16(af[i], bf[j], acc[i][j], 0, 0, 0);
    }
#undef STAGEF

#pragma unroll
    for (int i = 0; i < 8; ++i) {
        const int o = wm + i * 16 + kg * 4;
        const float4 bb = *(const float4*)(b_out + o);
#pragma unroll
        for (int j = 0; j < 4; ++j) {
            acc[i][j][0] = acc[i][j][0] * (1.f / 134217728.f) + bb.x;
            acc[i][j][1] = acc[i][j][1] * (1.f / 134217728.f) + bb.y;
            acc[i][j][2] = acc[i][j][2] * (1.f / 134217728.f) + bb.z;
            acc[i][j][3] = acc[i][j][3] * (1.f / 134217728.f) + bb.w;
        }
    }
    float s1[4], s2[4];
#pragma unroll
    for (int j = 0; j < 4; ++j) {
        s1[j] = 0.f; s2[j] = 0.f;
#pragma unroll
        for (int i = 0; i < 8; ++i)
#pragma unroll
            for (int r = 0; r < 4; ++r) {
                const float v = acc[i][j][r];
                s1[j] += v; s2[j] += v * v;
            }
        s1[j] += __shfl_xor(s1[j], 16); s1[j] += __shfl_xor(s1[j], 32);
        s2[j] += __shfl_xor(s2[j], 16); s2[j] += __shfl_xor(s2[j], 32);
    }
    if (kg == 0) {
#pragma unroll
        for (int j = 0; j < 4; ++j) {
            red1[wv >> 1][wn + j * 16 + lr] = s1[j];
            red2[wv >> 1][wn + j * 16 + lr] = s2[j];
        }
    }
    __syncthreads();
    if (tid < 128) {
        const float S1 = red1[0][tid] + red1[1][tid] + red1[2][tid] + red1[3][tid];
        const float S2 = red2[0][tid] + red2[1][tid] + red2[2][tid] + red2[3][tid];
        const float m = S1 * (1.f / 512.f);
        float var = S2 * (1.f / 512.f) - m * m;
        var = fmaxf(var, 0.f);
        mnS[tid] = m;
        rsS[tid] = rsqrtf(var + LN_EPS);
    }
    __syncthreads();
    float mj[4], rj[4];
#pragma unroll
    for (int j = 0; j < 4; ++j) {
        const int px = wn + j * 16 + lr;
        mj[j] = mnS[px]; rj[j] = rsS[px];
    }
#pragma unroll
    for (int i = 0; i < 8; ++i) {
        const int o = wm + i * 16 + kg * 4;
        const float4 gg = *(const float4*)(g_out + o);
#pragma unroll
        for (int r = 0; r < 4; ++r) {
            const float g = (r == 0) ? gg.x : (r == 1) ? gg.y : (r == 2) ? gg.z : gg.w;
            const float* xr = x + ((size_t)b * CCH + o + r) * HWN + hw0 + wn;
            float* dr = out + ((size_t)b * CCH + o + r) * HWN + hw0 + wn;
#pragma unroll
            for (int j = 0; j < 4; ++j) {
                const int c = j * 16 + lr;
                dr[c] = (acc[i][j][r] - mj[j]) * rj[j] * g + xr[c];
            }
        }
    }
}

// ---------------------------------------------------------------------------
extern "C" void kernel_launch(void* const* d_in, const int* in_sizes, int n_in,
                              void* d_out, int out_size, void* d_ws, size_t ws_size,
                              hipStream_t stream) {
    (void)in_sizes; (void)n_in; (void)out_size;
    const float* x     = (const float*)d_in[0];
    const float* w_qkv = (const float*)d_in[1];
    const float* w_out = (const float*)d_in[2];
    const float* b_out = (const float*)d_in[3];
    const float* g_out = (const float*)d_in[4];
    const float* g_ln  = (const float*)d_in[5];
    float* out = (float*)d_out;
    float* ws  = (float*)d_ws;

    float* s    = ws;                       // 1536
    float* ct   = s + OC3;                  // 524288
    float* ctp  = ct + 524288;              // 8650752 (128 bh x 16 ci x 4224)
    float* psum = ctp;                      // 524288 (alias: dead before ctx)
    float* psq  = psum + 524288;            // 524288
    h16*  wg_hi = (h16*)(ctp + 8650752);    // 786432 halfs
    h16*  wo_hi = wg_hi + 786432;           // 262144 halfs
    h16*  qkv16 = wo_hi + 262144;           // 100663296 halfs (fp16 q,k,v)
    h16*  at    = qkv16 + 100663296;        // 33554432 halfs (attn out, transposed)
    // alias of d_out: xt dead after qkv_gemm (out_fused is sole d_out writer)
    h16*  xt_hi = (h16*)d_out;

    const size_t need = 76809728ULL * 4ULL;   // ~307.2 MB
    if (ws_size < need) return;

    prep_w       <<<2048, 64, 0, stream>>>(w_qkv, g_ln, w_out, wg_hi, s, wo_hi);
    transpose_cvt<<<dim3(64, 8, 16), 256, 0, stream>>>(x, xt_hi, psum, psq);
    qkv_gemm     <<<dim3(12, 256), 512, 0, stream>>>(wg_hi, xt_hi,
                                                     s, psum, psq, qkv16);
    ctx_partial  <<<dim3(16, 128), 64, 0, stream>>>(qkv16, ctp);
    ctx_reduce   <<<128, 256, 0, stream>>>(ctp, ct);
    attn_out     <<<dim3(8, 128), 256, 0, stream>>>(qkv16, ct, at);
    out_fused    <<<512, 512, 0, stream>>>(wo_hi, at,
                                           b_out, g_out, x, out);
}

// Round 18
// 387.574 us; speedup vs baseline: 1.5009x; 1.1183x over previous
//
#include <hip/hip_runtime.h>
#include <math.h>

#define CCH    512
#define HWN    4096
#define NPIX   65536
#define OC3    1536
#define QSCALE 0.125f
#define LN_EPS 1e-5f

typedef _Float16 h16;
typedef h16  f16x8 __attribute__((ext_vector_type(8)));
typedef h16  f16x4 __attribute__((ext_vector_type(4)));
typedef float f32x4 __attribute__((ext_vector_type(4)));

__device__ __forceinline__ float waveReduceSum(float v) {
#pragma unroll
    for (int off = 32; off; off >>= 1) v += __shfl_xor(v, off);
    return v;
}

__device__ __forceinline__ void gl_lds16(const void* g, void* l) {
    __builtin_amdgcn_global_load_lds((const __attribute__((address_space(1))) void*)g,
                                     (__attribute__((address_space(3))) void*)l, 16, 0, 0);
}

// ---------------------------------------------------------------------------
// merged weight prep (single fp16, x64 scaled):
// o<1536 -> wg = w_qkv*g_ln + row-sum s;  o>=1536 -> wo = w_out
__global__ __launch_bounds__(64) void prep_w(const float* __restrict__ w_qkv,
                                             const float* __restrict__ g_ln,
                                             const float* __restrict__ w_out,
                                             h16* __restrict__ wg_h,
                                             float* __restrict__ s,
                                             h16* __restrict__ wo_h) {
    const int o = blockIdx.x, lane = threadIdx.x;
    if (o < OC3) {
        float sum = 0.f;
#pragma unroll
        for (int j = 0; j < 8; ++j) {
            const int c = lane + j * 64;
            const float w = w_qkv[(size_t)o * CCH + c] * g_ln[c];
            wg_h[(size_t)o * CCH + c] = (h16)(w * 64.f);
            sum += w;
        }
        sum = waveReduceSum(sum);
        if (lane == 0) s[o] = sum;
    } else {
        const int r = o - OC3;
#pragma unroll
        for (int j = 0; j < 8; ++j) {
            const int c = lane + j * 64;
            wo_h[(size_t)r * CCH + c] = (h16)(w_out[(size_t)r * CCH + c] * 64.f);
        }
    }
}

// ---------------------------------------------------------------------------
// fp32 [16][512][4096] -> transposed fp16 [16][4096][512]
// + per-(channel-block, pixel) LN partial sums (deterministic 2-stage stats)
__global__ __launch_bounds__(256) void transpose_cvt(const float* __restrict__ src,
                                                     h16* __restrict__ dhi,
                                                     float* __restrict__ psum,
                                                     float* __restrict__ psq) {
    __shared__ float tile[64][65];
    __shared__ float ps1[4][64], ps2[4][64];
    const int b = blockIdx.z, c0 = blockIdx.y * 64, p0 = blockIdx.x * 64;
    const int t = threadIdx.x;
    const float* sb = src + ((size_t)b * CCH + c0) * HWN + p0;
    const int rc = t >> 4, cc4 = (t & 15) * 4;
#pragma unroll
    for (int ps = 0; ps < 4; ++ps) {
        const float4 v = *(const float4*)(sb + (size_t)(rc + ps * 16) * HWN + cc4);
        tile[rc + ps * 16][cc4 + 0] = v.x;
        tile[rc + ps * 16][cc4 + 1] = v.y;
        tile[rc + ps * 16][cc4 + 2] = v.z;
        tile[rc + ps * 16][cc4 + 3] = v.w;
    }
    __syncthreads();
    {
        const int q = t >> 6, px = t & 63;
        float s1 = 0.f, s2 = 0.f;
#pragma unroll
        for (int c = q * 16; c < q * 16 + 16; ++c) {
            const float v = tile[c][px];
            s1 += v; s2 += v * v;
        }
        ps1[q][px] = s1; ps2[q][px] = s2;
    }
    const int pr0 = t >> 3, cs = (t & 7) * 8;
#pragma unroll
    for (int ps = 0; ps < 2; ++ps) {
        const int pr = pr0 + ps * 32;
        f16x8 vh;
#pragma unroll
        for (int q = 0; q < 8; ++q) vh[q] = (h16)tile[cs + q][pr];
        const size_t o = ((size_t)b * HWN + p0 + pr) * CCH + c0 + cs;
        *(f16x8*)(dhi + o) = vh;
    }
    __syncthreads();
    if (t < 64) {
        const float s1 = ps1[0][t] + ps1[1][t] + ps1[2][t] + ps1[3][t];
        const float s2 = ps2[0][t] + ps2[1][t] + ps2[2][t] + ps2[3][t];
        const size_t gp = (size_t)b * HWN + p0 + t;
        psum[(size_t)(c0 >> 6) * NPIX + gp] = s1;
        psq [(size_t)(c0 >> 6) * NPIX + gp] = s2;
    }
}

// ---------------------------------------------------------------------------
// QKV GEMM: 128x256 tile, BK=64 two-plane LDS, 512 threads (8 waves of 64x64).
// Single fp16 (A x64 scaled). LN stats finished in-block from psum/psq.
// out fp16 = rstd[p]*(acc/64 - mean[p]*s[o]).
__global__ __launch_bounds__(512) void qkv_gemm(const h16* __restrict__ Ahg,
                                                const h16* __restrict__ Bhg,
                                                const float* __restrict__ sv,
                                                const float* __restrict__ psum,
                                                const float* __restrict__ psq,
                                                h16* __restrict__ qout) {
    __shared__ __align__(16) h16 Ah[8192];    // 2 planes x [128][32]
    __shared__ __align__(16) h16 Bh[16384];   // 2 planes x [256][32]
    __shared__ float mnS[256], rsS[256];
    const int tid = threadIdx.x;
    const int om = blockIdx.x * 128;
    const int by0 = blockIdx.y;
    const int by  = (by0 & 7) * 32 + (by0 >> 3);   // bijective XCD chunking (256%8==0)
    const int p0  = by * 256;

    const int srow = tid >> 2;
    const int skh  = ((tid & 3) ^ (srow & 3)) * 8;
    const size_t a0 = (size_t)(om + srow) * CCH + skh;
    const size_t b0 = (size_t)(p0 + srow) * CCH + skh;

    const int lane = tid & 63;
    const int wv = tid >> 6;
    const int wm = (wv >> 2) * 64, wn = (wv & 3) * 64;
    const int lr = lane & 15, kg = lane >> 4;
    const int swz = (kg ^ (lr & 3)) * 8;

    f32x4 acc[4][4];
#pragma unroll
    for (int i = 0; i < 4; ++i)
#pragma unroll
        for (int j = 0; j < 4; ++j) acc[i][j] = {0.f, 0.f, 0.f, 0.f};

#define STAGE(KC)                                                          \
    do {                                                                   \
        gl_lds16(Ahg + a0 + (KC),                 Ah + tid * 8);           \
        gl_lds16(Ahg + a0 + (KC) + 32,            Ah + 4096 + tid * 8);    \
        gl_lds16(Bhg + b0 + (KC),                 Bh + tid * 8);           \
        gl_lds16(Bhg + b0 + (KC) + 128 * CCH,     Bh + 4096 + tid * 8);    \
        gl_lds16(Bhg + b0 + (KC) + 32,            Bh + 8192 + tid * 8);    \
        gl_lds16(Bhg + b0 + (KC) + 32 + 128 * CCH, Bh + 12288 + tid * 8);  \
    } while (0)

    STAGE(0);
    if (tid < 256) {
        const int gp = p0 + tid;
        float s1 = 0.f, s2 = 0.f;
#pragma unroll
        for (int cb = 0; cb < 8; ++cb) {
            s1 += psum[(size_t)cb * NPIX + gp];
            s2 += psq [(size_t)cb * NPIX + gp];
        }
        const float m = s1 * (1.f / 512.f);
        float var = s2 * (1.f / 512.f) - m * m;
        var = fmaxf(var, 0.f);
        mnS[tid] = m;
        rsS[tid] = rsqrtf(var + LN_EPS);
    }

#pragma unroll 1
    for (int kc = 0; kc < 512; kc += 64) {
        __syncthreads();
        f16x8 a0f[4], b0f[4], a1f[4], b1f[4];
#pragma unroll
        for (int i = 0; i < 4; ++i) {
            a0f[i] = *(const f16x8*)(Ah + (wm + i * 16 + lr) * 32 + swz);
            b0f[i] = *(const f16x8*)(Bh + (wn + i * 16 + lr) * 32 + swz);
        }
#pragma unroll
        for (int i = 0; i < 4; ++i)
#pragma unroll
            for (int j = 0; j < 4; ++j)
                acc[i][j] = __builtin_amdgcn_mfma_f32_16x16x32_f16(a0f[i], b0f[j], acc[i][j], 0, 0, 0);
#pragma unroll
        for (int i = 0; i < 4; ++i) {
            a1f[i] = *(const f16x8*)(Ah + 4096 + (wm + i * 16 + lr) * 32 + swz);
            b1f[i] = *(const f16x8*)(Bh + 8192 + (wn + i * 16 + lr) * 32 + swz);
        }
        __syncthreads();
        if (kc + 64 < 512) STAGE(kc + 64);
#pragma unroll
        for (int i = 0; i < 4; ++i)
#pragma unroll
            for (int j = 0; j < 4; ++j)
                acc[i][j] = __builtin_amdgcn_mfma_f32_16x16x32_f16(a1f[i], b1f[j], acc[i][j], 0, 0, 0);
    }
#undef STAGE

    const int b = p0 >> 12, hw0 = p0 & 4095;
    float mn[4], rs[4];
#pragma unroll
    for (int j = 0; j < 4; ++j) {
        const int px = wn + j * 16 + lr;
        mn[j] = mnS[px]; rs[j] = rsS[px];
    }
#pragma unroll
    for (int i = 0; i < 4; ++i)
#pragma unroll
        for (int r = 0; r < 4; ++r) {
            const int o = om + wm + i * 16 + kg * 4 + r;
            const float so = sv[o];
            h16* dst = qout + ((size_t)b * OC3 + o) * HWN;
#pragma unroll
            for (int j = 0; j < 4; ++j) {
                const int hw = hw0 + wn + j * 16 + lr;
                dst[hw] = (h16)(rs[j] * (acc[i][j][r] * (1.f / 64.f) - mn[j] * so));
            }
        }
}

// ---------------------------------------------------------------------------
// MFMA context partial over a 256-pixel chunk (1 wave, no LDS, no barriers):
// pass 1: chunk-local row max from k (32KB, leaves it L2-warm);
// pass 2: pt[d][e] = sum_n exp16(k-m) * v[e][n] via MFMA; z[d] = sum exp (f32).
// Output per (bh,ci): [4096 pt][64 z][64 m], stride 4224.
__global__ __launch_bounds__(64) void ctx_partial(const h16* __restrict__ qkv16,
                                                  float* __restrict__ ctp) {
    const int bh = blockIdx.y, ci = blockIdx.x;   // ci 0..15
    const int b = bh >> 3, h = bh & 7;
    const h16* kb = qkv16 + ((size_t)b * OC3 + CCH  + h * 64) * HWN;
    const h16* vb = qkv16 + ((size_t)b * OC3 + 1024 + h * 64) * HWN;
    const int lane = threadIdx.x;
    const int lr = lane & 15, kg = lane >> 4;
    const int nbase = ci * 256 + kg * 8;

    float m[4] = {-1e30f, -1e30f, -1e30f, -1e30f};
#pragma unroll 1
    for (int c = 0; c < 8; ++c) {
        const int n0 = nbase + c * 32;
#pragma unroll
        for (int i = 0; i < 4; ++i) {
            const f16x8 kv = *(const f16x8*)(kb + (size_t)(i * 16 + lr) * HWN + n0);
#pragma unroll
            for (int u = 0; u < 8; ++u) m[i] = fmaxf(m[i], (float)kv[u]);
        }
    }
#pragma unroll
    for (int i = 0; i < 4; ++i) {
        m[i] = fmaxf(m[i], __shfl_xor(m[i], 16));
        m[i] = fmaxf(m[i], __shfl_xor(m[i], 32));
    }

    float z[4] = {0.f, 0.f, 0.f, 0.f};
    f32x4 acc[4][4];
#pragma unroll
    for (int i = 0; i < 4; ++i)
#pragma unroll
        for (int j = 0; j < 4; ++j) acc[i][j] = {0.f, 0.f, 0.f, 0.f};

#pragma unroll 1
    for (int c = 0; c < 8; ++c) {
        const int n0 = nbase + c * 32;
        f16x8 ke[4], vf[4];
#pragma unroll
        for (int j = 0; j < 4; ++j)
            vf[j] = *(const f16x8*)(vb + (size_t)(j * 16 + lr) * HWN + n0);
#pragma unroll
        for (int i = 0; i < 4; ++i) {
            const f16x8 kv = *(const f16x8*)(kb + (size_t)(i * 16 + lr) * HWN + n0);
            f16x8 t;
#pragma unroll
            for (int u = 0; u < 8; ++u) {
                const float e = __expf((float)kv[u] - m[i]);
                z[i] += e;
                t[u] = (h16)e;
            }
            ke[i] = t;
        }
#pragma unroll
        for (int i = 0; i < 4; ++i)
#pragma unroll
            for (int j = 0; j < 4; ++j)
                acc[i][j] = __builtin_amdgcn_mfma_f32_16x16x32_f16(ke[i], vf[j], acc[i][j], 0, 0, 0);
    }
#pragma unroll
    for (int i = 0; i < 4; ++i) {
        z[i] += __shfl_xor(z[i], 16);
        z[i] += __shfl_xor(z[i], 32);
    }
    float* dst = ctp + ((size_t)bh * 16 + ci) * 4224;
#pragma unroll
    for (int i = 0; i < 4; ++i)
#pragma unroll
        for (int j = 0; j < 4; ++j)
#pragma unroll
            for (int r = 0; r < 4; ++r)
                dst[(i * 16 + kg * 4 + r) * 64 + j * 16 + lr] = acc[i][j][r];
    if (kg == 0)
#pragma unroll
        for (int i = 0; i < 4; ++i) {
            dst[4096 + i * 16 + lr] = z[i];
            dst[4160 + i * 16 + lr] = m[i];
        }
}

// ---------------------------------------------------------------------------
// combine 16 chunk partials with exp(m_loc - M) rescale, normalize, and emit
// TRANSPOSED fp16: ctt[e][d] = (sum_ci w*pt[d][e]) / (sum_ci w*z[d])
__global__ __launch_bounds__(256) void ctx_reduce(const float* __restrict__ ctp,
                                                  h16* __restrict__ ctt) {
    __shared__ float w[16][64];
    __shared__ float rz[64];
    const int bh = blockIdx.x;
    const int tid = threadIdx.x;
    const float* src = ctp + (size_t)bh * 16 * 4224;
    if (tid < 64) {
        float M = -1e30f;
#pragma unroll
        for (int ci = 0; ci < 16; ++ci)
            M = fmaxf(M, src[(size_t)ci * 4224 + 4160 + tid]);
        float Z = 0.f;
#pragma unroll
        for (int ci = 0; ci < 16; ++ci) {
            const float ww = __expf(src[(size_t)ci * 4224 + 4160 + tid] - M);
            w[ci][tid] = ww;
            Z += ww * src[(size_t)ci * 4224 + 4096 + tid];
        }
        rz[tid] = 1.f / Z;
    }
    __syncthreads();
    h16* dstt = ctt + (size_t)bh * 4096;
    for (int e4 = tid * 4; e4 < 4096; e4 += 1024) {
        const int d = e4 >> 6, e0 = e4 & 63;
        float4 sum = make_float4(0.f, 0.f, 0.f, 0.f);
#pragma unroll
        for (int ci = 0; ci < 16; ++ci) {
            const float4 v = *(const float4*)(src + (size_t)ci * 4224 + e4);
            const float ww = w[ci][d];
            sum.x += ww * v.x; sum.y += ww * v.y;
            sum.z += ww * v.z; sum.w += ww * v.w;
        }
        const float r = rz[d];
        dstt[(e0 + 0) * 64 + d] = (h16)(sum.x * r);
        dstt[(e0 + 1) * 64 + d] = (h16)(sum.y * r);
        dstt[(e0 + 2) * 64 + d] = (h16)(sum.z * r);
        dstt[(e0 + 3) * 64 + d] = (h16)(sum.w * r);
    }
}

// ---------------------------------------------------------------------------
// q-softmax(d)*(512*SCALE), at[e][n] = sum_d ctt[e][d]*qtilde[d][n] via MFMA.
// ctt A-frags held in registers per block; qtilde fp16 in LDS (B operand).
// writes at fp16, TRANSPOSED to [b*4096+n][512] (in ws).
__global__ __launch_bounds__(256) void attn_out(const h16* __restrict__ qkv16,
                                                const h16* __restrict__ ctt,
                                                h16* __restrict__ at) {
    __shared__ __align__(16) h16 qt[64][72];   // [px][d]; reused as ot[px][e]

    const int bh = blockIdx.y, ci = blockIdx.x;
    const int b = bh >> 3, h = bh & 7;
    const h16* qb = qkv16 + ((size_t)b * OC3 + h * 64) * HWN;
    const int tid = threadIdx.x;
    const int lane = tid & 63, wv = tid >> 6;
    const int lr = lane & 15, kg = lane >> 4;

    // A-frags: ctt[e = wv*16+lr][d = ks*32 + kg*8 + u], loaded once per block
    const h16* cb = ctt + (size_t)bh * 4096 + (wv * 16 + lr) * 64 + kg * 8;
    f16x8 af0 = *(const f16x8*)(cb);
    f16x8 af1 = *(const f16x8*)(cb + 32);

    const int d  = tid >> 2;
    const int rn = tid >> 2, d0q = (tid & 3) * 16;

    for (int t = 0; t < 8; ++t) {
        const int n0 = ci * 512 + t * 64;
        __syncthreads();   // ot fully consumed (t>0)
#pragma unroll
        for (int jj = 0; jj < 2; ++jj) {
            const int nn = (tid & 3) * 8 + jj * 32;
            const f16x8 qv = *(const f16x8*)(qb + (size_t)d * HWN + n0 + nn);
#pragma unroll
            for (int u = 0; u < 8; ++u) qt[nn + u][d] = qv[u];
        }
        __syncthreads();
        {   // softmax over d (4 lanes/px, 16 d each); write qtilde fp16 in place
            float qv[16];
            float mx = -1e30f;
#pragma unroll
            for (int dd = 0; dd < 16; ++dd) {
                qv[dd] = (float)qt[rn][d0q + dd];
                mx = fmaxf(mx, qv[dd]);
            }
            mx = fmaxf(mx, __shfl_xor(mx, 1));
            mx = fmaxf(mx, __shfl_xor(mx, 2));
            float sm = 0.f;
#pragma unroll
            for (int dd = 0; dd < 16; ++dd) {
                qv[dd] = __expf(qv[dd] - mx);
                sm += qv[dd];
            }
            sm += __shfl_xor(sm, 1);
            sm += __shfl_xor(sm, 2);
            const float sc = 512.f * QSCALE / sm;
#pragma unroll
            for (int dd = 0; dd < 16; ++dd)
                qt[rn][d0q + dd] = (h16)(qv[dd] * sc);
        }
        __syncthreads();
        // MFMA: wave wv computes e-rows wv*16..+16 x 64 px (4 j x 2 ks)
        f32x4 acc4[4];
#pragma unroll
        for (int j = 0; j < 4; ++j) acc4[j] = {0.f, 0.f, 0.f, 0.f};
#pragma unroll
        for (int j = 0; j < 4; ++j) {
            const f16x8 bf0 = *(const f16x8*)(&qt[j * 16 + lr][kg * 8]);
            const f16x8 bf1 = *(const f16x8*)(&qt[j * 16 + lr][32 + kg * 8]);
            acc4[j] = __builtin_amdgcn_mfma_f32_16x16x32_f16(af0, bf0, acc4[j], 0, 0, 0);
            acc4[j] = __builtin_amdgcn_mfma_f32_16x16x32_f16(af1, bf1, acc4[j], 0, 0, 0);
        }
        __syncthreads();   // qt reads done; reuse as ot[px][e]
#pragma unroll
        for (int j = 0; j < 4; ++j) {
            f16x4 o4;
            o4[0] = (h16)acc4[j][0]; o4[1] = (h16)acc4[j][1];
            o4[2] = (h16)acc4[j][2]; o4[3] = (h16)acc4[j][3];
            *(f16x4*)(&qt[j * 16 + lr][wv * 16 + kg * 4]) = o4;
        }
        __syncthreads();
        {   // gather per pixel: 4 threads/pixel, 16 e each
            const int px = tid >> 2, e0 = (tid & 3) * 16;
            const f16x8 vh0 = *(const f16x8*)(&qt[px][e0]);
            const f16x8 vh1 = *(const f16x8*)(&qt[px][e0 + 8]);
            const size_t o = ((size_t)b * HWN + n0 + px) * CCH + h * 64 + e0;
            *(f16x8*)(at + o)     = vh0;
            *(f16x8*)(at + o + 8) = vh1;
        }
    }
}

// ---------------------------------------------------------------------------
// Fused out-GEMM + channel LN + residual. Single fp16: (wo_hi, at), K=512.
__global__ __launch_bounds__(512) void out_fused(const h16* __restrict__ wo_hi,
                                                 const h16* __restrict__ at,
                                                 const float* __restrict__ b_out,
                                                 const float* __restrict__ g_out,
                                                 const float* __restrict__ x,
                                                 float* __restrict__ out) {
    __shared__ __align__(16) h16 Alds[512 * 32];
    __shared__ __align__(16) h16 Blds[128 * 32];
    __shared__ float red1[4][128], red2[4][128];
    __shared__ float mnS[128], rsS[128];

    const int tid = threadIdx.x;
    const int p0 = blockIdx.x * 128;
    const int b = p0 >> 12, hw0 = p0 & 4095;

    const int trow = tid >> 2;
    const int skh  = ((tid & 3) ^ (trow & 3)) * 8;
    const size_t aoff = (size_t)trow * CCH + skh;
    const size_t boff = (size_t)p0 * CCH + aoff;
    const int wofs = (tid >> 6) * 512;

    const int wv = tid >> 6;
    const int wm = (wv >> 1) * 128, wn = (wv & 1) * 64;
    const int lane = tid & 63;
    const int lr = lane & 15, kg = lane >> 4;
    const int swz = (kg ^ (lr & 3)) * 8;

    f32x4 acc[8][4];
#pragma unroll
    for (int i = 0; i < 8; ++i)
#pragma unroll
        for (int j = 0; j < 4; ++j) acc[i][j] = {0.f, 0.f, 0.f, 0.f};

#define STAGEF(S)                                                           \
    do {                                                                    \
        const int kc_ = (S) * 32;                                           \
        gl_lds16(wo_hi + aoff + kc_,               Alds + wofs);            \
        gl_lds16(wo_hi + aoff + kc_ + 128 * CCH,   Alds + 4096 + wofs);     \
        gl_lds16(wo_hi + aoff + kc_ + 256 * CCH,   Alds + 8192 + wofs);     \
        gl_lds16(wo_hi + aoff + kc_ + 384 * CCH,   Alds + 12288 + wofs);    \
        gl_lds16(at + boff + kc_,                  Blds + wofs);            \
    } while (0)

    STAGEF(0);
#pragma unroll 1
    for (int s = 0; s < 16; ++s) {
        __syncthreads();
        f16x8 af[8], bf[4];
#pragma unroll
        for (int i = 0; i < 8; ++i)
            af[i] = *(const f16x8*)(Alds + (wm + i * 16 + lr) * 32 + swz);
#pragma unroll
        for (int j = 0; j < 4; ++j)
            bf[j] = *(const f16x8*)(Blds + (wn + j * 16 + lr) * 32 + swz);
        __syncthreads();
        if (s < 15) STAGEF(s + 1);
#pragma unroll
        for (int i = 0; i < 8; ++i)
#pragma unroll
            for (int j = 0; j < 4; ++j)
                acc[i][j] = __builtin_amdgcn_mfma_f32_16x16x32_f16(af[i], bf[j], acc[i][j], 0, 0, 0);
    }
#undef STAGEF

#pragma unroll
    for (int i = 0; i < 8; ++i) {
        const int o = wm + i * 16 + kg * 4;
        const float4 bb = *(const float4*)(b_out + o);
#pragma unroll
        for (int j = 0; j < 4; ++j) {
            acc[i][j][0] = acc[i][j][0] * (1.f / 134217728.f) + bb.x;
            acc[i][j][1] = acc[i][j][1] * (1.f / 134217728.f) + bb.y;
            acc[i][j][2] = acc[i][j][2] * (1.f / 134217728.f) + bb.z;
            acc[i][j][3] = acc[i][j][3] * (1.f / 134217728.f) + bb.w;
        }
    }
    float s1[4], s2[4];
#pragma unroll
    for (int j = 0; j < 4; ++j) {
        s1[j] = 0.f; s2[j] = 0.f;
#pragma unroll
        for (int i = 0; i < 8; ++i)
#pragma unroll
            for (int r = 0; r < 4; ++r) {
                const float v = acc[i][j][r];
                s1[j] += v; s2[j] += v * v;
            }
        s1[j] += __shfl_xor(s1[j], 16); s1[j] += __shfl_xor(s1[j], 32);
        s2[j] += __shfl_xor(s2[j], 16); s2[j] += __shfl_xor(s2[j], 32);
    }
    if (kg == 0) {
#pragma unroll
        for (int j = 0; j < 4; ++j) {
            red1[wv >> 1][wn + j * 16 + lr] = s1[j];
            red2[wv >> 1][wn + j * 16 + lr] = s2[j];
        }
    }
    __syncthreads();
    if (tid < 128) {
        const float S1 = red1[0][tid] + red1[1][tid] + red1[2][tid] + red1[3][tid];
        const float S2 = red2[0][tid] + red2[1][tid] + red2[2][tid] + red2[3][tid];
        const float m = S1 * (1.f / 512.f);
        float var = S2 * (1.f / 512.f) - m * m;
        var = fmaxf(var, 0.f);
        mnS[tid] = m;
        rsS[tid] = rsqrtf(var + LN_EPS);
    }
    __syncthreads();
    float mj[4], rj[4];
#pragma unroll
    for (int j = 0; j < 4; ++j) {
        const int px = wn + j * 16 + lr;
        mj[j] = mnS[px]; rj[j] = rsS[px];
    }
#pragma unroll
    for (int i = 0; i < 8; ++i) {
        const int o = wm + i * 16 + kg * 4;
        const float4 gg = *(const float4*)(g_out + o);
#pragma unroll
        for (int r = 0; r < 4; ++r) {
            const float g = (r == 0) ? gg.x : (r == 1) ? gg.y : (r == 2) ? gg.z : gg.w;
            const float* xr = x + ((size_t)b * CCH + o + r) * HWN + hw0 + wn;
            float* dr = out + ((size_t)b * CCH + o + r) * HWN + hw0 + wn;
#pragma unroll
            for (int j = 0; j < 4; ++j) {
                const int c = j * 16 + lr;
                dr[c] = (acc[i][j][r] - mj[j]) * rj[j] * g + xr[c];
            }
        }
    }
}

// ---------------------------------------------------------------------------
extern "C" void kernel_launch(void* const* d_in, const int* in_sizes, int n_in,
                              void* d_out, int out_size, void* d_ws, size_t ws_size,
                              hipStream_t stream) {
    (void)in_sizes; (void)n_in; (void)out_size;
    const float* x     = (const float*)d_in[0];
    const float* w_qkv = (const float*)d_in[1];
    const float* w_out = (const float*)d_in[2];
    const float* b_out = (const float*)d_in[3];
    const float* g_out = (const float*)d_in[4];
    const float* g_ln  = (const float*)d_in[5];
    float* out = (float*)d_out;
    float* ws  = (float*)d_ws;

    float* s    = ws;                       // 1536
    h16*  ctt   = (h16*)(s + OC3);          // 524288 halfs (fits the old ct slot)
    float* ctp  = s + OC3 + 524288;         // 8650752 (128 bh x 16 ci x 4224)
    float* psum = ctp;                      // 524288 (alias: dead before ctx)
    float* psq  = psum + 524288;            // 524288
    h16*  wg_hi = (h16*)(ctp + 8650752);    // 786432 halfs
    h16*  wo_hi = wg_hi + 786432;           // 262144 halfs
    h16*  qkv16 = wo_hi + 262144;           // 100663296 halfs (fp16 q,k,v)
    h16*  at    = qkv16 + 100663296;        // 33554432 halfs (attn out, transposed)
    // alias of d_out: xt dead after qkv_gemm (out_fused is sole d_out writer)
    h16*  xt_hi = (h16*)d_out;

    const size_t need = 76809728ULL * 4ULL;   // ~307.2 MB
    if (ws_size < need) return;

    prep_w       <<<2048, 64, 0, stream>>>(w_qkv, g_ln, w_out, wg_hi, s, wo_hi);
    transpose_cvt<<<dim3(64, 8, 16), 256, 0, stream>>>(x, xt_hi, psum, psq);
    qkv_gemm     <<<dim3(12, 256), 512, 0, stream>>>(wg_hi, xt_hi,
                                                     s, psum, psq, qkv16);
    ctx_partial  <<<dim3(16, 128), 64, 0, stream>>>(qkv16, ctp);
    ctx_reduce   <<<128, 256, 0, stream>>>(ctp, ctt);
    attn_out     <<<dim3(8, 128), 256, 0, stream>>>(qkv16, ctt, at);
    out_fused    <<<512, 512, 0, stream>>>(wo_hi, at,
                                           b_out, g_out, x, out);
}

// Round 19
// 384.826 us; speedup vs baseline: 1.5116x; 1.0071x over previous
//
#include <hip/hip_runtime.h>
#include <math.h>

#define CCH    512
#define HWN    4096
#define NPIX   65536
#define OC3    1536
#define QSCALE 0.125f
#define LN_EPS 1e-5f

typedef _Float16 h16;
typedef h16  f16x8 __attribute__((ext_vector_type(8)));
typedef h16  f16x4 __attribute__((ext_vector_type(4)));
typedef float f32x4 __attribute__((ext_vector_type(4)));

__device__ __forceinline__ float waveReduceSum(float v) {
#pragma unroll
    for (int off = 32; off; off >>= 1) v += __shfl_xor(v, off);
    return v;
}

__device__ __forceinline__ void gl_lds16(const void* g, void* l) {
    __builtin_amdgcn_global_load_lds((const __attribute__((address_space(1))) void*)g,
                                     (__attribute__((address_space(3))) void*)l, 16, 0, 0);
}

// ---------------------------------------------------------------------------
// fused: z<16  -> fp32 x [16][512][4096] -> transposed fp16 [16][4096][512]
//               + per-(channel-block, pixel) LN partial sums
//        z==16 -> weight prep (512 blocks x 4 rows; wave = one row):
//               o<1536: wg = w_qkv*g_ln (x64, fp16) + row-sum s; else wo = w_out
__global__ __launch_bounds__(256) void transpose_prep(const float* __restrict__ src,
                                                      h16* __restrict__ dhi,
                                                      float* __restrict__ psum,
                                                      float* __restrict__ psq,
                                                      const float* __restrict__ w_qkv,
                                                      const float* __restrict__ g_ln,
                                                      const float* __restrict__ w_out,
                                                      h16* __restrict__ wg_h,
                                                      float* __restrict__ s,
                                                      h16* __restrict__ wo_h) {
    __shared__ float tile[64][65];
    __shared__ float ps1[4][64], ps2[4][64];
    const int t = threadIdx.x;

    if (blockIdx.z == 16) {   // weight-prep blocks
        const int o = (blockIdx.x + 64 * blockIdx.y) * 4 + (t >> 6);
        const int lane = t & 63;
        if (o < OC3) {
            float sum = 0.f;
#pragma unroll
            for (int j = 0; j < 8; ++j) {
                const int c = lane + j * 64;
                const float w = w_qkv[(size_t)o * CCH + c] * g_ln[c];
                wg_h[(size_t)o * CCH + c] = (h16)(w * 64.f);
                sum += w;
            }
            sum = waveReduceSum(sum);
            if (lane == 0) s[o] = sum;
        } else {
            const int r = o - OC3;
#pragma unroll
            for (int j = 0; j < 8; ++j) {
                const int c = lane + j * 64;
                wo_h[(size_t)r * CCH + c] = (h16)(w_out[(size_t)r * CCH + c] * 64.f);
            }
        }
        return;
    }

    const int b = blockIdx.z, c0 = blockIdx.y * 64, p0 = blockIdx.x * 64;
    const float* sb = src + ((size_t)b * CCH + c0) * HWN + p0;
    const int rc = t >> 4, cc4 = (t & 15) * 4;
#pragma unroll
    for (int ps = 0; ps < 4; ++ps) {
        const float4 v = *(const float4*)(sb + (size_t)(rc + ps * 16) * HWN + cc4);
        tile[rc + ps * 16][cc4 + 0] = v.x;
        tile[rc + ps * 16][cc4 + 1] = v.y;
        tile[rc + ps * 16][cc4 + 2] = v.z;
        tile[rc + ps * 16][cc4 + 3] = v.w;
    }
    __syncthreads();
    {
        const int q = t >> 6, px = t & 63;
        float s1 = 0.f, s2 = 0.f;
#pragma unroll
        for (int c = q * 16; c < q * 16 + 16; ++c) {
            const float v = tile[c][px];
            s1 += v; s2 += v * v;
        }
        ps1[q][px] = s1; ps2[q][px] = s2;
    }
    const int pr0 = t >> 3, cs = (t & 7) * 8;
#pragma unroll
    for (int ps = 0; ps < 2; ++ps) {
        const int pr = pr0 + ps * 32;
        f16x8 vh;
#pragma unroll
        for (int q = 0; q < 8; ++q) vh[q] = (h16)tile[cs + q][pr];
        const size_t o = ((size_t)b * HWN + p0 + pr) * CCH + c0 + cs;
        *(f16x8*)(dhi + o) = vh;
    }
    __syncthreads();
    if (t < 64) {
        const float s1 = ps1[0][t] + ps1[1][t] + ps1[2][t] + ps1[3][t];
        const float s2 = ps2[0][t] + ps2[1][t] + ps2[2][t] + ps2[3][t];
        const size_t gp = (size_t)b * HWN + p0 + t;
        psum[(size_t)(c0 >> 6) * NPIX + gp] = s1;
        psq [(size_t)(c0 >> 6) * NPIX + gp] = s2;
    }
}

// ---------------------------------------------------------------------------
// QKV GEMM: 128x256 tile, BK=64 two-plane LDS, 512 threads (8 waves of 64x64).
// Single fp16 (A x64 scaled). LN stats finished in-block from psum/psq.
// out fp16 = rstd[p]*(acc/64 - mean[p]*s[o]).
__global__ __launch_bounds__(512) void qkv_gemm(const h16* __restrict__ Ahg,
                                                const h16* __restrict__ Bhg,
                                                const float* __restrict__ sv,
                                                const float* __restrict__ psum,
                                                const float* __restrict__ psq,
                                                h16* __restrict__ qout) {
    __shared__ __align__(16) h16 Ah[8192];    // 2 planes x [128][32]
    __shared__ __align__(16) h16 Bh[16384];   // 2 planes x [256][32]
    __shared__ float mnS[256], rsS[256];
    const int tid = threadIdx.x;
    const int om = blockIdx.x * 128;
    const int by0 = blockIdx.y;
    const int by  = (by0 & 7) * 32 + (by0 >> 3);   // bijective XCD chunking (256%8==0)
    const int p0  = by * 256;

    const int srow = tid >> 2;
    const int skh  = ((tid & 3) ^ (srow & 3)) * 8;
    const size_t a0 = (size_t)(om + srow) * CCH + skh;
    const size_t b0 = (size_t)(p0 + srow) * CCH + skh;

    const int lane = tid & 63;
    const int wv = tid >> 6;
    const int wm = (wv >> 2) * 64, wn = (wv & 3) * 64;
    const int lr = lane & 15, kg = lane >> 4;
    const int swz = (kg ^ (lr & 3)) * 8;

    f32x4 acc[4][4];
#pragma unroll
    for (int i = 0; i < 4; ++i)
#pragma unroll
        for (int j = 0; j < 4; ++j) acc[i][j] = {0.f, 0.f, 0.f, 0.f};

#define STAGE(KC)                                                          \
    do {                                                                   \
        gl_lds16(Ahg + a0 + (KC),                 Ah + tid * 8);           \
        gl_lds16(Ahg + a0 + (KC) + 32,            Ah + 4096 + tid * 8);    \
        gl_lds16(Bhg + b0 + (KC),                 Bh + tid * 8);           \
        gl_lds16(Bhg + b0 + (KC) + 128 * CCH,     Bh + 4096 + tid * 8);    \
        gl_lds16(Bhg + b0 + (KC) + 32,            Bh + 8192 + tid * 8);    \
        gl_lds16(Bhg + b0 + (KC) + 32 + 128 * CCH, Bh + 12288 + tid * 8);  \
    } while (0)

    STAGE(0);
    if (tid < 256) {
        const int gp = p0 + tid;
        float s1 = 0.f, s2 = 0.f;
#pragma unroll
        for (int cb = 0; cb < 8; ++cb) {
            s1 += psum[(size_t)cb * NPIX + gp];
            s2 += psq [(size_t)cb * NPIX + gp];
        }
        const float m = s1 * (1.f / 512.f);
        float var = s2 * (1.f / 512.f) - m * m;
        var = fmaxf(var, 0.f);
        mnS[tid] = m;
        rsS[tid] = rsqrtf(var + LN_EPS);
    }

#pragma unroll 1
    for (int kc = 0; kc < 512; kc += 64) {
        __syncthreads();
        f16x8 a0f[4], b0f[4], a1f[4], b1f[4];
#pragma unroll
        for (int i = 0; i < 4; ++i) {
            a0f[i] = *(const f16x8*)(Ah + (wm + i * 16 + lr) * 32 + swz);
            b0f[i] = *(const f16x8*)(Bh + (wn + i * 16 + lr) * 32 + swz);
        }
#pragma unroll
        for (int i = 0; i < 4; ++i)
#pragma unroll
            for (int j = 0; j < 4; ++j)
                acc[i][j] = __builtin_amdgcn_mfma_f32_16x16x32_f16(a0f[i], b0f[j], acc[i][j], 0, 0, 0);
#pragma unroll
        for (int i = 0; i < 4; ++i) {
            a1f[i] = *(const f16x8*)(Ah + 4096 + (wm + i * 16 + lr) * 32 + swz);
            b1f[i] = *(const f16x8*)(Bh + 8192 + (wn + i * 16 + lr) * 32 + swz);
        }
        __syncthreads();
        if (kc + 64 < 512) STAGE(kc + 64);
#pragma unroll
        for (int i = 0; i < 4; ++i)
#pragma unroll
            for (int j = 0; j < 4; ++j)
                acc[i][j] = __builtin_amdgcn_mfma_f32_16x16x32_f16(a1f[i], b1f[j], acc[i][j], 0, 0, 0);
    }
#undef STAGE

    const int b = p0 >> 12, hw0 = p0 & 4095;
    float mn[4], rs[4];
#pragma unroll
    for (int j = 0; j < 4; ++j) {
        const int px = wn + j * 16 + lr;
        mn[j] = mnS[px]; rs[j] = rsS[px];
    }
#pragma unroll
    for (int i = 0; i < 4; ++i)
#pragma unroll
        for (int r = 0; r < 4; ++r) {
            const int o = om + wm + i * 16 + kg * 4 + r;
            const float so = sv[o];
            h16* dst = qout + ((size_t)b * OC3 + o) * HWN;
#pragma unroll
            for (int j = 0; j < 4; ++j) {
                const int hw = hw0 + wn + j * 16 + lr;
                dst[hw] = (h16)(rs[j] * (acc[i][j][r] * (1.f / 64.f) - mn[j] * so));
            }
        }
}

// ---------------------------------------------------------------------------
// MFMA context partial over a 256-pixel chunk (1 wave, no LDS, no barriers):
// pass 1: chunk-local row max from k (32KB, leaves it L2-warm);
// pass 2: pt[d][e] = sum_n exp16(k-m) * v[e][n] via MFMA; z[d] = sum exp (f32).
// Output per (bh,ci): [4096 pt][64 z][64 m], stride 4224.
__global__ __launch_bounds__(64) void ctx_partial(const h16* __restrict__ qkv16,
                                                  float* __restrict__ ctp) {
    const int bh = blockIdx.y, ci = blockIdx.x;   // ci 0..15
    const int b = bh >> 3, h = bh & 7;
    const h16* kb = qkv16 + ((size_t)b * OC3 + CCH  + h * 64) * HWN;
    const h16* vb = qkv16 + ((size_t)b * OC3 + 1024 + h * 64) * HWN;
    const int lane = threadIdx.x;
    const int lr = lane & 15, kg = lane >> 4;
    const int nbase = ci * 256 + kg * 8;

    float m[4] = {-1e30f, -1e30f, -1e30f, -1e30f};
#pragma unroll 1
    for (int c = 0; c < 8; ++c) {
        const int n0 = nbase + c * 32;
#pragma unroll
        for (int i = 0; i < 4; ++i) {
            const f16x8 kv = *(const f16x8*)(kb + (size_t)(i * 16 + lr) * HWN + n0);
#pragma unroll
            for (int u = 0; u < 8; ++u) m[i] = fmaxf(m[i], (float)kv[u]);
        }
    }
#pragma unroll
    for (int i = 0; i < 4; ++i) {
        m[i] = fmaxf(m[i], __shfl_xor(m[i], 16));
        m[i] = fmaxf(m[i], __shfl_xor(m[i], 32));
    }

    float z[4] = {0.f, 0.f, 0.f, 0.f};
    f32x4 acc[4][4];
#pragma unroll
    for (int i = 0; i < 4; ++i)
#pragma unroll
        for (int j = 0; j < 4; ++j) acc[i][j] = {0.f, 0.f, 0.f, 0.f};

#pragma unroll 1
    for (int c = 0; c < 8; ++c) {
        const int n0 = nbase + c * 32;
        f16x8 ke[4], vf[4];
#pragma unroll
        for (int j = 0; j < 4; ++j)
            vf[j] = *(const f16x8*)(vb + (size_t)(j * 16 + lr) * HWN + n0);
#pragma unroll
        for (int i = 0; i < 4; ++i) {
            const f16x8 kv = *(const f16x8*)(kb + (size_t)(i * 16 + lr) * HWN + n0);
            f16x8 t;
#pragma unroll
            for (int u = 0; u < 8; ++u) {
                const float e = __expf((float)kv[u] - m[i]);
                z[i] += e;
                t[u] = (h16)e;
            }
            ke[i] = t;
        }
#pragma unroll
        for (int i = 0; i < 4; ++i)
#pragma unroll
            for (int j = 0; j < 4; ++j)
                acc[i][j] = __builtin_amdgcn_mfma_f32_16x16x32_f16(ke[i], vf[j], acc[i][j], 0, 0, 0);
    }
#pragma unroll
    for (int i = 0; i < 4; ++i) {
        z[i] += __shfl_xor(z[i], 16);
        z[i] += __shfl_xor(z[i], 32);
    }
    float* dst = ctp + ((size_t)bh * 16 + ci) * 4224;
#pragma unroll
    for (int i = 0; i < 4; ++i)
#pragma unroll
        for (int j = 0; j < 4; ++j)
#pragma unroll
            for (int r = 0; r < 4; ++r)
                dst[(i * 16 + kg * 4 + r) * 64 + j * 16 + lr] = acc[i][j][r];
    if (kg == 0)
#pragma unroll
        for (int i = 0; i < 4; ++i) {
            dst[4096 + i * 16 + lr] = z[i];
            dst[4160 + i * 16 + lr] = m[i];
        }
}

// ---------------------------------------------------------------------------
// combine 16 chunk partials with exp(m_loc - M) rescale, normalize, and emit
// TRANSPOSED fp16: ctt[e][d] = (sum_ci w*pt[d][e]) / (sum_ci w*z[d])
__global__ __launch_bounds__(256) void ctx_reduce(const float* __restrict__ ctp,
                                                  h16* __restrict__ ctt) {
    __shared__ float w[16][64];
    __shared__ float rz[64];
    const int bh = blockIdx.x;
    const int tid = threadIdx.x;
    const float* src = ctp + (size_t)bh * 16 * 4224;
    if (tid < 64) {
        float M = -1e30f;
#pragma unroll
        for (int ci = 0; ci < 16; ++ci)
            M = fmaxf(M, src[(size_t)ci * 4224 + 4160 + tid]);
        float Z = 0.f;
#pragma unroll
        for (int ci = 0; ci < 16; ++ci) {
            const float ww = __expf(src[(size_t)ci * 4224 + 4160 + tid] - M);
            w[ci][tid] = ww;
            Z += ww * src[(size_t)ci * 4224 + 4096 + tid];
        }
        rz[tid] = 1.f / Z;
    }
    __syncthreads();
    h16* dstt = ctt + (size_t)bh * 4096;
    for (int e4 = tid * 4; e4 < 4096; e4 += 1024) {
        const int d = e4 >> 6, e0 = e4 & 63;
        float4 sum = make_float4(0.f, 0.f, 0.f, 0.f);
#pragma unroll
        for (int ci = 0; ci < 16; ++ci) {
            const float4 v = *(const float4*)(src + (size_t)ci * 4224 + e4);
            const float ww = w[ci][d];
            sum.x += ww * v.x; sum.y += ww * v.y;
            sum.z += ww * v.z; sum.w += ww * v.w;
        }
        const float r = rz[d];
        dstt[(e0 + 0) * 64 + d] = (h16)(sum.x * r);
        dstt[(e0 + 1) * 64 + d] = (h16)(sum.y * r);
        dstt[(e0 + 2) * 64 + d] = (h16)(sum.z * r);
        dstt[(e0 + 3) * 64 + d] = (h16)(sum.w * r);
    }
}

// ---------------------------------------------------------------------------
// q-softmax(d)*(512*SCALE), at[e][n] = sum_d ctt[e][d]*qtilde[d][n] via MFMA.
// ctt A-frags held in registers per block; qtilde fp16 in LDS (B operand).
// writes at fp16, TRANSPOSED to [b*4096+n][512] (in ws).
__global__ __launch_bounds__(256) void attn_out(const h16* __restrict__ qkv16,
                                                const h16* __restrict__ ctt,
                                                h16* __restrict__ at) {
    __shared__ __align__(16) h16 qt[64][72];   // [px][d]; reused as ot[px][e]

    const int bh = blockIdx.y, ci = blockIdx.x;
    const int b = bh >> 3, h = bh & 7;
    const h16* qb = qkv16 + ((size_t)b * OC3 + h * 64) * HWN;
    const int tid = threadIdx.x;
    const int lane = tid & 63, wv = tid >> 6;
    const int lr = lane & 15, kg = lane >> 4;

    // A-frags: ctt[e = wv*16+lr][d = ks*32 + kg*8 + u], loaded once per block
    const h16* cb = ctt + (size_t)bh * 4096 + (wv * 16 + lr) * 64 + kg * 8;
    f16x8 af0 = *(const f16x8*)(cb);
    f16x8 af1 = *(const f16x8*)(cb + 32);

    const int d  = tid >> 2;
    const int rn = tid >> 2, d0q = (tid & 3) * 16;

    for (int t = 0; t < 8; ++t) {
        const int n0 = ci * 512 + t * 64;
        __syncthreads();   // ot fully consumed (t>0)
#pragma unroll
        for (int jj = 0; jj < 2; ++jj) {
            const int nn = (tid & 3) * 8 + jj * 32;
            const f16x8 qv = *(const f16x8*)(qb + (size_t)d * HWN + n0 + nn);
#pragma unroll
            for (int u = 0; u < 8; ++u) qt[nn + u][d] = qv[u];
        }
        __syncthreads();
        {   // softmax over d (4 lanes/px, 16 d each); write qtilde fp16 in place
            float qv[16];
            float mx = -1e30f;
#pragma unroll
            for (int dd = 0; dd < 16; ++dd) {
                qv[dd] = (float)qt[rn][d0q + dd];
                mx = fmaxf(mx, qv[dd]);
            }
            mx = fmaxf(mx, __shfl_xor(mx, 1));
            mx = fmaxf(mx, __shfl_xor(mx, 2));
            float sm = 0.f;
#pragma unroll
            for (int dd = 0; dd < 16; ++dd) {
                qv[dd] = __expf(qv[dd] - mx);
                sm += qv[dd];
            }
            sm += __shfl_xor(sm, 1);
            sm += __shfl_xor(sm, 2);
            const float sc = 512.f * QSCALE / sm;
#pragma unroll
            for (int dd = 0; dd < 16; ++dd)
                qt[rn][d0q + dd] = (h16)(qv[dd] * sc);
        }
        __syncthreads();
        // MFMA: wave wv computes e-rows wv*16..+16 x 64 px (4 j x 2 ks)
        f32x4 acc4[4];
#pragma unroll
        for (int j = 0; j < 4; ++j) acc4[j] = {0.f, 0.f, 0.f, 0.f};
#pragma unroll
        for (int j = 0; j < 4; ++j) {
            const f16x8 bf0 = *(const f16x8*)(&qt[j * 16 + lr][kg * 8]);
            const f16x8 bf1 = *(const f16x8*)(&qt[j * 16 + lr][32 + kg * 8]);
            acc4[j] = __builtin_amdgcn_mfma_f32_16x16x32_f16(af0, bf0, acc4[j], 0, 0, 0);
            acc4[j] = __builtin_amdgcn_mfma_f32_16x16x32_f16(af1, bf1, acc4[j], 0, 0, 0);
        }
        __syncthreads();   // qt reads done; reuse as ot[px][e]
#pragma unroll
        for (int j = 0; j < 4; ++j) {
            f16x4 o4;
            o4[0] = (h16)acc4[j][0]; o4[1] = (h16)acc4[j][1];
            o4[2] = (h16)acc4[j][2]; o4[3] = (h16)acc4[j][3];
            *(f16x4*)(&qt[j * 16 + lr][wv * 16 + kg * 4]) = o4;
        }
        __syncthreads();
        {   // gather per pixel: 4 threads/pixel, 16 e each
            const int px = tid >> 2, e0 = (tid & 3) * 16;
            const f16x8 vh0 = *(const f16x8*)(&qt[px][e0]);
            const f16x8 vh1 = *(const f16x8*)(&qt[px][e0 + 8]);
            const size_t o = ((size_t)b * HWN + n0 + px) * CCH + h * 64 + e0;
            *(f16x8*)(at + o)     = vh0;
            *(f16x8*)(at + o + 8) = vh1;
        }
    }
}

// ---------------------------------------------------------------------------
// Fused out-GEMM + channel LN + residual. Single fp16: (wo_hi, at), K=512.
__global__ __launch_bounds__(512) void out_fused(const h16* __restrict__ wo_hi,
                                                 const h16* __restrict__ at,
                                                 const float* __restrict__ b_out,
                                                 const float* __restrict__ g_out,
                                                 const float* __restrict__ x,
                                                 float* __restrict__ out) {
    __shared__ __align__(16) h16 Alds[512 * 32];
    __shared__ __align__(16) h16 Blds[128 * 32];
    __shared__ float red1[4][128], red2[4][128];
    __shared__ float mnS[128], rsS[128];

    const int tid = threadIdx.x;
    const int p0 = blockIdx.x * 128;
    const int b = p0 >> 12, hw0 = p0 & 4095;

    const int trow = tid >> 2;
    const int skh  = ((tid & 3) ^ (trow & 3)) * 8;
    const size_t aoff = (size_t)trow * CCH + skh;
    const size_t boff = (size_t)p0 * CCH + aoff;
    const int wofs = (tid >> 6) * 512;

    const int wv = tid >> 6;
    const int wm = (wv >> 1) * 128, wn = (wv & 1) * 64;
    const int lane = tid & 63;
    const int lr = lane & 15, kg = lane >> 4;
    const int swz = (kg ^ (lr & 3)) * 8;

    f32x4 acc[8][4];
#pragma unroll
    for (int i = 0; i < 8; ++i)
#pragma unroll
        for (int j = 0; j < 4; ++j) acc[i][j] = {0.f, 0.f, 0.f, 0.f};

#define STAGEF(S)                                                           \
    do {                                                                    \
        const int kc_ = (S) * 32;                                           \
        gl_lds16(wo_hi + aoff + kc_,               Alds + wofs);            \
        gl_lds16(wo_hi + aoff + kc_ + 128 * CCH,   Alds + 4096 + wofs);     \
        gl_lds16(wo_hi + aoff + kc_ + 256 * CCH,   Alds + 8192 + wofs);     \
        gl_lds16(wo_hi + aoff + kc_ + 384 * CCH,   Alds + 12288 + wofs);    \
        gl_lds16(at + boff + kc_,                  Blds + wofs);            \
    } while (0)

    STAGEF(0);
#pragma unroll 1
    for (int s = 0; s < 16; ++s) {
        __syncthreads();
        f16x8 af[8], bf[4];
#pragma unroll
        for (int i = 0; i < 8; ++i)
            af[i] = *(const f16x8*)(Alds + (wm + i * 16 + lr) * 32 + swz);
#pragma unroll
        for (int j = 0; j < 4; ++j)
            bf[j] = *(const f16x8*)(Blds + (wn + j * 16 + lr) * 32 + swz);
        __syncthreads();
        if (s < 15) STAGEF(s + 1);
#pragma unroll
        for (int i = 0; i < 8; ++i)
#pragma unroll
            for (int j = 0; j < 4; ++j)
                acc[i][j] = __builtin_amdgcn_mfma_f32_16x16x32_f16(af[i], bf[j], acc[i][j], 0, 0, 0);
    }
#undef STAGEF

#pragma unroll
    for (int i = 0; i < 8; ++i) {
        const int o = wm + i * 16 + kg * 4;
        const float4 bb = *(const float4*)(b_out + o);
#pragma unroll
        for (int j = 0; j < 4; ++j) {
            acc[i][j][0] = acc[i][j][0] * (1.f / 134217728.f) + bb.x;
            acc[i][j][1] = acc[i][j][1] * (1.f / 134217728.f) + bb.y;
            acc[i][j][2] = acc[i][j][2] * (1.f / 134217728.f) + bb.z;
            acc[i][j][3] = acc[i][j][3] * (1.f / 134217728.f) + bb.w;
        }
    }
    float s1[4], s2[4];
#pragma unroll
    for (int j = 0; j < 4; ++j) {
        s1[j] = 0.f; s2[j] = 0.f;
#pragma unroll
        for (int i = 0; i < 8; ++i)
#pragma unroll
            for (int r = 0; r < 4; ++r) {
                const float v = acc[i][j][r];
                s1[j] += v; s2[j] += v * v;
            }
        s1[j] += __shfl_xor(s1[j], 16); s1[j] += __shfl_xor(s1[j], 32);
        s2[j] += __shfl_xor(s2[j], 16); s2[j] += __shfl_xor(s2[j], 32);
    }
    if (kg == 0) {
#pragma unroll
        for (int j = 0; j < 4; ++j) {
            red1[wv >> 1][wn + j * 16 + lr] = s1[j];
            red2[wv >> 1][wn + j * 16 + lr] = s2[j];
        }
    }
    __syncthreads();
    if (tid < 128) {
        const float S1 = red1[0][tid] + red1[1][tid] + red1[2][tid] + red1[3][tid];
        const float S2 = red2[0][tid] + red2[1][tid] + red2[2][tid] + red2[3][tid];
        const float m = S1 * (1.f / 512.f);
        float var = S2 * (1.f / 512.f) - m * m;
        var = fmaxf(var, 0.f);
        mnS[tid] = m;
        rsS[tid] = rsqrtf(var + LN_EPS);
    }
    __syncthreads();
    float mj[4], rj[4];
#pragma unroll
    for (int j = 0; j < 4; ++j) {
        const int px = wn + j * 16 + lr;
        mj[j] = mnS[px]; rj[j] = rsS[px];
    }
#pragma unroll
    for (int i = 0; i < 8; ++i) {
        const int o = wm + i * 16 + kg * 4;
        const float4 gg = *(const float4*)(g_out + o);
#pragma unroll
        for (int r = 0; r < 4; ++r) {
            const float g = (r == 0) ? gg.x : (r == 1) ? gg.y : (r == 2) ? gg.z : gg.w;
            const float* xr = x + ((size_t)b * CCH + o + r) * HWN + hw0 + wn;
            float* dr = out + ((size_t)b * CCH + o + r) * HWN + hw0 + wn;
#pragma unroll
            for (int j = 0; j < 4; ++j) {
                const int c = j * 16 + lr;
                dr[c] = (acc[i][j][r] - mj[j]) * rj[j] * g + xr[c];
            }
        }
    }
}

// ---------------------------------------------------------------------------
extern "C" void kernel_launch(void* const* d_in, const int* in_sizes, int n_in,
                              void* d_out, int out_size, void* d_ws, size_t ws_size,
                              hipStream_t stream) {
    (void)in_sizes; (void)n_in; (void)out_size;
    const float* x     = (const float*)d_in[0];
    const float* w_qkv = (const float*)d_in[1];
    const float* w_out = (const float*)d_in[2];
    const float* b_out = (const float*)d_in[3];
    const float* g_out = (const float*)d_in[4];
    const float* g_ln  = (const float*)d_in[5];
    float* out = (float*)d_out;
    float* ws  = (float*)d_ws;

    float* s    = ws;                       // 1536
    h16*  ctt   = (h16*)(s + OC3);          // 524288 halfs
    float* ctp  = s + OC3 + 524288;         // 8650752 (128 bh x 16 ci x 4224)
    float* psum = ctp;                      // 524288 (alias: dead before ctx)
    float* psq  = psum + 524288;            // 524288
    h16*  wg_hi = (h16*)(ctp + 8650752);    // 786432 halfs
    h16*  wo_hi = wg_hi + 786432;           // 262144 halfs
    h16*  qkv16 = wo_hi + 262144;           // 100663296 halfs (fp16 q,k,v)
    h16*  at    = qkv16 + 100663296;        // 33554432 halfs (attn out, transposed)
    // alias of d_out: xt dead after qkv_gemm (out_fused is sole d_out writer)
    h16*  xt_hi = (h16*)d_out;

    const size_t need = 76809728ULL * 4ULL;   // ~307.2 MB
    if (ws_size < need) return;

    transpose_prep<<<dim3(64, 8, 17), 256, 0, stream>>>(x, xt_hi, psum, psq,
                                                        w_qkv, g_ln, w_out,
                                                        wg_hi, s, wo_hi);
    qkv_gemm     <<<dim3(12, 256), 512, 0, stream>>>(wg_hi, xt_hi,
                                                     s, psum, psq, qkv16);
    ctx_partial  <<<dim3(16, 128), 64, 0, stream>>>(qkv16, ctp);
    ctx_reduce   <<<128, 256, 0, stream>>>(ctp, ctt);
    attn_out     <<<dim3(8, 128), 256, 0, stream>>>(qkv16, ctt, at);
    out_fused    <<<512, 512, 0, stream>>>(wo_hi, at,
                                           b_out, g_out, x, out);
}

// Round 20
// 378.361 us; speedup vs baseline: 1.5375x; 1.0171x over previous
//
#include <hip/hip_runtime.h>
#include <math.h>

#define CCH    512
#define HWN    4096
#define NPIX   65536
#define OC3    1536
#define QSCALE 0.125f
#define LN_EPS 1e-5f

typedef _Float16 h16;
typedef h16  f16x8 __attribute__((ext_vector_type(8)));
typedef h16  f16x4 __attribute__((ext_vector_type(4)));
typedef float f32x4 __attribute__((ext_vector_type(4)));

__device__ __forceinline__ float waveReduceSum(float v) {
#pragma unroll
    for (int off = 32; off; off >>= 1) v += __shfl_xor(v, off);
    return v;
}

__device__ __forceinline__ void gl_lds16(const void* g, void* l) {
    __builtin_amdgcn_global_load_lds((const __attribute__((address_space(1))) void*)g,
                                     (__attribute__((address_space(3))) void*)l, 16, 0, 0);
}

// ---------------------------------------------------------------------------
// fused: z<16  -> fp32 x -> transposed fp16 [16][4096][512] + LN partials
//        z==16 -> weight prep (wave = one row)
__global__ __launch_bounds__(256) void transpose_prep(const float* __restrict__ src,
                                                      h16* __restrict__ dhi,
                                                      float* __restrict__ psum,
                                                      float* __restrict__ psq,
                                                      const float* __restrict__ w_qkv,
                                                      const float* __restrict__ g_ln,
                                                      const float* __restrict__ w_out,
                                                      h16* __restrict__ wg_h,
                                                      float* __restrict__ s,
                                                      h16* __restrict__ wo_h) {
    __shared__ float tile[64][65];
    __shared__ float ps1[4][64], ps2[4][64];
    const int t = threadIdx.x;

    if (blockIdx.z == 16) {
        const int o = (blockIdx.x + 64 * blockIdx.y) * 4 + (t >> 6);
        const int lane = t & 63;
        if (o < OC3) {
            float sum = 0.f;
#pragma unroll
            for (int j = 0; j < 8; ++j) {
                const int c = lane + j * 64;
                const float w = w_qkv[(size_t)o * CCH + c] * g_ln[c];
                wg_h[(size_t)o * CCH + c] = (h16)(w * 64.f);
                sum += w;
            }
            sum = waveReduceSum(sum);
            if (lane == 0) s[o] = sum;
        } else {
            const int r = o - OC3;
#pragma unroll
            for (int j = 0; j < 8; ++j) {
                const int c = lane + j * 64;
                wo_h[(size_t)r * CCH + c] = (h16)(w_out[(size_t)r * CCH + c] * 64.f);
            }
        }
        return;
    }

    const int b = blockIdx.z, c0 = blockIdx.y * 64, p0 = blockIdx.x * 64;
    const float* sb = src + ((size_t)b * CCH + c0) * HWN + p0;
    const int rc = t >> 4, cc4 = (t & 15) * 4;
#pragma unroll
    for (int ps = 0; ps < 4; ++ps) {
        const float4 v = *(const float4*)(sb + (size_t)(rc + ps * 16) * HWN + cc4);
        tile[rc + ps * 16][cc4 + 0] = v.x;
        tile[rc + ps * 16][cc4 + 1] = v.y;
        tile[rc + ps * 16][cc4 + 2] = v.z;
        tile[rc + ps * 16][cc4 + 3] = v.w;
    }
    __syncthreads();
    {
        const int q = t >> 6, px = t & 63;
        float s1 = 0.f, s2 = 0.f;
#pragma unroll
        for (int c = q * 16; c < q * 16 + 16; ++c) {
            const float v = tile[c][px];
            s1 += v; s2 += v * v;
        }
        ps1[q][px] = s1; ps2[q][px] = s2;
    }
    const int pr0 = t >> 3, cs = (t & 7) * 8;
#pragma unroll
    for (int ps = 0; ps < 2; ++ps) {
        const int pr = pr0 + ps * 32;
        f16x8 vh;
#pragma unroll
        for (int q = 0; q < 8; ++q) vh[q] = (h16)tile[cs + q][pr];
        const size_t o = ((size_t)b * HWN + p0 + pr) * CCH + c0 + cs;
        *(f16x8*)(dhi + o) = vh;
    }
    __syncthreads();
    if (t < 64) {
        const float s1 = ps1[0][t] + ps1[1][t] + ps1[2][t] + ps1[3][t];
        const float s2 = ps2[0][t] + ps2[1][t] + ps2[2][t] + ps2[3][t];
        const size_t gp = (size_t)b * HWN + p0 + t;
        psum[(size_t)(c0 >> 6) * NPIX + gp] = s1;
        psq [(size_t)(c0 >> 6) * NPIX + gp] = s2;
    }
}

// ---------------------------------------------------------------------------
// QKV GEMM: 128x256 tile, BK=64 two-plane LDS, 512 threads (8 waves of 64x64).
// Single fp16 (A x64 scaled). LN stats finished in-block from psum/psq.
// out fp16 = rstd[p]*(acc/64 - mean[p]*s[o]).
__global__ __launch_bounds__(512) void qkv_gemm(const h16* __restrict__ Ahg,
                                                const h16* __restrict__ Bhg,
                                                const float* __restrict__ sv,
                                                const float* __restrict__ psum,
                                                const float* __restrict__ psq,
                                                h16* __restrict__ qout) {
    __shared__ __align__(16) h16 Ah[8192];
    __shared__ __align__(16) h16 Bh[16384];
    __shared__ float mnS[256], rsS[256];
    const int tid = threadIdx.x;
    const int om = blockIdx.x * 128;
    const int by0 = blockIdx.y;
    const int by  = (by0 & 7) * 32 + (by0 >> 3);
    const int p0  = by * 256;

    const int srow = tid >> 2;
    const int skh  = ((tid & 3) ^ (srow & 3)) * 8;
    const size_t a0 = (size_t)(om + srow) * CCH + skh;
    const size_t b0 = (size_t)(p0 + srow) * CCH + skh;

    const int lane = tid & 63;
    const int wv = tid >> 6;
    const int wm = (wv >> 2) * 64, wn = (wv & 3) * 64;
    const int lr = lane & 15, kg = lane >> 4;
    const int swz = (kg ^ (lr & 3)) * 8;

    f32x4 acc[4][4];
#pragma unroll
    for (int i = 0; i < 4; ++i)
#pragma unroll
        for (int j = 0; j < 4; ++j) acc[i][j] = {0.f, 0.f, 0.f, 0.f};

#define STAGE(KC)                                                          \
    do {                                                                   \
        gl_lds16(Ahg + a0 + (KC),                 Ah + tid * 8);           \
        gl_lds16(Ahg + a0 + (KC) + 32,            Ah + 4096 + tid * 8);    \
        gl_lds16(Bhg + b0 + (KC),                 Bh + tid * 8);           \
        gl_lds16(Bhg + b0 + (KC) + 128 * CCH,     Bh + 4096 + tid * 8);    \
        gl_lds16(Bhg + b0 + (KC) + 32,            Bh + 8192 + tid * 8);    \
        gl_lds16(Bhg + b0 + (KC) + 32 + 128 * CCH, Bh + 12288 + tid * 8);  \
    } while (0)

    STAGE(0);
    if (tid < 256) {
        const int gp = p0 + tid;
        float s1 = 0.f, s2 = 0.f;
#pragma unroll
        for (int cb = 0; cb < 8; ++cb) {
            s1 += psum[(size_t)cb * NPIX + gp];
            s2 += psq [(size_t)cb * NPIX + gp];
        }
        const float m = s1 * (1.f / 512.f);
        float var = s2 * (1.f / 512.f) - m * m;
        var = fmaxf(var, 0.f);
        mnS[tid] = m;
        rsS[tid] = rsqrtf(var + LN_EPS);
    }

#pragma unroll 1
    for (int kc = 0; kc < 512; kc += 64) {
        __syncthreads();
        f16x8 a0f[4], b0f[4], a1f[4], b1f[4];
#pragma unroll
        for (int i = 0; i < 4; ++i) {
            a0f[i] = *(const f16x8*)(Ah + (wm + i * 16 + lr) * 32 + swz);
            b0f[i] = *(const f16x8*)(Bh + (wn + i * 16 + lr) * 32 + swz);
        }
#pragma unroll
        for (int i = 0; i < 4; ++i)
#pragma unroll
            for (int j = 0; j < 4; ++j)
                acc[i][j] = __builtin_amdgcn_mfma_f32_16x16x32_f16(a0f[i], b0f[j], acc[i][j], 0, 0, 0);
#pragma unroll
        for (int i = 0; i < 4; ++i) {
            a1f[i] = *(const f16x8*)(Ah + 4096 + (wm + i * 16 + lr) * 32 + swz);
            b1f[i] = *(const f16x8*)(Bh + 8192 + (wn + i * 16 + lr) * 32 + swz);
        }
        __syncthreads();
        if (kc + 64 < 512) STAGE(kc + 64);
#pragma unroll
        for (int i = 0; i < 4; ++i)
#pragma unroll
            for (int j = 0; j < 4; ++j)
                acc[i][j] = __builtin_amdgcn_mfma_f32_16x16x32_f16(a1f[i], b1f[j], acc[i][j], 0, 0, 0);
    }
#undef STAGE

    const int b = p0 >> 12, hw0 = p0 & 4095;
    float mn[4], rs[4];
#pragma unroll
    for (int j = 0; j < 4; ++j) {
        const int px = wn + j * 16 + lr;
        mn[j] = mnS[px]; rs[j] = rsS[px];
    }
#pragma unroll
    for (int i = 0; i < 4; ++i)
#pragma unroll
        for (int r = 0; r < 4; ++r) {
            const int o = om + wm + i * 16 + kg * 4 + r;
            const float so = sv[o];
            h16* dst = qout + ((size_t)b * OC3 + o) * HWN;
#pragma unroll
            for (int j = 0; j < 4; ++j) {
                const int hw = hw0 + wn + j * 16 + lr;
                dst[hw] = (h16)(rs[j] * (acc[i][j][r] * (1.f / 64.f) - mn[j] * so));
            }
        }
}

// ---------------------------------------------------------------------------
// MFMA context partial over a 256-pixel chunk (1 wave, no LDS, no barriers).
__global__ __launch_bounds__(64) void ctx_partial(const h16* __restrict__ qkv16,
                                                  float* __restrict__ ctp) {
    const int bh = blockIdx.y, ci = blockIdx.x;
    const int b = bh >> 3, h = bh & 7;
    const h16* kb = qkv16 + ((size_t)b * OC3 + CCH  + h * 64) * HWN;
    const h16* vb = qkv16 + ((size_t)b * OC3 + 1024 + h * 64) * HWN;
    const int lane = threadIdx.x;
    const int lr = lane & 15, kg = lane >> 4;
    const int nbase = ci * 256 + kg * 8;

    float m[4] = {-1e30f, -1e30f, -1e30f, -1e30f};
#pragma unroll 1
    for (int c = 0; c < 8; ++c) {
        const int n0 = nbase + c * 32;
#pragma unroll
        for (int i = 0; i < 4; ++i) {
            const f16x8 kv = *(const f16x8*)(kb + (size_t)(i * 16 + lr) * HWN + n0);
#pragma unroll
            for (int u = 0; u < 8; ++u) m[i] = fmaxf(m[i], (float)kv[u]);
        }
    }
#pragma unroll
    for (int i = 0; i < 4; ++i) {
        m[i] = fmaxf(m[i], __shfl_xor(m[i], 16));
        m[i] = fmaxf(m[i], __shfl_xor(m[i], 32));
    }

    float z[4] = {0.f, 0.f, 0.f, 0.f};
    f32x4 acc[4][4];
#pragma unroll
    for (int i = 0; i < 4; ++i)
#pragma unroll
        for (int j = 0; j < 4; ++j) acc[i][j] = {0.f, 0.f, 0.f, 0.f};

#pragma unroll 1
    for (int c = 0; c < 8; ++c) {
        const int n0 = nbase + c * 32;
        f16x8 ke[4], vf[4];
#pragma unroll
        for (int j = 0; j < 4; ++j)
            vf[j] = *(const f16x8*)(vb + (size_t)(j * 16 + lr) * HWN + n0);
#pragma unroll
        for (int i = 0; i < 4; ++i) {
            const f16x8 kv = *(const f16x8*)(kb + (size_t)(i * 16 + lr) * HWN + n0);
            f16x8 t;
#pragma unroll
            for (int u = 0; u < 8; ++u) {
                const float e = __expf((float)kv[u] - m[i]);
                z[i] += e;
                t[u] = (h16)e;
            }
            ke[i] = t;
        }
#pragma unroll
        for (int i = 0; i < 4; ++i)
#pragma unroll
            for (int j = 0; j < 4; ++j)
                acc[i][j] = __builtin_amdgcn_mfma_f32_16x16x32_f16(ke[i], vf[j], acc[i][j], 0, 0, 0);
    }
#pragma unroll
    for (int i = 0; i < 4; ++i) {
        z[i] += __shfl_xor(z[i], 16);
        z[i] += __shfl_xor(z[i], 32);
    }
    float* dst = ctp + ((size_t)bh * 16 + ci) * 4224;
#pragma unroll
    for (int i = 0; i < 4; ++i)
#pragma unroll
        for (int j = 0; j < 4; ++j)
#pragma unroll
            for (int r = 0; r < 4; ++r)
                dst[(i * 16 + kg * 4 + r) * 64 + j * 16 + lr] = acc[i][j][r];
    if (kg == 0)
#pragma unroll
        for (int i = 0; i < 4; ++i) {
            dst[4096 + i * 16 + lr] = z[i];
            dst[4160 + i * 16 + lr] = m[i];
        }
}

// ---------------------------------------------------------------------------
// combine 16 chunk partials with exp(m_loc - M) rescale, normalize, and emit
// TRANSPOSED fp16: ctt[e][d]
__global__ __launch_bounds__(256) void ctx_reduce(const float* __restrict__ ctp,
                                                  h16* __restrict__ ctt) {
    __shared__ float w[16][64];
    __shared__ float rz[64];
    const int bh = blockIdx.x;
    const int tid = threadIdx.x;
    const float* src = ctp + (size_t)bh * 16 * 4224;
    if (tid < 64) {
        float M = -1e30f;
#pragma unroll
        for (int ci = 0; ci < 16; ++ci)
            M = fmaxf(M, src[(size_t)ci * 4224 + 4160 + tid]);
        float Z = 0.f;
#pragma unroll
        for (int ci = 0; ci < 16; ++ci) {
            const float ww = __expf(src[(size_t)ci * 4224 + 4160 + tid] - M);
            w[ci][tid] = ww;
            Z += ww * src[(size_t)ci * 4224 + 4096 + tid];
        }
        rz[tid] = 1.f / Z;
    }
    __syncthreads();
    h16* dstt = ctt + (size_t)bh * 4096;
    for (int e4 = tid * 4; e4 < 4096; e4 += 1024) {
        const int d = e4 >> 6, e0 = e4 & 63;
        float4 sum = make_float4(0.f, 0.f, 0.f, 0.f);
#pragma unroll
        for (int ci = 0; ci < 16; ++ci) {
            const float4 v = *(const float4*)(src + (size_t)ci * 4224 + e4);
            const float ww = w[ci][d];
            sum.x += ww * v.x; sum.y += ww * v.y;
            sum.z += ww * v.z; sum.w += ww * v.w;
        }
        const float r = rz[d];
        dstt[(e0 + 0) * 64 + d] = (h16)(sum.x * r);
        dstt[(e0 + 1) * 64 + d] = (h16)(sum.y * r);
        dstt[(e0 + 2) * 64 + d] = (h16)(sum.z * r);
        dstt[(e0 + 3) * 64 + d] = (h16)(sum.w * r);
    }
}

// ---------------------------------------------------------------------------
// MEGA out kernel: per head h = 0..7:
//   A1: q[64d x 128px] (coalesced) -> qt[px][d] LDS
//   A2: q-softmax over d (4 lanes/px), qtilde fp16 in place (x 512*QSCALE)
//   A3: PV MFMA (A = ctt reg frags, B = qtilde) -> at-tile fp16 back into qt
//   A4: 2 GEMM K-steps: acc += wo(s) . at-tile
// epilogue: y = acc*2^-27 + bias; channel-LN; out = LN(y)*g_out + x.
__global__ __launch_bounds__(512) void out_fused(const h16* __restrict__ wo_hi,
                                                 const h16* __restrict__ qkv16,
                                                 const h16* __restrict__ ctt,
                                                 const float* __restrict__ b_out,
                                                 const float* __restrict__ g_out,
                                                 const float* __restrict__ x,
                                                 float* __restrict__ out) {
    __shared__ __align__(16) h16 Alds[512 * 32];   // 32 KB, one K-step
    __shared__ __align__(16) h16 qt[128][72];      // 18.4 KB; q / qtilde / at-tile
    __shared__ float red1[4][128], red2[4][128];
    __shared__ float mnS[128], rsS[128];

    const int tid = threadIdx.x;
    const int p0 = blockIdx.x * 128;
    const int b = p0 >> 12, hw0 = p0 & 4095;

    const int trow = tid >> 2;
    const int skh  = ((tid & 3) ^ (trow & 3)) * 8;
    const size_t aoff = (size_t)trow * CCH + skh;
    const int wofs = (tid >> 6) * 512;

    const int wv = tid >> 6;
    const int lane = tid & 63;
    const int lr = lane & 15, kg = lane >> 4;
    const int wm = (wv >> 1) * 128, wn = (wv & 1) * 64;   // GEMM map
    const int swz = (kg ^ (lr & 3)) * 8;
    const int pv_e0 = (wv & 3) * 16, pv_ph = (wv >> 2) * 64;   // PV map
    const int sm_px = tid >> 2, sm_d0 = (tid & 3) * 16;        // softmax map
    const int ql_d = tid >> 3, ql_px = (tid & 7) * 16;         // q-load map

    f32x4 acc[8][4];
#pragma unroll
    for (int i = 0; i < 8; ++i)
#pragma unroll
        for (int j = 0; j < 4; ++j) acc[i][j] = {0.f, 0.f, 0.f, 0.f};

#define STAGEF(S)                                                           \
    do {                                                                    \
        const int kc_ = (S) * 32;                                           \
        gl_lds16(wo_hi + aoff + kc_,               Alds + wofs);            \
        gl_lds16(wo_hi + aoff + kc_ + 128 * CCH,   Alds + 4096 + wofs);     \
        gl_lds16(wo_hi + aoff + kc_ + 256 * CCH,   Alds + 8192 + wofs);     \
        gl_lds16(wo_hi + aoff + kc_ + 384 * CCH,   Alds + 12288 + wofs);    \
    } while (0)

    STAGEF(0);

#pragma unroll 1
    for (int h = 0; h < 8; ++h) {
        const h16* qb = qkv16 + ((size_t)b * OC3 + h * 64) * HWN + hw0;
        // ---- A1: q load -> qt[px][d] ----
        {
            const f16x8 q0 = *(const f16x8*)(qb + (size_t)ql_d * HWN + ql_px);
            const f16x8 q1 = *(const f16x8*)(qb + (size_t)ql_d * HWN + ql_px + 8);
#pragma unroll
            for (int u = 0; u < 8; ++u) {
                qt[ql_px + u][ql_d]     = q0[u];
                qt[ql_px + 8 + u][ql_d] = q1[u];
            }
        }
        __syncthreads();
        // ---- A2: softmax over d ----
        {
            float qv[16];
            float mx = -1e30f;
#pragma unroll
            for (int dd = 0; dd < 16; ++dd) {
                qv[dd] = (float)qt[sm_px][sm_d0 + dd];
                mx = fmaxf(mx, qv[dd]);
            }
            mx = fmaxf(mx, __shfl_xor(mx, 1));
            mx = fmaxf(mx, __shfl_xor(mx, 2));
            float sm = 0.f;
#pragma unroll
            for (int dd = 0; dd < 16; ++dd) {
                qv[dd] = __expf(qv[dd] - mx);
                sm += qv[dd];
            }
            sm += __shfl_xor(sm, 1);
            sm += __shfl_xor(sm, 2);
            const float sc = 512.f * QSCALE / sm;
#pragma unroll
            for (int dd = 0; dd < 16; ++dd)
                qt[sm_px][sm_d0 + dd] = (h16)(qv[dd] * sc);
        }
        __syncthreads();
        // ---- A3: PV MFMA -> at-tile ----
        {
            const h16* cb = ctt + ((size_t)(b * 8 + h)) * 4096 + (pv_e0 + lr) * 64 + kg * 8;
            const f16x8 af0 = *(const f16x8*)(cb);
            const f16x8 af1 = *(const f16x8*)(cb + 32);
            f32x4 acc4[4];
#pragma unroll
            for (int j = 0; j < 4; ++j) acc4[j] = {0.f, 0.f, 0.f, 0.f};
#pragma unroll
            for (int j = 0; j < 4; ++j) {
                const int px = pv_ph + j * 16 + lr;
                const f16x8 bf0 = *(const f16x8*)(&qt[px][kg * 8]);
                const f16x8 bf1 = *(const f16x8*)(&qt[px][32 + kg * 8]);
                acc4[j] = __builtin_amdgcn_mfma_f32_16x16x32_f16(af0, bf0, acc4[j], 0, 0, 0);
                acc4[j] = __builtin_amdgcn_mfma_f32_16x16x32_f16(af1, bf1, acc4[j], 0, 0, 0);
            }
            __syncthreads();   // qtilde reads done; qt becomes at-tile
#pragma unroll
            for (int j = 0; j < 4; ++j) {
                f16x4 o4;
                o4[0] = (h16)acc4[j][0]; o4[1] = (h16)acc4[j][1];
                o4[2] = (h16)acc4[j][2]; o4[3] = (h16)acc4[j][3];
                *(f16x4*)(&qt[pv_ph + j * 16 + lr][pv_e0 + kg * 4]) = o4;
            }
        }
        // ---- A4: 2 GEMM K-steps consuming at-tile ----
#pragma unroll 1
        for (int ss = 0; ss < 2; ++ss) {
            const int s = 2 * h + ss;
            __syncthreads();   // at-tile visible (ss=0); STAGE(s) complete
            f16x8 af[8], bf[4];
#pragma unroll
            for (int i = 0; i < 8; ++i)
                af[i] = *(const f16x8*)(Alds + (wm + i * 16 + lr) * 32 + swz);
#pragma unroll
            for (int j = 0; j < 4; ++j)
                bf[j] = *(const f16x8*)(&qt[wn + j * 16 + lr][ss * 32 + kg * 8]);
            __syncthreads();   // frag reads done; Alds/qt free
            if (s < 15) STAGEF(s + 1);
#pragma unroll
            for (int i = 0; i < 8; ++i)
#pragma unroll
                for (int j = 0; j < 4; ++j)
                    acc[i][j] = __builtin_amdgcn_mfma_f32_16x16x32_f16(af[i], bf[j], acc[i][j], 0, 0, 0);
        }
    }
#undef STAGEF

    // ---- epilogue: y = acc*2^-27 + bias; LN; residual ----
#pragma unroll
    for (int i = 0; i < 8; ++i) {
        const int o = wm + i * 16 + kg * 4;
        const float4 bb = *(const float4*)(b_out + o);
#pragma unroll
        for (int j = 0; j < 4; ++j) {
            acc[i][j][0] = acc[i][j][0] * (1.f / 134217728.f) + bb.x;
            acc[i][j][1] = acc[i][j][1] * (1.f / 134217728.f) + bb.y;
            acc[i][j][2] = acc[i][j][2] * (1.f / 134217728.f) + bb.z;
            acc[i][j][3] = acc[i][j][3] * (1.f / 134217728.f) + bb.w;
        }
    }
    float s1[4], s2[4];
#pragma unroll
    for (int j = 0; j < 4; ++j) {
        s1[j] = 0.f; s2[j] = 0.f;
#pragma unroll
        for (int i = 0; i < 8; ++i)
#pragma unroll
            for (int r = 0; r < 4; ++r) {
                const float v = acc[i][j][r];
                s1[j] += v; s2[j] += v * v;
            }
        s1[j] += __shfl_xor(s1[j], 16); s1[j] += __shfl_xor(s1[j], 32);
        s2[j] += __shfl_xor(s2[j], 16); s2[j] += __shfl_xor(s2[j], 32);
    }
    if (kg == 0) {
#pragma unroll
        for (int j = 0; j < 4; ++j) {
            red1[wv >> 1][wn + j * 16 + lr] = s1[j];
            red2[wv >> 1][wn + j * 16 + lr] = s2[j];
        }
    }
    __syncthreads();
    if (tid < 128) {
        const float S1 = red1[0][tid] + red1[1][tid] + red1[2][tid] + red1[3][tid];
        const float S2 = red2[0][tid] + red2[1][tid] + red2[2][tid] + red2[3][tid];
        const float m = S1 * (1.f / 512.f);
        float var = S2 * (1.f / 512.f) - m * m;
        var = fmaxf(var, 0.f);
        mnS[tid] = m;
        rsS[tid] = rsqrtf(var + LN_EPS);
    }
    __syncthreads();
    float mj[4], rj[4];
#pragma unroll
    for (int j = 0; j < 4; ++j) {
        const int px = wn + j * 16 + lr;
        mj[j] = mnS[px]; rj[j] = rsS[px];
    }
#pragma unroll
    for (int i = 0; i < 8; ++i) {
        const int o = wm + i * 16 + kg * 4;
        const float4 gg = *(const float4*)(g_out + o);
#pragma unroll
        for (int r = 0; r < 4; ++r) {
            const float g = (r == 0) ? gg.x : (r == 1) ? gg.y : (r == 2) ? gg.z : gg.w;
            const float* xr = x + ((size_t)b * CCH + o + r) * HWN + hw0 + wn;
            float* dr = out + ((size_t)b * CCH + o + r) * HWN + hw0 + wn;
#pragma unroll
            for (int j = 0; j < 4; ++j) {
                const int c = j * 16 + lr;
                dr[c] = (acc[i][j][r] - mj[j]) * rj[j] * g + xr[c];
            }
        }
    }
}

// ---------------------------------------------------------------------------
extern "C" void kernel_launch(void* const* d_in, const int* in_sizes, int n_in,
                              void* d_out, int out_size, void* d_ws, size_t ws_size,
                              hipStream_t stream) {
    (void)in_sizes; (void)n_in; (void)out_size;
    const float* x     = (const float*)d_in[0];
    const float* w_qkv = (const float*)d_in[1];
    const float* w_out = (const float*)d_in[2];
    const float* b_out = (const float*)d_in[3];
    const float* g_out = (const float*)d_in[4];
    const float* g_ln  = (const float*)d_in[5];
    float* out = (float*)d_out;
    float* ws  = (float*)d_ws;

    float* s    = ws;                       // 1536
    h16*  ctt   = (h16*)(s + OC3);          // 524288 halfs
    float* ctp  = s + OC3 + 524288;         // 8650752 (128 bh x 16 ci x 4224)
    float* psum = ctp;                      // 524288 (alias: dead before ctx)
    float* psq  = psum + 524288;            // 524288
    h16*  wg_hi = (h16*)(ctp + 8650752);    // 786432 halfs
    h16*  wo_hi = wg_hi + 786432;           // 262144 halfs
    h16*  qkv16 = wo_hi + 262144;           // 100663296 halfs (fp16 q,k,v)
    // alias of d_out: xt dead after qkv_gemm (out_fused is sole d_out writer)
    h16*  xt_hi = (h16*)d_out;

    const size_t need = 60032512ULL * 4ULL;   // ~240.1 MB
    if (ws_size < need) return;

    transpose_prep<<<dim3(64, 8, 17), 256, 0, stream>>>(x, xt_hi, psum, psq,
                                                        w_qkv, g_ln, w_out,
                                                        wg_hi, s, wo_hi);
    qkv_gemm     <<<dim3(12, 256), 512, 0, stream>>>(wg_hi, xt_hi,
                                                     s, psum, psq, qkv16);
    ctx_partial  <<<dim3(16, 128), 64, 0, stream>>>(qkv16, ctp);
    ctx_reduce   <<<128, 256, 0, stream>>>(ctp, ctt);
    out_fused    <<<512, 512, 0, stream>>>(wo_hi, qkv16, ctt,
                                           b_out, g_out, x, out);
}